// Round 1
// baseline (2735.386 us; speedup 1.0000x reference)
//
#include <hip/hip_runtime.h>
#include <hip/hip_bf16.h>
#include <math.h>

// ---------------- static config ----------------
// B=4, H=W=256, TIN=10, F=4, P=8, CIN=12, E=768, NB=8, BS=96,
// HP=WP=32, MID=3072, DEPTH=4, LAM=0.01, WF=17, TOK=4096, POS=B*32*17=2176
// Spectral layout: X[((b*17+kw)*32 + h)*768 + c]   (h-rows contiguous per kw)
// Residual state t lives in f16 only (t_h); fp32 copy dropped (R9).
// R10: gemm_h K-loop rewritten depth-3 counted-vmcnt pipeline (T4):
//   4 LDS buffers, raw s_barrier, steady-state s_waitcnt vmcnt(3*LPT) -- never 0.

typedef __attribute__((ext_vector_type(8))) _Float16 half8;
typedef __attribute__((ext_vector_type(4))) _Float16 half4v;
typedef __attribute__((ext_vector_type(4))) float float4v;

__device__ __forceinline__ float gelu_f(float v) {
    return 0.5f * v * (1.0f + erff(v * 0.70710678118654752f));
}
__device__ __forceinline__ float shrink_f(float v) {
    return (v > 0.01f) ? (v - 0.01f) : ((v < -0.01f) ? (v + 0.01f) : 0.0f);
}

#define STEP32 0.19634954084936207f  // 2*pi/32

// async 16B global->LDS (lds dest wave-uniform; HW adds lane*16)
__device__ __forceinline__ void async16(const void* g, void* l) {
    __builtin_amdgcn_global_load_lds(
        (const __attribute__((address_space(1))) unsigned int*)g,
        (__attribute__((address_space(3))) unsigned int*)l, 16, 0, 0);
}

// ---------------- gather patches into A_h [4096][768] f16 ----------------
__global__ __launch_bounds__(256) void gather_patch(const float* __restrict__ x,
        const float* __restrict__ grd, _Float16* __restrict__ A)
{
    int idx = blockIdx.x * 256 + threadIdx.x;
    int j   = idx % 768;
    int tok = idx / 768;
    int c = j >> 6, p = (j >> 3) & 7, q = j & 7;
    int wp = tok & 31, hp = (tok >> 5) & 31, b = tok >> 10;
    int hh = hp * 8 + p, ww = wp * 8 + q;
    float v;
    if (c < 10) v = x[((b * 256 + hh) * 256 + ww) * 10 + c];
    else        v = grd[((b * 256 + hh) * 256 + ww) * 2 + (c - 10)];
    A[idx] = (_Float16)v;
}

// ---------------- forward DFT along W (f16 in -> 17 complex f16), scale 1/32 ----------------
// prepass + fallback path. out layout [b,kw,h,c]
__global__ __launch_bounds__(256) void dft_fwd_w(const _Float16* __restrict__ th,
        _Float16* __restrict__ Xr, _Float16* __restrict__ Xi)
{
    __shared__ float2 lut[32];
    int bh = blockIdx.x;            // b*32 + h
    int tid = threadIdx.x;
    if (tid < 32) { float a = tid * STEP32; lut[tid] = make_float2(cosf(a), sinf(a)); }
    __syncthreads();
    int b = bh >> 5, h = bh & 31;
    int c = blockIdx.y * 256 + tid;
    float v[32];
    #pragma unroll
    for (int w = 0; w < 32; ++w) v[w] = (float)th[(bh * 32 + w) * 768 + c];
    for (int kw = 0; kw <= 16; ++kw) {
        float ar = 0.f, ai = 0.f;
        #pragma unroll
        for (int w = 0; w < 32; ++w) {
            float2 cs = lut[(kw * w) & 31];
            ar += v[w] * cs.x;
            ai -= v[w] * cs.y;
        }
        size_t g = ((size_t)(b * 17 + kw) * 32 + h) * 768 + c;
        Xr[g] = (_Float16)(ar * 0.03125f);
        Xi[g] = (_Float16)(ai * 0.03125f);
    }
}

// ---------------- inverse DFT along W (f16 in, [b,kw,h,c]) + f16 residual in-place ----------------
__global__ __launch_bounds__(256) void dft_inv_w(const _Float16* __restrict__ Yr,
        const _Float16* __restrict__ Yi, _Float16* __restrict__ th)
{
    __shared__ float2 lut[32];
    int bh = blockIdx.x;
    int tid = threadIdx.x;
    if (tid < 32) { float a = tid * STEP32; lut[tid] = make_float2(cosf(a), sinf(a)); }
    __syncthreads();
    int b = bh >> 5, h = bh & 31;
    int c = blockIdx.y * 256 + tid;
    float yr[17], yi[16];
    #pragma unroll
    for (int k = 0; k <= 16; ++k) yr[k] = (float)Yr[((size_t)(b * 17 + k) * 32 + h) * 768 + c];
    #pragma unroll
    for (int k = 1; k <= 15; ++k) yi[k] = (float)Yi[((size_t)(b * 17 + k) * 32 + h) * 768 + c];
    for (int w = 0; w < 32; ++w) {
        float val = yr[0] + ((w & 1) ? -yr[16] : yr[16]);
        #pragma unroll
        for (int k = 1; k <= 15; ++k) {
            float2 cs = lut[(k * w) & 31];
            val += 2.f * (yr[k] * cs.x - yi[k] * cs.y);
        }
        int gi = (bh * 32 + w) * 768 + c;
        th[gi] = (_Float16)(val * 0.03125f + (float)th[gi]);
    }
}

// ---------------- spectral weight prep: [i][o] fp32 -> [o][i] f16, 128 matrices ----------------
__global__ __launch_bounds__(256) void prep_specw(const float* __restrict__ w1,
        const float* __restrict__ w2, _Float16* __restrict__ out)
{
    __shared__ float tile[96][97];
    int mid = blockIdx.x;
    int n  = mid & 7;
    int ri = (mid >> 3) & 1;
    int l  = (mid >> 4) & 1;
    int d  = mid >> 5;
    const float* src = (l ? w2 : w1) + ((size_t)(d * 2 + ri) * 8 + n) * 9216;
    for (int idx = threadIdx.x; idx < 9216; idx += 256)
        tile[idx / 96][idx % 96] = src[idx];
    __syncthreads();
    _Float16* dst = out + (size_t)mid * 9216;
    for (int idx = threadIdx.x; idx < 9216; idx += 256)
        dst[idx] = (_Float16)tile[idx % 96][idx / 96];   // dst[o][i] = src[i][o]
}

// ---------------- fused spectral: H-DFT -> spec1(gelu) -> spec2(shrink) -> H-IDFT ----------------
// IN-PLACE on X ([b,kw,h,c] layout). grid (68 = b*17+kw, 8 = n); 256 thr = 4 waves.
__global__ __launch_bounds__(256) void spec_fused(
        _Float16* __restrict__ Xr, _Float16* __restrict__ Xi,
        const _Float16* __restrict__ W1r, const _Float16* __restrict__ W1i,
        const _Float16* __restrict__ W2r, const _Float16* __restrict__ W2i,
        const float* __restrict__ b1r, const float* __restrict__ b1i,
        const float* __restrict__ b2r, const float* __restrict__ b2i)
{
    __shared__ alignas(16) _Float16 Ec[1024], Es[1024];       // [m][k] twiddle 32x32
    __shared__ alignas(16) _Float16 XTr[3840], XTi[3840];     // [c][h] pad40; stage C: [o][kh]
    __shared__ alignas(16) _Float16 Zr[3328], Zi[3328];       // [kh][c] pad104; stage D out [h][c]
    __shared__ alignas(16) _Float16 Sr[3328], Si[3328];       // [kh][o] pad104

    const int bk = blockIdx.x;       // b*17 + kw
    const int n  = blockIdx.y;
    const int tid = threadIdx.x;
    const int wave = tid >> 6, lane = tid & 63;
    const int wr = wave >> 1, wc = wave & 1;
    const int lr = lane & 15, quad = lane >> 4;
    const size_t base = (size_t)bk * 24576 + n * 96;    // + h*768 + c

    for (int i = tid; i < 1024; i += 256) {
        int kh = i >> 5, h = i & 31;
        float a = ((kh * h) & 31) * STEP32;
        Ec[i] = (_Float16)cosf(a);
        Es[i] = (_Float16)sinf(a);
    }
    // vector load -> LDS transpose [c][h]
    for (int i = tid; i < 384; i += 256) {
        int h = i / 12, cc = (i % 12) * 8;
        half8 vr = *(const half8*)(Xr + base + (size_t)h * 768 + cc);
        half8 vi = *(const half8*)(Xi + base + (size_t)h * 768 + cc);
        #pragma unroll
        for (int e = 0; e < 8; ++e) {
            XTr[(cc + e) * 40 + h] = vr[e];
            XTi[(cc + e) * 40 + h] = vi[e];
        }
    }
    __syncthreads();

    const _Float16* w1r = W1r + (size_t)n * 9216;
    const _Float16* w1i = W1i + (size_t)n * 9216;
    const _Float16* w2r = W2r + (size_t)n * 9216;
    const _Float16* w2i = W2i + (size_t)n * 9216;

    half8 eC = *(const half8*)&Ec[(wr * 16 + lr) * 32 + quad * 8];
    half8 eS = *(const half8*)&Es[(wr * 16 + lr) * 32 + quad * 8];
    half8 eSn = -eS;

    // stage A: Z[kh][c] = DFT_h(X)
    {
        float4v zr[3], zi[3];
        #pragma unroll
        for (int j = 0; j < 3; ++j) { float4v z = {0,0,0,0}; zr[j] = z; zi[j] = z; }
        #pragma unroll
        for (int j = 0; j < 3; ++j) {
            int c = wc * 48 + j * 16 + lr;
            half8 xr = *(const half8*)&XTr[c * 40 + quad * 8];
            half8 xi = *(const half8*)&XTi[c * 40 + quad * 8];
            zr[j] = __builtin_amdgcn_mfma_f32_16x16x32_f16(eC,  xr, zr[j], 0, 0, 0);
            zr[j] = __builtin_amdgcn_mfma_f32_16x16x32_f16(eS,  xi, zr[j], 0, 0, 0);
            zi[j] = __builtin_amdgcn_mfma_f32_16x16x32_f16(eC,  xi, zi[j], 0, 0, 0);
            zi[j] = __builtin_amdgcn_mfma_f32_16x16x32_f16(eSn, xr, zi[j], 0, 0, 0);
        }
        #pragma unroll
        for (int j = 0; j < 3; ++j) {
            int c = wc * 48 + j * 16 + lr;
            #pragma unroll
            for (int r = 0; r < 4; ++r) {
                int kh = wr * 16 + quad * 4 + r;
                Zr[kh * 104 + c] = (_Float16)zr[j][r];
                Zi[kh * 104 + c] = (_Float16)zi[j][r];
            }
        }
    }
    __syncthreads();

    // stage B: S = gelu(Z @ W1 + b1)
    {
        float4v sr[3], si[3];
        #pragma unroll
        for (int j = 0; j < 3; ++j) { float4v z = {0,0,0,0}; sr[j] = z; si[j] = z; }
        #pragma unroll
        for (int kc = 0; kc < 3; ++kc) {
            half8 ar = *(const half8*)&Zr[(wr * 16 + lr) * 104 + kc * 32 + quad * 8];
            half8 ai = *(const half8*)&Zi[(wr * 16 + lr) * 104 + kc * 32 + quad * 8];
            half8 ain = -ai;
            #pragma unroll
            for (int j = 0; j < 3; ++j) {
                int o = wc * 48 + j * 16 + lr;
                half8 br = *(const half8*)&w1r[o * 96 + kc * 32 + quad * 8];
                half8 bi = *(const half8*)&w1i[o * 96 + kc * 32 + quad * 8];
                sr[j] = __builtin_amdgcn_mfma_f32_16x16x32_f16(ar,  br, sr[j], 0, 0, 0);
                sr[j] = __builtin_amdgcn_mfma_f32_16x16x32_f16(ain, bi, sr[j], 0, 0, 0);
                si[j] = __builtin_amdgcn_mfma_f32_16x16x32_f16(ai,  br, si[j], 0, 0, 0);
                si[j] = __builtin_amdgcn_mfma_f32_16x16x32_f16(ar,  bi, si[j], 0, 0, 0);
            }
        }
        #pragma unroll
        for (int j = 0; j < 3; ++j) {
            int o = wc * 48 + j * 16 + lr;
            float br = b1r[n * 96 + o], bi = b1i[n * 96 + o];
            #pragma unroll
            for (int r = 0; r < 4; ++r) {
                int kh = wr * 16 + quad * 4 + r;
                Sr[kh * 104 + o] = (_Float16)gelu_f(sr[j][r] + br);
                Si[kh * 104 + o] = (_Float16)gelu_f(si[j][r] + bi);
            }
        }
    }
    __syncthreads();

    // stage C: T = shrink(S @ W2 + b2) -> transposed T2T[o][kh] (alias XT)
    {
        float4v tr[3], ti[3];
        #pragma unroll
        for (int j = 0; j < 3; ++j) { float4v z = {0,0,0,0}; tr[j] = z; ti[j] = z; }
        #pragma unroll
        for (int kc = 0; kc < 3; ++kc) {
            half8 ar = *(const half8*)&Sr[(wr * 16 + lr) * 104 + kc * 32 + quad * 8];
            half8 ai = *(const half8*)&Si[(wr * 16 + lr) * 104 + kc * 32 + quad * 8];
            half8 ain = -ai;
            #pragma unroll
            for (int j = 0; j < 3; ++j) {
                int o = wc * 48 + j * 16 + lr;
                half8 br = *(const half8*)&w2r[o * 96 + kc * 32 + quad * 8];
                half8 bi = *(const half8*)&w2i[o * 96 + kc * 32 + quad * 8];
                tr[j] = __builtin_amdgcn_mfma_f32_16x16x32_f16(ar,  br, tr[j], 0, 0, 0);
                tr[j] = __builtin_amdgcn_mfma_f32_16x16x32_f16(ain, bi, tr[j], 0, 0, 0);
                ti[j] = __builtin_amdgcn_mfma_f32_16x16x32_f16(ai,  br, ti[j], 0, 0, 0);
                ti[j] = __builtin_amdgcn_mfma_f32_16x16x32_f16(ar,  bi, ti[j], 0, 0, 0);
            }
        }
        #pragma unroll
        for (int j = 0; j < 3; ++j) {
            int o = wc * 48 + j * 16 + lr;
            float br = b2r[n * 96 + o], bi = b2i[n * 96 + o];
            #pragma unroll
            for (int r = 0; r < 4; ++r) {
                int kh = wr * 16 + quad * 4 + r;
                XTr[o * 40 + kh] = (_Float16)shrink_f(tr[j][r] + br);
                XTi[o * 40 + kh] = (_Float16)shrink_f(ti[j][r] + bi);
            }
        }
    }
    __syncthreads();

    // stage D: Y[h][c] = IDFT_h(T2) -> Zr/Zi as [h][c] pad104
    {
        float4v yr[3], yi[3];
        #pragma unroll
        for (int j = 0; j < 3; ++j) { float4v z = {0,0,0,0}; yr[j] = z; yi[j] = z; }
        #pragma unroll
        for (int j = 0; j < 3; ++j) {
            int c = wc * 48 + j * 16 + lr;
            half8 t2r = *(const half8*)&XTr[c * 40 + quad * 8];
            half8 t2i = *(const half8*)&XTi[c * 40 + quad * 8];
            yr[j] = __builtin_amdgcn_mfma_f32_16x16x32_f16(eC,  t2r, yr[j], 0, 0, 0);
            yr[j] = __builtin_amdgcn_mfma_f32_16x16x32_f16(eSn, t2i, yr[j], 0, 0, 0);
            yi[j] = __builtin_amdgcn_mfma_f32_16x16x32_f16(eC,  t2i, yi[j], 0, 0, 0);
            yi[j] = __builtin_amdgcn_mfma_f32_16x16x32_f16(eS,  t2r, yi[j], 0, 0, 0);
        }
        #pragma unroll
        for (int j = 0; j < 3; ++j) {
            int c = wc * 48 + j * 16 + lr;
            #pragma unroll
            for (int r = 0; r < 4; ++r) {
                int h = wr * 16 + quad * 4 + r;
                Zr[h * 104 + c] = (_Float16)yr[j][r];
                Zi[h * 104 + c] = (_Float16)yi[j][r];
            }
        }
    }
    __syncthreads();

    // vector store back (in-place)
    for (int i = tid; i < 384; i += 256) {
        int h = i / 12, cc = (i % 12) * 8;
        half8 vr = *(const half8*)&Zr[h * 104 + cc];
        half8 vi = *(const half8*)&Zi[h * 104 + cc];
        *(half8*)(Xr + base + (size_t)h * 768 + cc) = vr;
        *(half8*)(Xi + base + (size_t)h * 768 + cc) = vi;
    }
}

// ---------------- f32 -> f16 elementwise (vectorized x4) ----------------
__global__ __launch_bounds__(256) void cvt_f16(const float* __restrict__ in,
        _Float16* __restrict__ out)
{
    int i = blockIdx.x * 256 + threadIdx.x;
    float4 v = ((const float4*)in)[i];
    half4v o;
    o.x = (_Float16)v.x; o.y = (_Float16)v.y; o.z = (_Float16)v.z; o.w = (_Float16)v.w;
    ((half4v*)out)[i] = o;
}

// ---------------- f32 [K][N] -> f16 [N][K] transpose ----------------
__global__ __launch_bounds__(256) void cvt_transpose(const float* __restrict__ in,
        _Float16* __restrict__ out, int K, int N)
{
    __shared__ float tile[32][33];
    int kb = blockIdx.x * 32, nb = blockIdx.y * 32;
    int tx = threadIdx.x & 31, ty = threadIdx.x >> 5;
    #pragma unroll
    for (int r = 0; r < 32; r += 8)
        tile[ty + r][tx] = in[(size_t)(kb + ty + r) * N + nb + tx];
    __syncthreads();
    #pragma unroll
    for (int r = 0; r < 32; r += 8)
        out[(size_t)(nb + ty + r) * K + kb + tx] = (_Float16)tile[tx][ty + r];
}

// ---------------- fp16 MFMA GEMM, depth-3 counted-vmcnt pipeline, 2D-XCD swizzle ----------------
// OUT_MODE: 1 = f16, 3 = f32 pixel-shuffle scatter,
//           4 = f16 + fused forward W-DFT epilogue (fc2: writes XR/XI [b,kw,h,c])
// K-loop: 4 LDS buffers; iter t issues stage(t+3), waits vmcnt(3*LPT) (tile t landed,
// t+1..t+3 in flight), raw barrier, ds_read+MFMA, fence+barrier (protects buffer reuse
// by iter t+1's stage of tile t+4 into buf[t&3]). Epilogue drains 2L -> L -> 0.
template<int BN, int OUT_MODE, int ACT>
__global__ __launch_bounds__(256) void gemm_h(const _Float16* __restrict__ A,
        const _Float16* __restrict__ Bt, const float* __restrict__ bias,
        const float* __restrict__ pos, float* __restrict__ C32,
        _Float16* __restrict__ C16, _Float16* __restrict__ XR,
        _Float16* __restrict__ XI, int M, int N, int K, int f_idx)
{
    constexpr int WN  = BN / 2;
    constexpr int FN  = WN / 16;
    constexpr int NBJ = BN / 64;
    constexpr int LPT = 2 + NBJ;          // vmem loads per thread per K-tile
    __shared__ _Float16 Al[4][128 * 32];
    __shared__ _Float16 Bl[4][BN * 32];

    const int tid  = threadIdx.x;
    const int wave = tid >> 6;
    const int lane = tid & 63;
    const int wr   = wave >> 1;
    const int wc   = wave & 1;
    const int lr   = lane & 15;
    const int quad = lane >> 4;

    // XCD swizzle: prefer 2D (4 row-groups x 2 col-groups -> per-XCD A+B fits 4MB L2)
    const int gx = gridDim.x, gy = gridDim.y, nbk = gx * gy;
    int bx = blockIdx.x, by = blockIdx.y;
    if (!(gy & 3) && !(gx & 1)) {
        int id = by * gx + bx;
        int xcd = id & 7, j = id >> 3;
        int cols = gx >> 1;
        int rows = gy >> 2;
        int jr = j / cols, jc = j % cols;
        by = (xcd >> 1) * rows + jr;
        bx = (xcd & 1) * cols + jc;
    } else if (!(nbk & 7)) {
        int id  = by * gx + bx;
        int id2 = (id & 7) * (nbk >> 3) + (id >> 3);
        by = id2 / gx; bx = id2 % gx;
    }
    const int row0 = by * 128;
    const int col0 = bx * BN;

    const int srow = lane >> 2;
    const int skof = (lane & 3) * 8;

    auto stage = [&](int b, int kt) {
        const int k0 = kt << 5;
        #pragma unroll
        for (int j = 0; j < 2; ++j)
            async16(A + (size_t)(row0 + j * 64 + wave * 16 + srow) * K + k0 + skof,
                    &Al[b][(j * 64 + wave * 16) * 32]);
        #pragma unroll
        for (int j = 0; j < NBJ; ++j)
            async16(Bt + (size_t)(col0 + j * 64 + wave * 16 + srow) * K + k0 + skof,
                    &Bl[b][(j * 64 + wave * 16) * 32]);
    };

    float4v acc[4][FN];
    #pragma unroll
    for (int i = 0; i < 4; ++i)
        #pragma unroll
        for (int j = 0; j < FN; ++j) {
            float4v z = {0.f, 0.f, 0.f, 0.f};
            acc[i][j] = z;
        }

    auto compute = [&](int cb) {
        half8 af[4], bf[FN];
        #pragma unroll
        for (int i = 0; i < 4; ++i)
            af[i] = *(const half8*)&Al[cb][(wr * 64 + i * 16 + lr) * 32 + quad * 8];
        #pragma unroll
        for (int j = 0; j < FN; ++j)
            bf[j] = *(const half8*)&Bl[cb][(wc * WN + j * 16 + lr) * 32 + quad * 8];
        #pragma unroll
        for (int i = 0; i < 4; ++i)
            #pragma unroll
            for (int j = 0; j < FN; ++j)
                acc[i][j] = __builtin_amdgcn_mfma_f32_16x16x32_f16(af[i], bf[j], acc[i][j], 0, 0, 0);
    };

    const int KT = K >> 5;                // K >= 768 -> KT >= 24 (always > 4)
    stage(0, 0); stage(1, 1); stage(2, 2);
    int kt = 0;
    for (; kt < KT - 3; ++kt) {
        stage((kt + 3) & 3, kt + 3);
        if constexpr (LPT == 4) asm volatile("s_waitcnt vmcnt(12)" ::: "memory");
        else                    asm volatile("s_waitcnt vmcnt(9)"  ::: "memory");
        __builtin_amdgcn_s_barrier();
        compute(kt & 3);
        asm volatile("" ::: "memory");
        __builtin_amdgcn_s_barrier();
    }
    // tail: 3 tiles in flight, no more staging; drain 2L -> L -> 0
    if constexpr (LPT == 4) asm volatile("s_waitcnt vmcnt(8)" ::: "memory");
    else                    asm volatile("s_waitcnt vmcnt(6)" ::: "memory");
    __builtin_amdgcn_s_barrier();
    compute(kt & 3); ++kt;
    asm volatile("" ::: "memory");
    __builtin_amdgcn_s_barrier();
    if constexpr (LPT == 4) asm volatile("s_waitcnt vmcnt(4)" ::: "memory");
    else                    asm volatile("s_waitcnt vmcnt(3)" ::: "memory");
    __builtin_amdgcn_s_barrier();
    compute(kt & 3); ++kt;
    asm volatile("" ::: "memory");
    __builtin_amdgcn_s_barrier();
    asm volatile("s_waitcnt vmcnt(0)" ::: "memory");
    __builtin_amdgcn_s_barrier();
    compute(kt & 3);

    if constexpr (OUT_MODE == 4) {
        // fc2 epilogue: f16 write + stage tile + fused forward W-DFT
        __shared__ alignas(16) _Float16 Tl[4 * 64 * 32];   // [h][c][w]
        __shared__ alignas(16) _Float16 ECl[1024], ESl[1024];
        for (int i = tid; i < 1024; i += 256) {
            int kw = i >> 5, w = i & 31;
            float a = ((kw * w) & 31) * STEP32;
            ECl[i] = (_Float16)(cosf(a) * 0.03125f);
            ESl[i] = (_Float16)(-sinf(a) * 0.03125f);
        }
        #pragma unroll
        for (int j = 0; j < FN; ++j) {
            int col = col0 + wc * WN + j * 16 + lr;
            float bj = bias[col];
            #pragma unroll
            for (int i = 0; i < 4; ++i) {
                int row = row0 + wr * 64 + i * 16 + quad * 4;
                #pragma unroll
                for (int r = 0; r < 4; ++r) {
                    float v = acc[i][j][r] + bj;
                    size_t gi = (size_t)(row + r) * N + col;
                    C16[gi] = (_Float16)v;
                    int lrow = row + r - row0;
                    Tl[(((lrow >> 5) * 64) + (col - col0)) * 32 + (lrow & 31)] = (_Float16)v;
                }
            }
        }
        __syncthreads();
        // per-wave h-row DFT: X[kw][c] = E @ T   (wave = local h)
        const int b  = row0 >> 10;
        const int hp = ((row0 >> 5) & 31) + wave;
        half8 eC0 = *(const half8*)&ECl[lr * 32 + quad * 8];
        half8 eC1 = *(const half8*)&ECl[(16 + lr) * 32 + quad * 8];
        half8 eS0 = *(const half8*)&ESl[lr * 32 + quad * 8];
        half8 eS1 = *(const half8*)&ESl[(16 + lr) * 32 + quad * 8];
        float4v xr[2][4], xi[2][4];
        #pragma unroll
        for (int m = 0; m < 2; ++m)
            #pragma unroll
            for (int nj = 0; nj < 4; ++nj) {
                float4v z = {0.f, 0.f, 0.f, 0.f};
                xr[m][nj] = z; xi[m][nj] = z;
            }
        #pragma unroll
        for (int nj = 0; nj < 4; ++nj) {
            half8 tb = *(const half8*)&Tl[((wave * 64) + nj * 16 + lr) * 32 + quad * 8];
            xr[0][nj] = __builtin_amdgcn_mfma_f32_16x16x32_f16(eC0, tb, xr[0][nj], 0, 0, 0);
            xr[1][nj] = __builtin_amdgcn_mfma_f32_16x16x32_f16(eC1, tb, xr[1][nj], 0, 0, 0);
            xi[0][nj] = __builtin_amdgcn_mfma_f32_16x16x32_f16(eS0, tb, xi[0][nj], 0, 0, 0);
            xi[1][nj] = __builtin_amdgcn_mfma_f32_16x16x32_f16(eS1, tb, xi[1][nj], 0, 0, 0);
        }
        #pragma unroll
        for (int m = 0; m < 2; ++m)
            #pragma unroll
            for (int r = 0; r < 4; ++r) {
                int kw = m * 16 + quad * 4 + r;
                if (kw < 17) {
                    #pragma unroll
                    for (int nj = 0; nj < 4; ++nj) {
                        int c = col0 + nj * 16 + lr;
                        size_t g = ((size_t)(b * 17 + kw) * 32 + hp) * 768 + c;
                        XR[g] = (_Float16)xr[m][nj][r];
                        XI[g] = (_Float16)xi[m][nj][r];
                    }
                }
            }
    } else {
        #pragma unroll
        for (int j = 0; j < FN; ++j) {
            int col = col0 + wc * WN + j * 16 + lr;
            float bj = bias[col];
            #pragma unroll
            for (int i = 0; i < 4; ++i) {
                int row = row0 + wr * 64 + i * 16 + quad * 4;
                #pragma unroll
                for (int r = 0; r < 4; ++r) {
                    float v = acc[i][j][r] + bj;
                    if (pos) v += pos[(size_t)((row + r) & 1023) * N + col];
                    if (ACT) v = gelu_f(v);
                    if (OUT_MODE == 3) {
                        int rowv = row + r;
                        int bq = rowv >> 10, hp = (rowv >> 5) & 31, wp = rowv & 31;
                        int p = col >> 3, q = col & 7;
                        C32[(((size_t)(bq * 256 + hp * 8 + p)) * 256 + wp * 8 + q) * 4 + f_idx] = v;
                    } else {
                        C16[(size_t)(row + r) * N + col] = (_Float16)v;
                    }
                }
            }
        }
    }
}

// ---------------- launch ----------------
extern "C" void kernel_launch(void* const* d_in, const int* in_sizes, int n_in,
                              void* d_out, int out_size, void* d_ws, size_t ws_size,
                              hipStream_t stream) {
    const float* x        = (const float*)d_in[0];
    const float* grd      = (const float*)d_in[1];
    const float* conv_w   = (const float*)d_in[2];
    const float* conv_b   = (const float*)d_in[3];
    const float* pos_emb  = (const float*)d_in[4];
    const float* w1       = (const float*)d_in[5];
    const float* b1       = (const float*)d_in[6];
    const float* w2       = (const float*)d_in[7];
    const float* b2       = (const float*)d_in[8];
    const float* fc1_w    = (const float*)d_in[9];
    const float* fc1_b    = (const float*)d_in[10];
    const float* fc2_w    = (const float*)d_in[11];
    const float* fc2_b    = (const float*)d_in[12];
    const float* head_w1  = (const float*)d_in[13];
    const float* head_b1  = (const float*)d_in[14];
    const float* head_w2  = (const float*)d_in[15];
    const float* head_b2  = (const float*)d_in[16];
    float* out = (float*)d_out;
    float* ws  = (float*)d_ws;

    // ---- workspace layout, sizes in float units ----
    float* pf = ws;
    _Float16* t_h     = (_Float16*)pf; pf += 1572864;   // 4096x768 f16 (residual state)
    _Float16* Wsp     = (_Float16*)pf; pf += 589824;    // 128x9216 f16 spectral weights
    _Float16* h1t     = (_Float16*)pf; pf += 589824;    // [1536][768] f16
    _Float16* h2t     = (_Float16*)pf; pf += 49152;     // [64][1536] f16
    _Float16* convw_h = (_Float16*)pf; pf += 294912;    // 768x768 f16 (prepass only)
    float* alias    = pf;              pf += 6291456;   // hid_h 4096x3072 f16
    _Float16* hid_h = (_Float16*)alias;
    _Float16* WtAll = (_Float16*)pf;   pf += 9437184;   // 8 x [N][K] fc weights f16
    // fallback xa inside alias (hid dead when xa live); full mode: dedicated xa after WtAll
    _Float16* xa_r_fb = (_Float16*)alias;
    _Float16* xa_i_fb = (_Float16*)(alias + 835584);
    _Float16* xa_r_fu = (_Float16*)pf;                  // +835,584 f
    _Float16* xa_i_fu = (_Float16*)(pf + 835584);       // +835,584 f
    size_t full_total = (size_t)(pf - ws) + 1671168;    // 20,496,384 f = 82.0 MB
    bool full = ws_size >= full_total * 4ull;
    _Float16* xa_r = full ? xa_r_fu : xa_r_fb;
    _Float16* xa_i = full ? xa_i_fu : xa_i_fb;
    _Float16* A_h  = (_Float16*)alias;                  // prepass-only (gather input, dead after)

    // ---- prepass ----
    prep_specw<<<dim3(128), 256, 0, stream>>>(w1, w2, Wsp);
    cvt_f16<<<dim3(576), 256, 0, stream>>>(conv_w, convw_h);
    cvt_transpose<<<dim3(24, 48), 256, 0, stream>>>(head_w1, h1t, 768, 1536);
    cvt_transpose<<<dim3(48, 2), 256, 0, stream>>>(head_w2, h2t, 1536, 64);
    for (int d = 0; d < 4; ++d) {
        cvt_transpose<<<dim3(24, 96), 256, 0, stream>>>(
            fc1_w + (size_t)d * 2359296, WtAll + (size_t)(2 * d) * 2359296, 768, 3072);
        cvt_transpose<<<dim3(96, 24), 256, 0, stream>>>(
            fc2_w + (size_t)d * 2359296, WtAll + (size_t)(2 * d + 1) * 2359296, 3072, 768);
    }
    gather_patch<<<dim3(12288), 256, 0, stream>>>(x, grd, A_h);
    gemm_h<128, 1, 0><<<dim3(6, 32), 256, 0, stream>>>(
        A_h, convw_h, conv_b, pos_emb, nullptr, t_h, nullptr, nullptr, 4096, 768, 768, 0);
    dft_fwd_w<<<dim3(128, 3), 256, 0, stream>>>(t_h, xa_r, xa_i);

    for (int f = 0; f < 4; ++f) {
        for (int d = 0; d < 4; ++d) {
            // fused H-DFT + complex MLP + H-IDFT (in-place on xa)
            spec_fused<<<dim3(68, 8), 256, 0, stream>>>(
                xa_r, xa_i,
                Wsp + (size_t)(d * 4 + 0) * 73728, Wsp + (size_t)(d * 4 + 1) * 73728,
                Wsp + (size_t)(d * 4 + 2) * 73728, Wsp + (size_t)(d * 4 + 3) * 73728,
                b1 + d * 1536, b1 + d * 1536 + 768,
                b2 + d * 1536, b2 + d * 1536 + 768);
            // irfft2 W-pass + f16 residual (in place on t_h)
            dft_inv_w<<<dim3(128, 3), 256, 0, stream>>>(xa_r, xa_i, t_h);
            // channel MLP
            gemm_h<128, 1, 1><<<dim3(24, 32), 256, 0, stream>>>(
                t_h, WtAll + (size_t)(2 * d) * 2359296, fc1_b + d * 3072,
                nullptr, nullptr, hid_h, nullptr, nullptr, 4096, 3072, 768, 0);
            if (full) {
                // fc2 + fused forward W-DFT (seeds xa for the next spectral block)
                gemm_h<64, 4, 0><<<dim3(12, 32), 256, 0, stream>>>(
                    hid_h, WtAll + (size_t)(2 * d + 1) * 2359296, fc2_b + d * 768,
                    nullptr, nullptr, t_h, xa_r, xa_i, 4096, 768, 3072, 0);
            } else {
                gemm_h<64, 1, 0><<<dim3(12, 32), 256, 0, stream>>>(
                    hid_h, WtAll + (size_t)(2 * d + 1) * 2359296, fc2_b + d * 768,
                    nullptr, nullptr, t_h, nullptr, nullptr, 4096, 768, 3072, 0);
                dft_fwd_w<<<dim3(128, 3), 256, 0, stream>>>(t_h, xa_r, xa_i);
            }
        }
        // head on current state (t_h from fc2)
        gemm_h<128, 1, 1><<<dim3(12, 32), 256, 0, stream>>>(
            t_h, h1t, head_b1, nullptr, nullptr, hid_h, nullptr, nullptr, 4096, 1536, 768, 0);
        gemm_h<64, 3, 0><<<dim3(1, 32), 256, 0, stream>>>(
            hid_h, h2t, head_b2, nullptr, out, nullptr, nullptr, nullptr, 4096, 64, 1536, f);
    }
}

// Round 2
// 2495.357 us; speedup vs baseline: 1.0962x; 1.0962x over previous
//
#include <hip/hip_runtime.h>
#include <hip/hip_bf16.h>
#include <math.h>

// ---------------- static config ----------------
// B=4, H=W=256, TIN=10, F=4, P=8, CIN=12, E=768, NB=8, BS=96,
// HP=WP=32, MID=3072, DEPTH=4, LAM=0.01, WF=17, TOK=4096, POS=B*32*17=2176
// Spectral layout: X[((b*17+kw)*32 + h)*768 + c]   (h-rows contiguous per kw)
// R10: gemm_h depth-3 counted-vmcnt (neutral; kept for conv/fc2/head2).
// R11: new gemm256 for fc1/head1 -- 256x192 tile, 8 waves (128x48/wave),
//   BK=64, 2-buffer LDS (112KB), 2 barriers + vmcnt(7)/tile (never 0 mid-loop),
//   XOR-swizzled LDS (chunk ^= row&7, applied to BOTH gload_lds source and
//   ds_read addr), setprio around MFMA. fc1 grid 16x16 = 256 blocks = 1/CU.

typedef __attribute__((ext_vector_type(8))) _Float16 half8;
typedef __attribute__((ext_vector_type(4))) _Float16 half4v;
typedef __attribute__((ext_vector_type(4))) float float4v;

__device__ __forceinline__ float gelu_f(float v) {
    return 0.5f * v * (1.0f + erff(v * 0.70710678118654752f));
}
__device__ __forceinline__ float shrink_f(float v) {
    return (v > 0.01f) ? (v - 0.01f) : ((v < -0.01f) ? (v + 0.01f) : 0.0f);
}

#define STEP32 0.19634954084936207f  // 2*pi/32

// async 16B global->LDS (lds dest wave-uniform; HW adds lane*16)
__device__ __forceinline__ void async16(const void* g, void* l) {
    __builtin_amdgcn_global_load_lds(
        (const __attribute__((address_space(1))) unsigned int*)g,
        (__attribute__((address_space(3))) unsigned int*)l, 16, 0, 0);
}

// ---------------- gather patches into A_h [4096][768] f16 ----------------
__global__ __launch_bounds__(256) void gather_patch(const float* __restrict__ x,
        const float* __restrict__ grd, _Float16* __restrict__ A)
{
    int idx = blockIdx.x * 256 + threadIdx.x;
    int j   = idx % 768;
    int tok = idx / 768;
    int c = j >> 6, p = (j >> 3) & 7, q = j & 7;
    int wp = tok & 31, hp = (tok >> 5) & 31, b = tok >> 10;
    int hh = hp * 8 + p, ww = wp * 8 + q;
    float v;
    if (c < 10) v = x[((b * 256 + hh) * 256 + ww) * 10 + c];
    else        v = grd[((b * 256 + hh) * 256 + ww) * 2 + (c - 10)];
    A[idx] = (_Float16)v;
}

// ---------------- forward DFT along W (f16 in -> 17 complex f16), scale 1/32 ----------------
// prepass + fallback path. out layout [b,kw,h,c]
__global__ __launch_bounds__(256) void dft_fwd_w(const _Float16* __restrict__ th,
        _Float16* __restrict__ Xr, _Float16* __restrict__ Xi)
{
    __shared__ float2 lut[32];
    int bh = blockIdx.x;            // b*32 + h
    int tid = threadIdx.x;
    if (tid < 32) { float a = tid * STEP32; lut[tid] = make_float2(cosf(a), sinf(a)); }
    __syncthreads();
    int b = bh >> 5, h = bh & 31;
    int c = blockIdx.y * 256 + tid;
    float v[32];
    #pragma unroll
    for (int w = 0; w < 32; ++w) v[w] = (float)th[(bh * 32 + w) * 768 + c];
    for (int kw = 0; kw <= 16; ++kw) {
        float ar = 0.f, ai = 0.f;
        #pragma unroll
        for (int w = 0; w < 32; ++w) {
            float2 cs = lut[(kw * w) & 31];
            ar += v[w] * cs.x;
            ai -= v[w] * cs.y;
        }
        size_t g = ((size_t)(b * 17 + kw) * 32 + h) * 768 + c;
        Xr[g] = (_Float16)(ar * 0.03125f);
        Xi[g] = (_Float16)(ai * 0.03125f);
    }
}

// ---------------- inverse DFT along W (f16 in, [b,kw,h,c]) + f16 residual in-place ----------------
__global__ __launch_bounds__(256) void dft_inv_w(const _Float16* __restrict__ Yr,
        const _Float16* __restrict__ Yi, _Float16* __restrict__ th)
{
    __shared__ float2 lut[32];
    int bh = blockIdx.x;
    int tid = threadIdx.x;
    if (tid < 32) { float a = tid * STEP32; lut[tid] = make_float2(cosf(a), sinf(a)); }
    __syncthreads();
    int b = bh >> 5, h = bh & 31;
    int c = blockIdx.y * 256 + tid;
    float yr[17], yi[16];
    #pragma unroll
    for (int k = 0; k <= 16; ++k) yr[k] = (float)Yr[((size_t)(b * 17 + k) * 32 + h) * 768 + c];
    #pragma unroll
    for (int k = 1; k <= 15; ++k) yi[k] = (float)Yi[((size_t)(b * 17 + k) * 32 + h) * 768 + c];
    for (int w = 0; w < 32; ++w) {
        float val = yr[0] + ((w & 1) ? -yr[16] : yr[16]);
        #pragma unroll
        for (int k = 1; k <= 15; ++k) {
            float2 cs = lut[(k * w) & 31];
            val += 2.f * (yr[k] * cs.x - yi[k] * cs.y);
        }
        int gi = (bh * 32 + w) * 768 + c;
        th[gi] = (_Float16)(val * 0.03125f + (float)th[gi]);
    }
}

// ---------------- spectral weight prep: [i][o] fp32 -> [o][i] f16, 128 matrices ----------------
__global__ __launch_bounds__(256) void prep_specw(const float* __restrict__ w1,
        const float* __restrict__ w2, _Float16* __restrict__ out)
{
    __shared__ float tile[96][97];
    int mid = blockIdx.x;
    int n  = mid & 7;
    int ri = (mid >> 3) & 1;
    int l  = (mid >> 4) & 1;
    int d  = mid >> 5;
    const float* src = (l ? w2 : w1) + ((size_t)(d * 2 + ri) * 8 + n) * 9216;
    for (int idx = threadIdx.x; idx < 9216; idx += 256)
        tile[idx / 96][idx % 96] = src[idx];
    __syncthreads();
    _Float16* dst = out + (size_t)mid * 9216;
    for (int idx = threadIdx.x; idx < 9216; idx += 256)
        dst[idx] = (_Float16)tile[idx % 96][idx / 96];   // dst[o][i] = src[i][o]
}

// ---------------- fused spectral: H-DFT -> spec1(gelu) -> spec2(shrink) -> H-IDFT ----------------
// IN-PLACE on X ([b,kw,h,c] layout). grid (68 = b*17+kw, 8 = n); 256 thr = 4 waves.
__global__ __launch_bounds__(256) void spec_fused(
        _Float16* __restrict__ Xr, _Float16* __restrict__ Xi,
        const _Float16* __restrict__ W1r, const _Float16* __restrict__ W1i,
        const _Float16* __restrict__ W2r, const _Float16* __restrict__ W2i,
        const float* __restrict__ b1r, const float* __restrict__ b1i,
        const float* __restrict__ b2r, const float* __restrict__ b2i)
{
    __shared__ alignas(16) _Float16 Ec[1024], Es[1024];       // [m][k] twiddle 32x32
    __shared__ alignas(16) _Float16 XTr[3840], XTi[3840];     // [c][h] pad40; stage C: [o][kh]
    __shared__ alignas(16) _Float16 Zr[3328], Zi[3328];       // [kh][c] pad104; stage D out [h][c]
    __shared__ alignas(16) _Float16 Sr[3328], Si[3328];       // [kh][o] pad104

    const int bk = blockIdx.x;       // b*17 + kw
    const int n  = blockIdx.y;
    const int tid = threadIdx.x;
    const int wave = tid >> 6, lane = tid & 63;
    const int wr = wave >> 1, wc = wave & 1;
    const int lr = lane & 15, quad = lane >> 4;
    const size_t base = (size_t)bk * 24576 + n * 96;    // + h*768 + c

    for (int i = tid; i < 1024; i += 256) {
        int kh = i >> 5, h = i & 31;
        float a = ((kh * h) & 31) * STEP32;
        Ec[i] = (_Float16)cosf(a);
        Es[i] = (_Float16)sinf(a);
    }
    // vector load -> LDS transpose [c][h]
    for (int i = tid; i < 384; i += 256) {
        int h = i / 12, cc = (i % 12) * 8;
        half8 vr = *(const half8*)(Xr + base + (size_t)h * 768 + cc);
        half8 vi = *(const half8*)(Xi + base + (size_t)h * 768 + cc);
        #pragma unroll
        for (int e = 0; e < 8; ++e) {
            XTr[(cc + e) * 40 + h] = vr[e];
            XTi[(cc + e) * 40 + h] = vi[e];
        }
    }
    __syncthreads();

    const _Float16* w1r = W1r + (size_t)n * 9216;
    const _Float16* w1i = W1i + (size_t)n * 9216;
    const _Float16* w2r = W2r + (size_t)n * 9216;
    const _Float16* w2i = W2i + (size_t)n * 9216;

    half8 eC = *(const half8*)&Ec[(wr * 16 + lr) * 32 + quad * 8];
    half8 eS = *(const half8*)&Es[(wr * 16 + lr) * 32 + quad * 8];
    half8 eSn = -eS;

    // stage A: Z[kh][c] = DFT_h(X)
    {
        float4v zr[3], zi[3];
        #pragma unroll
        for (int j = 0; j < 3; ++j) { float4v z = {0,0,0,0}; zr[j] = z; zi[j] = z; }
        #pragma unroll
        for (int j = 0; j < 3; ++j) {
            int c = wc * 48 + j * 16 + lr;
            half8 xr = *(const half8*)&XTr[c * 40 + quad * 8];
            half8 xi = *(const half8*)&XTi[c * 40 + quad * 8];
            zr[j] = __builtin_amdgcn_mfma_f32_16x16x32_f16(eC,  xr, zr[j], 0, 0, 0);
            zr[j] = __builtin_amdgcn_mfma_f32_16x16x32_f16(eS,  xi, zr[j], 0, 0, 0);
            zi[j] = __builtin_amdgcn_mfma_f32_16x16x32_f16(eC,  xi, zi[j], 0, 0, 0);
            zi[j] = __builtin_amdgcn_mfma_f32_16x16x32_f16(eSn, xr, zi[j], 0, 0, 0);
        }
        #pragma unroll
        for (int j = 0; j < 3; ++j) {
            int c = wc * 48 + j * 16 + lr;
            #pragma unroll
            for (int r = 0; r < 4; ++r) {
                int kh = wr * 16 + quad * 4 + r;
                Zr[kh * 104 + c] = (_Float16)zr[j][r];
                Zi[kh * 104 + c] = (_Float16)zi[j][r];
            }
        }
    }
    __syncthreads();

    // stage B: S = gelu(Z @ W1 + b1)
    {
        float4v sr[3], si[3];
        #pragma unroll
        for (int j = 0; j < 3; ++j) { float4v z = {0,0,0,0}; sr[j] = z; si[j] = z; }
        #pragma unroll
        for (int kc = 0; kc < 3; ++kc) {
            half8 ar = *(const half8*)&Zr[(wr * 16 + lr) * 104 + kc * 32 + quad * 8];
            half8 ai = *(const half8*)&Zi[(wr * 16 + lr) * 104 + kc * 32 + quad * 8];
            half8 ain = -ai;
            #pragma unroll
            for (int j = 0; j < 3; ++j) {
                int o = wc * 48 + j * 16 + lr;
                half8 br = *(const half8*)&w1r[o * 96 + kc * 32 + quad * 8];
                half8 bi = *(const half8*)&w1i[o * 96 + kc * 32 + quad * 8];
                sr[j] = __builtin_amdgcn_mfma_f32_16x16x32_f16(ar,  br, sr[j], 0, 0, 0);
                sr[j] = __builtin_amdgcn_mfma_f32_16x16x32_f16(ain, bi, sr[j], 0, 0, 0);
                si[j] = __builtin_amdgcn_mfma_f32_16x16x32_f16(ai,  br, si[j], 0, 0, 0);
                si[j] = __builtin_amdgcn_mfma_f32_16x16x32_f16(ar,  bi, si[j], 0, 0, 0);
            }
        }
        #pragma unroll
        for (int j = 0; j < 3; ++j) {
            int o = wc * 48 + j * 16 + lr;
            float br = b1r[n * 96 + o], bi = b1i[n * 96 + o];
            #pragma unroll
            for (int r = 0; r < 4; ++r) {
                int kh = wr * 16 + quad * 4 + r;
                Sr[kh * 104 + o] = (_Float16)gelu_f(sr[j][r] + br);
                Si[kh * 104 + o] = (_Float16)gelu_f(si[j][r] + bi);
            }
        }
    }
    __syncthreads();

    // stage C: T = shrink(S @ W2 + b2) -> transposed T2T[o][kh] (alias XT)
    {
        float4v tr[3], ti[3];
        #pragma unroll
        for (int j = 0; j < 3; ++j) { float4v z = {0,0,0,0}; tr[j] = z; ti[j] = z; }
        #pragma unroll
        for (int kc = 0; kc < 3; ++kc) {
            half8 ar = *(const half8*)&Sr[(wr * 16 + lr) * 104 + kc * 32 + quad * 8];
            half8 ai = *(const half8*)&Si[(wr * 16 + lr) * 104 + kc * 32 + quad * 8];
            half8 ain = -ai;
            #pragma unroll
            for (int j = 0; j < 3; ++j) {
                int o = wc * 48 + j * 16 + lr;
                half8 br = *(const half8*)&w2r[o * 96 + kc * 32 + quad * 8];
                half8 bi = *(const half8*)&w2i[o * 96 + kc * 32 + quad * 8];
                tr[j] = __builtin_amdgcn_mfma_f32_16x16x32_f16(ar,  br, tr[j], 0, 0, 0);
                tr[j] = __builtin_amdgcn_mfma_f32_16x16x32_f16(ain, bi, tr[j], 0, 0, 0);
                ti[j] = __builtin_amdgcn_mfma_f32_16x16x32_f16(ai,  br, ti[j], 0, 0, 0);
                ti[j] = __builtin_amdgcn_mfma_f32_16x16x32_f16(ar,  bi, ti[j], 0, 0, 0);
            }
        }
        #pragma unroll
        for (int j = 0; j < 3; ++j) {
            int o = wc * 48 + j * 16 + lr;
            float br = b2r[n * 96 + o], bi = b2i[n * 96 + o];
            #pragma unroll
            for (int r = 0; r < 4; ++r) {
                int kh = wr * 16 + quad * 4 + r;
                XTr[o * 40 + kh] = (_Float16)shrink_f(tr[j][r] + br);
                XTi[o * 40 + kh] = (_Float16)shrink_f(ti[j][r] + bi);
            }
        }
    }
    __syncthreads();

    // stage D: Y[h][c] = IDFT_h(T2) -> Zr/Zi as [h][c] pad104
    {
        float4v yr[3], yi[3];
        #pragma unroll
        for (int j = 0; j < 3; ++j) { float4v z = {0,0,0,0}; yr[j] = z; yi[j] = z; }
        #pragma unroll
        for (int j = 0; j < 3; ++j) {
            int c = wc * 48 + j * 16 + lr;
            half8 t2r = *(const half8*)&XTr[c * 40 + quad * 8];
            half8 t2i = *(const half8*)&XTi[c * 40 + quad * 8];
            yr[j] = __builtin_amdgcn_mfma_f32_16x16x32_f16(eC,  t2r, yr[j], 0, 0, 0);
            yr[j] = __builtin_amdgcn_mfma_f32_16x16x32_f16(eSn, t2i, yr[j], 0, 0, 0);
            yi[j] = __builtin_amdgcn_mfma_f32_16x16x32_f16(eC,  t2i, yi[j], 0, 0, 0);
            yi[j] = __builtin_amdgcn_mfma_f32_16x16x32_f16(eS,  t2r, yi[j], 0, 0, 0);
        }
        #pragma unroll
        for (int j = 0; j < 3; ++j) {
            int c = wc * 48 + j * 16 + lr;
            #pragma unroll
            for (int r = 0; r < 4; ++r) {
                int h = wr * 16 + quad * 4 + r;
                Zr[h * 104 + c] = (_Float16)yr[j][r];
                Zi[h * 104 + c] = (_Float16)yi[j][r];
            }
        }
    }
    __syncthreads();

    // vector store back (in-place)
    for (int i = tid; i < 384; i += 256) {
        int h = i / 12, cc = (i % 12) * 8;
        half8 vr = *(const half8*)&Zr[h * 104 + cc];
        half8 vi = *(const half8*)&Zi[h * 104 + cc];
        *(half8*)(Xr + base + (size_t)h * 768 + cc) = vr;
        *(half8*)(Xi + base + (size_t)h * 768 + cc) = vi;
    }
}

// ---------------- f32 -> f16 elementwise (vectorized x4) ----------------
__global__ __launch_bounds__(256) void cvt_f16(const float* __restrict__ in,
        _Float16* __restrict__ out)
{
    int i = blockIdx.x * 256 + threadIdx.x;
    float4 v = ((const float4*)in)[i];
    half4v o;
    o.x = (_Float16)v.x; o.y = (_Float16)v.y; o.z = (_Float16)v.z; o.w = (_Float16)v.w;
    ((half4v*)out)[i] = o;
}

// ---------------- f32 [K][N] -> f16 [N][K] transpose ----------------
__global__ __launch_bounds__(256) void cvt_transpose(const float* __restrict__ in,
        _Float16* __restrict__ out, int K, int N)
{
    __shared__ float tile[32][33];
    int kb = blockIdx.x * 32, nb = blockIdx.y * 32;
    int tx = threadIdx.x & 31, ty = threadIdx.x >> 5;
    #pragma unroll
    for (int r = 0; r < 32; r += 8)
        tile[ty + r][tx] = in[(size_t)(kb + ty + r) * N + nb + tx];
    __syncthreads();
    #pragma unroll
    for (int r = 0; r < 32; r += 8)
        out[(size_t)(nb + ty + r) * K + kb + tx] = (_Float16)tile[tx][ty + r];
}

// ---------------- NEW R11: 256x192-tile 8-wave GEMM (fc1 / head1) ----------------
// 8 waves = 2M x 4N, per-wave 128x48 output (8 m-reps x 3 n-reps).
// BK=64, 2 K-tile LDS buffers (A 64KB + B 48KB = 112KB), 1 block/CU.
// Per tile: vmcnt(7) [counted, never 0 mid-loop] -> barrier -> 22 ds_read + 48 MFMA
// -> barrier -> stage tile t+2 into just-freed buffer (full K-tile latency cover).
// LDS rows are 64 halfs = 128B = exact bank wrap -> XOR swizzle chunk^=(row&7),
// applied to BOTH the gload_lds global source and the ds_read address (rule #21).
template<int BN, int ACT>
__global__ __launch_bounds__(512, 2) void gemm256(const _Float16* __restrict__ A,
        const _Float16* __restrict__ Bt, const float* __restrict__ bias,
        _Float16* __restrict__ C16, int M, int N, int K)
{
    constexpr int WN  = BN / 4;           // 48
    constexpr int FN  = WN / 16;          // 3
    constexpr int AU  = 4;                // A: 4 x 64-row units
    constexpr int BU  = BN / 64;          // 3
    __shared__ _Float16 Al[2][256 * 64];
    __shared__ _Float16 Bl[2][BN * 64];

    const int tid  = threadIdx.x;
    const int wave = tid >> 6;            // 0..7
    const int lane = tid & 63;
    const int wr   = wave >> 2;           // 0..1 (M)
    const int wc   = wave & 3;            // 0..3 (N)
    const int lr   = lane & 15;
    const int quad = lane >> 4;

    // XCD swizzle (2D): per-XCD contiguous patch for L2 reuse
    const int gx = gridDim.x, gy = gridDim.y, nbk = gx * gy;
    int bx = blockIdx.x, by = blockIdx.y;
    if (!(gy & 3) && !(gx & 1)) {
        int id = by * gx + bx;
        int xcd = id & 7, j = id >> 3;
        int cols = gx >> 1;
        int rows = gy >> 2;
        int jr = j / cols, jc = j % cols;
        by = (xcd >> 1) * rows + jr;
        bx = (xcd & 1) * cols + jc;
    } else if (!(nbk & 7)) {
        int id  = by * gx + bx;
        int id2 = (id & 7) * (nbk >> 3) + (id >> 3);
        by = id2 / gx; bx = id2 % gx;
    }
    const int row0 = by * 256;
    const int col0 = bx * BN;

    // staging: per load-unit (64 rows x 64 halfs = 8KB), wave w covers rows w*8..w*8+7.
    // lane l: row = l>>3, physical chunk = l&7; source logical chunk = (l&7)^((l>>3)&7).
    const int srow = lane >> 3;
    const int schk = (lane & 7) ^ (srow & 7);
    const _Float16* Ab = A  + (size_t)(row0 + wave * 8 + srow) * K + schk * 8;
    const _Float16* Bb = Bt + (size_t)(col0 + wave * 8 + srow) * K + schk * 8;

    auto stage = [&](int b, int kt) {
        const int k0 = kt * 64;
        #pragma unroll
        for (int u = 0; u < AU; ++u)
            async16(Ab + (size_t)u * 64 * K + k0, &Al[b][(u * 64 + wave * 8) * 64]);
        #pragma unroll
        for (int u = 0; u < BU; ++u)
            async16(Bb + (size_t)u * 64 * K + k0, &Bl[b][(u * 64 + wave * 8) * 64]);
    };

    float4v acc[8][FN];
    #pragma unroll
    for (int m = 0; m < 8; ++m)
        #pragma unroll
        for (int n = 0; n < FN; ++n) {
            float4v z = {0.f, 0.f, 0.f, 0.f};
            acc[m][n] = z;
        }

    auto compute = [&](int cb) {
        #pragma unroll
        for (int ks = 0; ks < 2; ++ks) {
            const int cA = ((ks * 4 + quad) ^ (lr & 7)) * 8;   // swizzled chunk (halfs)
            half8 bf[FN];
            #pragma unroll
            for (int n = 0; n < FN; ++n)
                bf[n] = *(const half8*)&Bl[cb][(wc * WN + n * 16 + lr) * 64 + cA];
            half8 af[8];
            #pragma unroll
            for (int m = 0; m < 8; ++m)
                af[m] = *(const half8*)&Al[cb][(wr * 128 + m * 16 + lr) * 64 + cA];
            __builtin_amdgcn_s_setprio(1);
            #pragma unroll
            for (int m = 0; m < 8; ++m)
                #pragma unroll
                for (int n = 0; n < FN; ++n)
                    acc[m][n] = __builtin_amdgcn_mfma_f32_16x16x32_f16(af[m], bf[n], acc[m][n], 0, 0, 0);
            __builtin_amdgcn_s_setprio(0);
        }
    };

    const int NT = K >> 6;                // K=768 -> 12 tiles
    stage(0, 0);
    stage(1, 1);
    for (int t = 0; t < NT; ++t) {
        // need tile t landed; newest outstanding (if any) are tile t+1's 7 loads
        if (t + 1 < NT) asm volatile("s_waitcnt vmcnt(7)" ::: "memory");
        else            asm volatile("s_waitcnt vmcnt(0)" ::: "memory");
        __builtin_amdgcn_s_barrier();     // all waves' tile-t loads visible
        compute(t & 1);
        __builtin_amdgcn_s_barrier();     // all waves done reading buf[t&1]
        if (t + 2 < NT) stage(t & 1, t + 2);   // prefetch into just-freed buffer
    }

    // epilogue: bias (+GELU) -> f16 store
    #pragma unroll
    for (int n = 0; n < FN; ++n) {
        int col = col0 + wc * WN + n * 16 + lr;
        float bj = bias[col];
        #pragma unroll
        for (int m = 0; m < 8; ++m) {
            int row = row0 + wr * 128 + m * 16 + quad * 4;
            #pragma unroll
            for (int r = 0; r < 4; ++r) {
                float v = acc[m][n][r] + bj;
                if (ACT) v = gelu_f(v);
                C16[(size_t)(row + r) * N + col] = (_Float16)v;
            }
        }
    }
}

// ---------------- fp16 MFMA GEMM, depth-3 counted-vmcnt pipeline, 2D-XCD swizzle ----------------
// OUT_MODE: 1 = f16, 3 = f32 pixel-shuffle scatter,
//           4 = f16 + fused forward W-DFT epilogue (fc2: writes XR/XI [b,kw,h,c])
template<int BN, int OUT_MODE, int ACT>
__global__ __launch_bounds__(256) void gemm_h(const _Float16* __restrict__ A,
        const _Float16* __restrict__ Bt, const float* __restrict__ bias,
        const float* __restrict__ pos, float* __restrict__ C32,
        _Float16* __restrict__ C16, _Float16* __restrict__ XR,
        _Float16* __restrict__ XI, int M, int N, int K, int f_idx)
{
    constexpr int WN  = BN / 2;
    constexpr int FN  = WN / 16;
    constexpr int NBJ = BN / 64;
    constexpr int LPT = 2 + NBJ;          // vmem loads per thread per K-tile
    __shared__ _Float16 Al[4][128 * 32];
    __shared__ _Float16 Bl[4][BN * 32];

    const int tid  = threadIdx.x;
    const int wave = tid >> 6;
    const int lane = tid & 63;
    const int wr   = wave >> 1;
    const int wc   = wave & 1;
    const int lr   = lane & 15;
    const int quad = lane >> 4;

    // XCD swizzle: prefer 2D (4 row-groups x 2 col-groups -> per-XCD A+B fits 4MB L2)
    const int gx = gridDim.x, gy = gridDim.y, nbk = gx * gy;
    int bx = blockIdx.x, by = blockIdx.y;
    if (!(gy & 3) && !(gx & 1)) {
        int id = by * gx + bx;
        int xcd = id & 7, j = id >> 3;
        int cols = gx >> 1;
        int rows = gy >> 2;
        int jr = j / cols, jc = j % cols;
        by = (xcd >> 1) * rows + jr;
        bx = (xcd & 1) * cols + jc;
    } else if (!(nbk & 7)) {
        int id  = by * gx + bx;
        int id2 = (id & 7) * (nbk >> 3) + (id >> 3);
        by = id2 / gx; bx = id2 % gx;
    }
    const int row0 = by * 128;
    const int col0 = bx * BN;

    const int srow = lane >> 2;
    const int skof = (lane & 3) * 8;

    auto stage = [&](int b, int kt) {
        const int k0 = kt << 5;
        #pragma unroll
        for (int j = 0; j < 2; ++j)
            async16(A + (size_t)(row0 + j * 64 + wave * 16 + srow) * K + k0 + skof,
                    &Al[b][(j * 64 + wave * 16) * 32]);
        #pragma unroll
        for (int j = 0; j < NBJ; ++j)
            async16(Bt + (size_t)(col0 + j * 64 + wave * 16 + srow) * K + k0 + skof,
                    &Bl[b][(j * 64 + wave * 16) * 32]);
    };

    float4v acc[4][FN];
    #pragma unroll
    for (int i = 0; i < 4; ++i)
        #pragma unroll
        for (int j = 0; j < FN; ++j) {
            float4v z = {0.f, 0.f, 0.f, 0.f};
            acc[i][j] = z;
        }

    auto compute = [&](int cb) {
        half8 af[4], bf[FN];
        #pragma unroll
        for (int i = 0; i < 4; ++i)
            af[i] = *(const half8*)&Al[cb][(wr * 64 + i * 16 + lr) * 32 + quad * 8];
        #pragma unroll
        for (int j = 0; j < FN; ++j)
            bf[j] = *(const half8*)&Bl[cb][(wc * WN + j * 16 + lr) * 32 + quad * 8];
        #pragma unroll
        for (int i = 0; i < 4; ++i)
            #pragma unroll
            for (int j = 0; j < FN; ++j)
                acc[i][j] = __builtin_amdgcn_mfma_f32_16x16x32_f16(af[i], bf[j], acc[i][j], 0, 0, 0);
    };

    const int KT = K >> 5;                // K >= 768 -> KT >= 24 (always > 4)
    stage(0, 0); stage(1, 1); stage(2, 2);
    int kt = 0;
    for (; kt < KT - 3; ++kt) {
        stage((kt + 3) & 3, kt + 3);
        if constexpr (LPT == 4) asm volatile("s_waitcnt vmcnt(12)" ::: "memory");
        else                    asm volatile("s_waitcnt vmcnt(9)"  ::: "memory");
        __builtin_amdgcn_s_barrier();
        compute(kt & 3);
        asm volatile("" ::: "memory");
        __builtin_amdgcn_s_barrier();
    }
    // tail: 3 tiles in flight, no more staging; drain 2L -> L -> 0
    if constexpr (LPT == 4) asm volatile("s_waitcnt vmcnt(8)" ::: "memory");
    else                    asm volatile("s_waitcnt vmcnt(6)" ::: "memory");
    __builtin_amdgcn_s_barrier();
    compute(kt & 3); ++kt;
    asm volatile("" ::: "memory");
    __builtin_amdgcn_s_barrier();
    if constexpr (LPT == 4) asm volatile("s_waitcnt vmcnt(4)" ::: "memory");
    else                    asm volatile("s_waitcnt vmcnt(3)" ::: "memory");
    __builtin_amdgcn_s_barrier();
    compute(kt & 3); ++kt;
    asm volatile("" ::: "memory");
    __builtin_amdgcn_s_barrier();
    asm volatile("s_waitcnt vmcnt(0)" ::: "memory");
    __builtin_amdgcn_s_barrier();
    compute(kt & 3);

    if constexpr (OUT_MODE == 4) {
        // fc2 epilogue: f16 write + stage tile + fused forward W-DFT
        __shared__ alignas(16) _Float16 Tl[4 * 64 * 32];   // [h][c][w]
        __shared__ alignas(16) _Float16 ECl[1024], ESl[1024];
        for (int i = tid; i < 1024; i += 256) {
            int kw = i >> 5, w = i & 31;
            float a = ((kw * w) & 31) * STEP32;
            ECl[i] = (_Float16)(cosf(a) * 0.03125f);
            ESl[i] = (_Float16)(-sinf(a) * 0.03125f);
        }
        #pragma unroll
        for (int j = 0; j < FN; ++j) {
            int col = col0 + wc * WN + j * 16 + lr;
            float bj = bias[col];
            #pragma unroll
            for (int i = 0; i < 4; ++i) {
                int row = row0 + wr * 64 + i * 16 + quad * 4;
                #pragma unroll
                for (int r = 0; r < 4; ++r) {
                    float v = acc[i][j][r] + bj;
                    size_t gi = (size_t)(row + r) * N + col;
                    C16[gi] = (_Float16)v;
                    int lrow = row + r - row0;
                    Tl[(((lrow >> 5) * 64) + (col - col0)) * 32 + (lrow & 31)] = (_Float16)v;
                }
            }
        }
        __syncthreads();
        // per-wave h-row DFT: X[kw][c] = E @ T   (wave = local h)
        const int b  = row0 >> 10;
        const int hp = ((row0 >> 5) & 31) + wave;
        half8 eC0 = *(const half8*)&ECl[lr * 32 + quad * 8];
        half8 eC1 = *(const half8*)&ECl[(16 + lr) * 32 + quad * 8];
        half8 eS0 = *(const half8*)&ESl[lr * 32 + quad * 8];
        half8 eS1 = *(const half8*)&ESl[(16 + lr) * 32 + quad * 8];
        float4v xr[2][4], xi[2][4];
        #pragma unroll
        for (int m = 0; m < 2; ++m)
            #pragma unroll
            for (int nj = 0; nj < 4; ++nj) {
                float4v z = {0.f, 0.f, 0.f, 0.f};
                xr[m][nj] = z; xi[m][nj] = z;
            }
        #pragma unroll
        for (int nj = 0; nj < 4; ++nj) {
            half8 tb = *(const half8*)&Tl[((wave * 64) + nj * 16 + lr) * 32 + quad * 8];
            xr[0][nj] = __builtin_amdgcn_mfma_f32_16x16x32_f16(eC0, tb, xr[0][nj], 0, 0, 0);
            xr[1][nj] = __builtin_amdgcn_mfma_f32_16x16x32_f16(eC1, tb, xr[1][nj], 0, 0, 0);
            xi[0][nj] = __builtin_amdgcn_mfma_f32_16x16x32_f16(eS0, tb, xi[0][nj], 0, 0, 0);
            xi[1][nj] = __builtin_amdgcn_mfma_f32_16x16x32_f16(eS1, tb, xi[1][nj], 0, 0, 0);
        }
        #pragma unroll
        for (int m = 0; m < 2; ++m)
            #pragma unroll
            for (int r = 0; r < 4; ++r) {
                int kw = m * 16 + quad * 4 + r;
                if (kw < 17) {
                    #pragma unroll
                    for (int nj = 0; nj < 4; ++nj) {
                        int c = col0 + nj * 16 + lr;
                        size_t g = ((size_t)(b * 17 + kw) * 32 + hp) * 768 + c;
                        XR[g] = (_Float16)xr[m][nj][r];
                        XI[g] = (_Float16)xi[m][nj][r];
                    }
                }
            }
    } else {
        #pragma unroll
        for (int j = 0; j < FN; ++j) {
            int col = col0 + wc * WN + j * 16 + lr;
            float bj = bias[col];
            #pragma unroll
            for (int i = 0; i < 4; ++i) {
                int row = row0 + wr * 64 + i * 16 + quad * 4;
                #pragma unroll
                for (int r = 0; r < 4; ++r) {
                    float v = acc[i][j][r] + bj;
                    if (pos) v += pos[(size_t)((row + r) & 1023) * N + col];
                    if (ACT) v = gelu_f(v);
                    if (OUT_MODE == 3) {
                        int rowv = row + r;
                        int bq = rowv >> 10, hp = (rowv >> 5) & 31, wp = rowv & 31;
                        int p = col >> 3, q = col & 7;
                        C32[(((size_t)(bq * 256 + hp * 8 + p)) * 256 + wp * 8 + q) * 4 + f_idx] = v;
                    } else {
                        C16[(size_t)(row + r) * N + col] = (_Float16)v;
                    }
                }
            }
        }
    }
}

// ---------------- launch ----------------
extern "C" void kernel_launch(void* const* d_in, const int* in_sizes, int n_in,
                              void* d_out, int out_size, void* d_ws, size_t ws_size,
                              hipStream_t stream) {
    const float* x        = (const float*)d_in[0];
    const float* grd      = (const float*)d_in[1];
    const float* conv_w   = (const float*)d_in[2];
    const float* conv_b   = (const float*)d_in[3];
    const float* pos_emb  = (const float*)d_in[4];
    const float* w1       = (const float*)d_in[5];
    const float* b1       = (const float*)d_in[6];
    const float* w2       = (const float*)d_in[7];
    const float* b2       = (const float*)d_in[8];
    const float* fc1_w    = (const float*)d_in[9];
    const float* fc1_b    = (const float*)d_in[10];
    const float* fc2_w    = (const float*)d_in[11];
    const float* fc2_b    = (const float*)d_in[12];
    const float* head_w1  = (const float*)d_in[13];
    const float* head_b1  = (const float*)d_in[14];
    const float* head_w2  = (const float*)d_in[15];
    const float* head_b2  = (const float*)d_in[16];
    float* out = (float*)d_out;
    float* ws  = (float*)d_ws;

    // ---- workspace layout, sizes in float units ----
    float* pf = ws;
    _Float16* t_h     = (_Float16*)pf; pf += 1572864;   // 4096x768 f16 (residual state)
    _Float16* Wsp     = (_Float16*)pf; pf += 589824;    // 128x9216 f16 spectral weights
    _Float16* h1t     = (_Float16*)pf; pf += 589824;    // [1536][768] f16
    _Float16* h2t     = (_Float16*)pf; pf += 49152;     // [64][1536] f16
    _Float16* convw_h = (_Float16*)pf; pf += 294912;    // 768x768 f16 (prepass only)
    float* alias    = pf;              pf += 6291456;   // hid_h 4096x3072 f16
    _Float16* hid_h = (_Float16*)alias;
    _Float16* WtAll = (_Float16*)pf;   pf += 9437184;   // 8 x [N][K] fc weights f16
    // fallback xa inside alias (hid dead when xa live); full mode: dedicated xa after WtAll
    _Float16* xa_r_fb = (_Float16*)alias;
    _Float16* xa_i_fb = (_Float16*)(alias + 835584);
    _Float16* xa_r_fu = (_Float16*)pf;                  // +835,584 f
    _Float16* xa_i_fu = (_Float16*)(pf + 835584);       // +835,584 f
    size_t full_total = (size_t)(pf - ws) + 1671168;    // 20,496,384 f = 82.0 MB
    bool full = ws_size >= full_total * 4ull;
    _Float16* xa_r = full ? xa_r_fu : xa_r_fb;
    _Float16* xa_i = full ? xa_i_fu : xa_i_fb;
    _Float16* A_h  = (_Float16*)alias;                  // prepass-only (gather input, dead after)

    // ---- prepass ----
    prep_specw<<<dim3(128), 256, 0, stream>>>(w1, w2, Wsp);
    cvt_f16<<<dim3(576), 256, 0, stream>>>(conv_w, convw_h);
    cvt_transpose<<<dim3(24, 48), 256, 0, stream>>>(head_w1, h1t, 768, 1536);
    cvt_transpose<<<dim3(48, 2), 256, 0, stream>>>(head_w2, h2t, 1536, 64);
    for (int d = 0; d < 4; ++d) {
        cvt_transpose<<<dim3(24, 96), 256, 0, stream>>>(
            fc1_w + (size_t)d * 2359296, WtAll + (size_t)(2 * d) * 2359296, 768, 3072);
        cvt_transpose<<<dim3(96, 24), 256, 0, stream>>>(
            fc2_w + (size_t)d * 2359296, WtAll + (size_t)(2 * d + 1) * 2359296, 3072, 768);
    }
    gather_patch<<<dim3(12288), 256, 0, stream>>>(x, grd, A_h);
    gemm_h<128, 1, 0><<<dim3(6, 32), 256, 0, stream>>>(
        A_h, convw_h, conv_b, pos_emb, nullptr, t_h, nullptr, nullptr, 4096, 768, 768, 0);
    dft_fwd_w<<<dim3(128, 3), 256, 0, stream>>>(t_h, xa_r, xa_i);

    for (int f = 0; f < 4; ++f) {
        for (int d = 0; d < 4; ++d) {
            // fused H-DFT + complex MLP + H-IDFT (in-place on xa)
            spec_fused<<<dim3(68, 8), 256, 0, stream>>>(
                xa_r, xa_i,
                Wsp + (size_t)(d * 4 + 0) * 73728, Wsp + (size_t)(d * 4 + 1) * 73728,
                Wsp + (size_t)(d * 4 + 2) * 73728, Wsp + (size_t)(d * 4 + 3) * 73728,
                b1 + d * 1536, b1 + d * 1536 + 768,
                b2 + d * 1536, b2 + d * 1536 + 768);
            // irfft2 W-pass + f16 residual (in place on t_h)
            dft_inv_w<<<dim3(128, 3), 256, 0, stream>>>(xa_r, xa_i, t_h);
            // channel MLP fc1: 256x192-tile kernel, 256 blocks = 1/CU
            gemm256<192, 1><<<dim3(16, 16), 512, 0, stream>>>(
                t_h, WtAll + (size_t)(2 * d) * 2359296, fc1_b + d * 3072,
                hid_h, 4096, 3072, 768);
            if (full) {
                // fc2 + fused forward W-DFT (seeds xa for the next spectral block)
                gemm_h<64, 4, 0><<<dim3(12, 32), 256, 0, stream>>>(
                    hid_h, WtAll + (size_t)(2 * d + 1) * 2359296, fc2_b + d * 768,
                    nullptr, nullptr, t_h, xa_r, xa_i, 4096, 768, 3072, 0);
            } else {
                gemm_h<64, 1, 0><<<dim3(12, 32), 256, 0, stream>>>(
                    hid_h, WtAll + (size_t)(2 * d + 1) * 2359296, fc2_b + d * 768,
                    nullptr, nullptr, t_h, nullptr, nullptr, 4096, 768, 3072, 0);
                dft_fwd_w<<<dim3(128, 3), 256, 0, stream>>>(t_h, xa_r, xa_i);
            }
        }
        // head on current state (t_h from fc2)
        gemm256<192, 1><<<dim3(8, 16), 512, 0, stream>>>(
            t_h, h1t, head_b1, hid_h, 4096, 1536, 768);
        gemm_h<64, 3, 0><<<dim3(1, 32), 256, 0, stream>>>(
            hid_h, h2t, head_b2, nullptr, out, nullptr, nullptr, nullptr, 4096, 64, 1536, f);
    }
}

// Round 3
// 2312.505 us; speedup vs baseline: 1.1829x; 1.0791x over previous
//
#include <hip/hip_runtime.h>
#include <hip/hip_bf16.h>
#include <math.h>

// ---------------- static config ----------------
// B=4, H=W=256, TIN=10, F=4, P=8, CIN=12, E=768, NB=8, BS=96,
// HP=WP=32, MID=3072, DEPTH=4, LAM=0.01, WF=17, TOK=4096, POS=B*32*17=2176
// Spectral layout: X[((b*17+kw)*32 + h)*768 + c]   (h-rows contiguous per kw)
// R10: gemm_h depth-3 counted-vmcnt (kept for conv/fc2/head2).
// R11: gemm256 (256x192, 1 blk/CU) for fc1/head1 -- +240us but 2-phase ceiling.
// R12: gemm128d replaces gemm256: 128x192 tile, 8 waves (64x48/wave), BK=64,
//   LDS exactly 80KB -> 2 blocks/CU (fc1 grid 512 = 2/CU) so co-resident block
//   covers the per-tile vmcnt+barrier stall. gemm_h K-loop gains chunk^row XOR
//   swizzle (8-way -> 4-way bank conflicts), same counted-vmcnt skeleton.

typedef __attribute__((ext_vector_type(8))) _Float16 half8;
typedef __attribute__((ext_vector_type(4))) _Float16 half4v;
typedef __attribute__((ext_vector_type(4))) float float4v;

__device__ __forceinline__ float gelu_f(float v) {
    return 0.5f * v * (1.0f + erff(v * 0.70710678118654752f));
}
__device__ __forceinline__ float shrink_f(float v) {
    return (v > 0.01f) ? (v - 0.01f) : ((v < -0.01f) ? (v + 0.01f) : 0.0f);
}

#define STEP32 0.19634954084936207f  // 2*pi/32

// async 16B global->LDS (lds dest wave-uniform; HW adds lane*16)
__device__ __forceinline__ void async16(const void* g, void* l) {
    __builtin_amdgcn_global_load_lds(
        (const __attribute__((address_space(1))) unsigned int*)g,
        (__attribute__((address_space(3))) unsigned int*)l, 16, 0, 0);
}

// ---------------- gather patches into A_h [4096][768] f16 ----------------
__global__ __launch_bounds__(256) void gather_patch(const float* __restrict__ x,
        const float* __restrict__ grd, _Float16* __restrict__ A)
{
    int idx = blockIdx.x * 256 + threadIdx.x;
    int j   = idx % 768;
    int tok = idx / 768;
    int c = j >> 6, p = (j >> 3) & 7, q = j & 7;
    int wp = tok & 31, hp = (tok >> 5) & 31, b = tok >> 10;
    int hh = hp * 8 + p, ww = wp * 8 + q;
    float v;
    if (c < 10) v = x[((b * 256 + hh) * 256 + ww) * 10 + c];
    else        v = grd[((b * 256 + hh) * 256 + ww) * 2 + (c - 10)];
    A[idx] = (_Float16)v;
}

// ---------------- forward DFT along W (f16 in -> 17 complex f16), scale 1/32 ----------------
// prepass + fallback path. out layout [b,kw,h,c]
__global__ __launch_bounds__(256) void dft_fwd_w(const _Float16* __restrict__ th,
        _Float16* __restrict__ Xr, _Float16* __restrict__ Xi)
{
    __shared__ float2 lut[32];
    int bh = blockIdx.x;            // b*32 + h
    int tid = threadIdx.x;
    if (tid < 32) { float a = tid * STEP32; lut[tid] = make_float2(cosf(a), sinf(a)); }
    __syncthreads();
    int b = bh >> 5, h = bh & 31;
    int c = blockIdx.y * 256 + tid;
    float v[32];
    #pragma unroll
    for (int w = 0; w < 32; ++w) v[w] = (float)th[(bh * 32 + w) * 768 + c];
    for (int kw = 0; kw <= 16; ++kw) {
        float ar = 0.f, ai = 0.f;
        #pragma unroll
        for (int w = 0; w < 32; ++w) {
            float2 cs = lut[(kw * w) & 31];
            ar += v[w] * cs.x;
            ai -= v[w] * cs.y;
        }
        size_t g = ((size_t)(b * 17 + kw) * 32 + h) * 768 + c;
        Xr[g] = (_Float16)(ar * 0.03125f);
        Xi[g] = (_Float16)(ai * 0.03125f);
    }
}

// ---------------- inverse DFT along W (f16 in, [b,kw,h,c]) + f16 residual in-place ----------------
__global__ __launch_bounds__(256) void dft_inv_w(const _Float16* __restrict__ Yr,
        const _Float16* __restrict__ Yi, _Float16* __restrict__ th)
{
    __shared__ float2 lut[32];
    int bh = blockIdx.x;
    int tid = threadIdx.x;
    if (tid < 32) { float a = tid * STEP32; lut[tid] = make_float2(cosf(a), sinf(a)); }
    __syncthreads();
    int b = bh >> 5, h = bh & 31;
    int c = blockIdx.y * 256 + tid;
    float yr[17], yi[16];
    #pragma unroll
    for (int k = 0; k <= 16; ++k) yr[k] = (float)Yr[((size_t)(b * 17 + k) * 32 + h) * 768 + c];
    #pragma unroll
    for (int k = 1; k <= 15; ++k) yi[k] = (float)Yi[((size_t)(b * 17 + k) * 32 + h) * 768 + c];
    for (int w = 0; w < 32; ++w) {
        float val = yr[0] + ((w & 1) ? -yr[16] : yr[16]);
        #pragma unroll
        for (int k = 1; k <= 15; ++k) {
            float2 cs = lut[(k * w) & 31];
            val += 2.f * (yr[k] * cs.x - yi[k] * cs.y);
        }
        int gi = (bh * 32 + w) * 768 + c;
        th[gi] = (_Float16)(val * 0.03125f + (float)th[gi]);
    }
}

// ---------------- spectral weight prep: [i][o] fp32 -> [o][i] f16, 128 matrices ----------------
__global__ __launch_bounds__(256) void prep_specw(const float* __restrict__ w1,
        const float* __restrict__ w2, _Float16* __restrict__ out)
{
    __shared__ float tile[96][97];
    int mid = blockIdx.x;
    int n  = mid & 7;
    int ri = (mid >> 3) & 1;
    int l  = (mid >> 4) & 1;
    int d  = mid >> 5;
    const float* src = (l ? w2 : w1) + ((size_t)(d * 2 + ri) * 8 + n) * 9216;
    for (int idx = threadIdx.x; idx < 9216; idx += 256)
        tile[idx / 96][idx % 96] = src[idx];
    __syncthreads();
    _Float16* dst = out + (size_t)mid * 9216;
    for (int idx = threadIdx.x; idx < 9216; idx += 256)
        dst[idx] = (_Float16)tile[idx % 96][idx / 96];   // dst[o][i] = src[i][o]
}

// ---------------- fused spectral: H-DFT -> spec1(gelu) -> spec2(shrink) -> H-IDFT ----------------
// IN-PLACE on X ([b,kw,h,c] layout). grid (68 = b*17+kw, 8 = n); 256 thr = 4 waves.
__global__ __launch_bounds__(256) void spec_fused(
        _Float16* __restrict__ Xr, _Float16* __restrict__ Xi,
        const _Float16* __restrict__ W1r, const _Float16* __restrict__ W1i,
        const _Float16* __restrict__ W2r, const _Float16* __restrict__ W2i,
        const float* __restrict__ b1r, const float* __restrict__ b1i,
        const float* __restrict__ b2r, const float* __restrict__ b2i)
{
    __shared__ alignas(16) _Float16 Ec[1024], Es[1024];       // [m][k] twiddle 32x32
    __shared__ alignas(16) _Float16 XTr[3840], XTi[3840];     // [c][h] pad40; stage C: [o][kh]
    __shared__ alignas(16) _Float16 Zr[3328], Zi[3328];       // [kh][c] pad104; stage D out [h][c]
    __shared__ alignas(16) _Float16 Sr[3328], Si[3328];       // [kh][o] pad104

    const int bk = blockIdx.x;       // b*17 + kw
    const int n  = blockIdx.y;
    const int tid = threadIdx.x;
    const int wave = tid >> 6, lane = tid & 63;
    const int wr = wave >> 1, wc = wave & 1;
    const int lr = lane & 15, quad = lane >> 4;
    const size_t base = (size_t)bk * 24576 + n * 96;    // + h*768 + c

    for (int i = tid; i < 1024; i += 256) {
        int kh = i >> 5, h = i & 31;
        float a = ((kh * h) & 31) * STEP32;
        Ec[i] = (_Float16)cosf(a);
        Es[i] = (_Float16)sinf(a);
    }
    // vector load -> LDS transpose [c][h]
    for (int i = tid; i < 384; i += 256) {
        int h = i / 12, cc = (i % 12) * 8;
        half8 vr = *(const half8*)(Xr + base + (size_t)h * 768 + cc);
        half8 vi = *(const half8*)(Xi + base + (size_t)h * 768 + cc);
        #pragma unroll
        for (int e = 0; e < 8; ++e) {
            XTr[(cc + e) * 40 + h] = vr[e];
            XTi[(cc + e) * 40 + h] = vi[e];
        }
    }
    __syncthreads();

    const _Float16* w1r = W1r + (size_t)n * 9216;
    const _Float16* w1i = W1i + (size_t)n * 9216;
    const _Float16* w2r = W2r + (size_t)n * 9216;
    const _Float16* w2i = W2i + (size_t)n * 9216;

    half8 eC = *(const half8*)&Ec[(wr * 16 + lr) * 32 + quad * 8];
    half8 eS = *(const half8*)&Es[(wr * 16 + lr) * 32 + quad * 8];
    half8 eSn = -eS;

    // stage A: Z[kh][c] = DFT_h(X)
    {
        float4v zr[3], zi[3];
        #pragma unroll
        for (int j = 0; j < 3; ++j) { float4v z = {0,0,0,0}; zr[j] = z; zi[j] = z; }
        #pragma unroll
        for (int j = 0; j < 3; ++j) {
            int c = wc * 48 + j * 16 + lr;
            half8 xr = *(const half8*)&XTr[c * 40 + quad * 8];
            half8 xi = *(const half8*)&XTi[c * 40 + quad * 8];
            zr[j] = __builtin_amdgcn_mfma_f32_16x16x32_f16(eC,  xr, zr[j], 0, 0, 0);
            zr[j] = __builtin_amdgcn_mfma_f32_16x16x32_f16(eS,  xi, zr[j], 0, 0, 0);
            zi[j] = __builtin_amdgcn_mfma_f32_16x16x32_f16(eC,  xi, zi[j], 0, 0, 0);
            zi[j] = __builtin_amdgcn_mfma_f32_16x16x32_f16(eSn, xr, zi[j], 0, 0, 0);
        }
        #pragma unroll
        for (int j = 0; j < 3; ++j) {
            int c = wc * 48 + j * 16 + lr;
            #pragma unroll
            for (int r = 0; r < 4; ++r) {
                int kh = wr * 16 + quad * 4 + r;
                Zr[kh * 104 + c] = (_Float16)zr[j][r];
                Zi[kh * 104 + c] = (_Float16)zi[j][r];
            }
        }
    }
    __syncthreads();

    // stage B: S = gelu(Z @ W1 + b1)
    {
        float4v sr[3], si[3];
        #pragma unroll
        for (int j = 0; j < 3; ++j) { float4v z = {0,0,0,0}; sr[j] = z; si[j] = z; }
        #pragma unroll
        for (int kc = 0; kc < 3; ++kc) {
            half8 ar = *(const half8*)&Zr[(wr * 16 + lr) * 104 + kc * 32 + quad * 8];
            half8 ai = *(const half8*)&Zi[(wr * 16 + lr) * 104 + kc * 32 + quad * 8];
            half8 ain = -ai;
            #pragma unroll
            for (int j = 0; j < 3; ++j) {
                int o = wc * 48 + j * 16 + lr;
                half8 br = *(const half8*)&w1r[o * 96 + kc * 32 + quad * 8];
                half8 bi = *(const half8*)&w1i[o * 96 + kc * 32 + quad * 8];
                sr[j] = __builtin_amdgcn_mfma_f32_16x16x32_f16(ar,  br, sr[j], 0, 0, 0);
                sr[j] = __builtin_amdgcn_mfma_f32_16x16x32_f16(ain, bi, sr[j], 0, 0, 0);
                si[j] = __builtin_amdgcn_mfma_f32_16x16x32_f16(ai,  br, si[j], 0, 0, 0);
                si[j] = __builtin_amdgcn_mfma_f32_16x16x32_f16(ar,  bi, si[j], 0, 0, 0);
            }
        }
        #pragma unroll
        for (int j = 0; j < 3; ++j) {
            int o = wc * 48 + j * 16 + lr;
            float br = b1r[n * 96 + o], bi = b1i[n * 96 + o];
            #pragma unroll
            for (int r = 0; r < 4; ++r) {
                int kh = wr * 16 + quad * 4 + r;
                Sr[kh * 104 + o] = (_Float16)gelu_f(sr[j][r] + br);
                Si[kh * 104 + o] = (_Float16)gelu_f(si[j][r] + bi);
            }
        }
    }
    __syncthreads();

    // stage C: T = shrink(S @ W2 + b2) -> transposed T2T[o][kh] (alias XT)
    {
        float4v tr[3], ti[3];
        #pragma unroll
        for (int j = 0; j < 3; ++j) { float4v z = {0,0,0,0}; tr[j] = z; ti[j] = z; }
        #pragma unroll
        for (int kc = 0; kc < 3; ++kc) {
            half8 ar = *(const half8*)&Sr[(wr * 16 + lr) * 104 + kc * 32 + quad * 8];
            half8 ai = *(const half8*)&Si[(wr * 16 + lr) * 104 + kc * 32 + quad * 8];
            half8 ain = -ai;
            #pragma unroll
            for (int j = 0; j < 3; ++j) {
                int o = wc * 48 + j * 16 + lr;
                half8 br = *(const half8*)&w2r[o * 96 + kc * 32 + quad * 8];
                half8 bi = *(const half8*)&w2i[o * 96 + kc * 32 + quad * 8];
                tr[j] = __builtin_amdgcn_mfma_f32_16x16x32_f16(ar,  br, tr[j], 0, 0, 0);
                tr[j] = __builtin_amdgcn_mfma_f32_16x16x32_f16(ain, bi, tr[j], 0, 0, 0);
                ti[j] = __builtin_amdgcn_mfma_f32_16x16x32_f16(ai,  br, ti[j], 0, 0, 0);
                ti[j] = __builtin_amdgcn_mfma_f32_16x16x32_f16(ar,  bi, ti[j], 0, 0, 0);
            }
        }
        #pragma unroll
        for (int j = 0; j < 3; ++j) {
            int o = wc * 48 + j * 16 + lr;
            float br = b2r[n * 96 + o], bi = b2i[n * 96 + o];
            #pragma unroll
            for (int r = 0; r < 4; ++r) {
                int kh = wr * 16 + quad * 4 + r;
                XTr[o * 40 + kh] = (_Float16)shrink_f(tr[j][r] + br);
                XTi[o * 40 + kh] = (_Float16)shrink_f(ti[j][r] + bi);
            }
        }
    }
    __syncthreads();

    // stage D: Y[h][c] = IDFT_h(T2) -> Zr/Zi as [h][c] pad104
    {
        float4v yr[3], yi[3];
        #pragma unroll
        for (int j = 0; j < 3; ++j) { float4v z = {0,0,0,0}; yr[j] = z; yi[j] = z; }
        #pragma unroll
        for (int j = 0; j < 3; ++j) {
            int c = wc * 48 + j * 16 + lr;
            half8 t2r = *(const half8*)&XTr[c * 40 + quad * 8];
            half8 t2i = *(const half8*)&XTi[c * 40 + quad * 8];
            yr[j] = __builtin_amdgcn_mfma_f32_16x16x32_f16(eC,  t2r, yr[j], 0, 0, 0);
            yr[j] = __builtin_amdgcn_mfma_f32_16x16x32_f16(eSn, t2i, yr[j], 0, 0, 0);
            yi[j] = __builtin_amdgcn_mfma_f32_16x16x32_f16(eC,  t2i, yi[j], 0, 0, 0);
            yi[j] = __builtin_amdgcn_mfma_f32_16x16x32_f16(eS,  t2r, yi[j], 0, 0, 0);
        }
        #pragma unroll
        for (int j = 0; j < 3; ++j) {
            int c = wc * 48 + j * 16 + lr;
            #pragma unroll
            for (int r = 0; r < 4; ++r) {
                int h = wr * 16 + quad * 4 + r;
                Zr[h * 104 + c] = (_Float16)yr[j][r];
                Zi[h * 104 + c] = (_Float16)yi[j][r];
            }
        }
    }
    __syncthreads();

    // vector store back (in-place)
    for (int i = tid; i < 384; i += 256) {
        int h = i / 12, cc = (i % 12) * 8;
        half8 vr = *(const half8*)&Zr[h * 104 + cc];
        half8 vi = *(const half8*)&Zi[h * 104 + cc];
        *(half8*)(Xr + base + (size_t)h * 768 + cc) = vr;
        *(half8*)(Xi + base + (size_t)h * 768 + cc) = vi;
    }
}

// ---------------- f32 -> f16 elementwise (vectorized x4) ----------------
__global__ __launch_bounds__(256) void cvt_f16(const float* __restrict__ in,
        _Float16* __restrict__ out)
{
    int i = blockIdx.x * 256 + threadIdx.x;
    float4 v = ((const float4*)in)[i];
    half4v o;
    o.x = (_Float16)v.x; o.y = (_Float16)v.y; o.z = (_Float16)v.z; o.w = (_Float16)v.w;
    ((half4v*)out)[i] = o;
}

// ---------------- f32 [K][N] -> f16 [N][K] transpose ----------------
__global__ __launch_bounds__(256) void cvt_transpose(const float* __restrict__ in,
        _Float16* __restrict__ out, int K, int N)
{
    __shared__ float tile[32][33];
    int kb = blockIdx.x * 32, nb = blockIdx.y * 32;
    int tx = threadIdx.x & 31, ty = threadIdx.x >> 5;
    #pragma unroll
    for (int r = 0; r < 32; r += 8)
        tile[ty + r][tx] = in[(size_t)(kb + ty + r) * N + nb + tx];
    __syncthreads();
    #pragma unroll
    for (int r = 0; r < 32; r += 8)
        out[(size_t)(nb + ty + r) * K + kb + tx] = (_Float16)tile[tx][ty + r];
}

// ---------------- R12: 128x192-tile 8-wave GEMM, 2 blocks/CU (fc1 / head1) ----------------
// 8 waves = 2M x 4N, per-wave 64x48 (4 m-frags x 3 n-frags, 24 MFMA / K64-tile).
// BK=64, 2 LDS buffers: A 2x16KB + B 2x24KB = 80KB exactly -> 2 blocks/CU.
// fc1 grid 16x32 = 512 blocks = 2/CU: co-resident block covers barrier/vmcnt stalls.
// Per tile: vmcnt(5) counted (never 0 mid-loop) -> barrier -> ds_read+MFMA -> barrier
// -> stage tile t+2 into just-freed buffer. 128B rows: full 8-chunk XOR swizzle
// (chunk ^= row&7) on BOTH gload_lds source and ds_read addr (rule #21).
template<int BN, int ACT>
__global__ __launch_bounds__(512, 4) void gemm128d(const _Float16* __restrict__ A,
        const _Float16* __restrict__ Bt, const float* __restrict__ bias,
        _Float16* __restrict__ C16, int M, int N, int K)
{
    constexpr int WN  = BN / 4;           // 48
    constexpr int FN  = WN / 16;          // 3
    constexpr int AU  = 2;                // A: 2 x 64-row units
    constexpr int BU  = BN / 64;          // 3
    constexpr int LPT = AU + BU;          // 5 loads/thread/K-tile
    __shared__ _Float16 Al[2][128 * 64];
    __shared__ _Float16 Bl[2][BN * 64];

    const int tid  = threadIdx.x;
    const int wave = tid >> 6;            // 0..7
    const int lane = tid & 63;
    const int wr   = wave >> 2;           // 0..1 (M)
    const int wc   = wave & 3;            // 0..3 (N)
    const int lr   = lane & 15;
    const int quad = lane >> 4;

    // XCD swizzle (2D): per-XCD contiguous patch for L2 reuse
    const int gx = gridDim.x, gy = gridDim.y, nbk = gx * gy;
    int bx = blockIdx.x, by = blockIdx.y;
    if (!(gy & 3) && !(gx & 1)) {
        int id = by * gx + bx;
        int xcd = id & 7, j = id >> 3;
        int cols = gx >> 1;
        int rows = gy >> 2;
        int jr = j / cols, jc = j % cols;
        by = (xcd >> 1) * rows + jr;
        bx = (xcd & 1) * cols + jc;
    } else if (!(nbk & 7)) {
        int id  = by * gx + bx;
        int id2 = (id & 7) * (nbk >> 3) + (id >> 3);
        by = id2 / gx; bx = id2 % gx;
    }
    const int row0 = by * 128;
    const int col0 = bx * BN;

    // staging: per 64-row unit (64x64 halfs = 8KB) each wave covers 8 rows.
    // lane l: row = l>>3, phys chunk = l&7, source logical chunk = (l&7)^(row&7).
    const int srow = lane >> 3;
    const int schk = (lane & 7) ^ (srow & 7);
    const _Float16* Ab = A  + (size_t)(row0 + wave * 8 + srow) * K + schk * 8;
    const _Float16* Bb = Bt + (size_t)(col0 + wave * 8 + srow) * K + schk * 8;

    auto stage = [&](int b, int kt) {
        const int k0 = kt * 64;
        #pragma unroll
        for (int u = 0; u < AU; ++u)
            async16(Ab + (size_t)u * 64 * K + k0, &Al[b][(u * 64 + wave * 8) * 64]);
        #pragma unroll
        for (int u = 0; u < BU; ++u)
            async16(Bb + (size_t)u * 64 * K + k0, &Bl[b][(u * 64 + wave * 8) * 64]);
    };

    float4v acc[4][FN];
    #pragma unroll
    for (int m = 0; m < 4; ++m)
        #pragma unroll
        for (int n = 0; n < FN; ++n) {
            float4v z = {0.f, 0.f, 0.f, 0.f};
            acc[m][n] = z;
        }

    auto compute = [&](int cb) {
        #pragma unroll
        for (int ks = 0; ks < 2; ++ks) {
            const int cA = ((ks * 4 + quad) ^ (lr & 7)) * 8;   // swizzled chunk (halfs)
            half8 bf[FN];
            #pragma unroll
            for (int n = 0; n < FN; ++n)
                bf[n] = *(const half8*)&Bl[cb][(wc * WN + n * 16 + lr) * 64 + cA];
            half8 af[4];
            #pragma unroll
            for (int m = 0; m < 4; ++m)
                af[m] = *(const half8*)&Al[cb][(wr * 64 + m * 16 + lr) * 64 + cA];
            __builtin_amdgcn_s_setprio(1);
            #pragma unroll
            for (int m = 0; m < 4; ++m)
                #pragma unroll
                for (int n = 0; n < FN; ++n)
                    acc[m][n] = __builtin_amdgcn_mfma_f32_16x16x32_f16(af[m], bf[n], acc[m][n], 0, 0, 0);
            __builtin_amdgcn_s_setprio(0);
        }
    };

    const int NT = K >> 6;                // K=768 -> 12 tiles
    stage(0, 0);
    stage(1, 1);
    for (int t = 0; t < NT; ++t) {
        if (t + 1 < NT) asm volatile("s_waitcnt vmcnt(5)" ::: "memory");
        else            asm volatile("s_waitcnt vmcnt(0)" ::: "memory");
        __builtin_amdgcn_s_barrier();     // all waves' tile-t loads visible
        compute(t & 1);
        __builtin_amdgcn_s_barrier();     // all waves done reading buf[t&1]
        if (t + 2 < NT) stage(t & 1, t + 2);   // prefetch into just-freed buffer
    }

    // epilogue: bias (+GELU) -> f16 store
    #pragma unroll
    for (int n = 0; n < FN; ++n) {
        int col = col0 + wc * WN + n * 16 + lr;
        float bj = bias[col];
        #pragma unroll
        for (int m = 0; m < 4; ++m) {
            int row = row0 + wr * 64 + m * 16 + quad * 4;
            #pragma unroll
            for (int r = 0; r < 4; ++r) {
                float v = acc[m][n][r] + bj;
                if (ACT) v = gelu_f(v);
                C16[(size_t)(row + r) * N + col] = (_Float16)v;
            }
        }
    }
}

// ---------------- fp16 MFMA GEMM, depth-3 counted-vmcnt pipeline, 2D-XCD swizzle ----------------
// OUT_MODE: 1 = f16, 3 = f32 pixel-shuffle scatter,
//           4 = f16 + fused forward W-DFT epilogue (fc2: writes XR/XI [b,kw,h,c])
// R12: K-loop LDS chunk^row XOR swizzle (8-way -> 4-way bank conflicts); bijective
// per row, applied to both gload_lds source and ds_read addr.
template<int BN, int OUT_MODE, int ACT>
__global__ __launch_bounds__(256) void gemm_h(const _Float16* __restrict__ A,
        const _Float16* __restrict__ Bt, const float* __restrict__ bias,
        const float* __restrict__ pos, float* __restrict__ C32,
        _Float16* __restrict__ C16, _Float16* __restrict__ XR,
        _Float16* __restrict__ XI, int M, int N, int K, int f_idx)
{
    constexpr int WN  = BN / 2;
    constexpr int FN  = WN / 16;
    constexpr int NBJ = BN / 64;
    constexpr int LPT = 2 + NBJ;          // vmem loads per thread per K-tile
    __shared__ _Float16 Al[4][128 * 32];
    __shared__ _Float16 Bl[4][BN * 32];

    const int tid  = threadIdx.x;
    const int wave = tid >> 6;
    const int lane = tid & 63;
    const int wr   = wave >> 1;
    const int wc   = wave & 1;
    const int lr   = lane & 15;
    const int quad = lane >> 4;

    // XCD swizzle: prefer 2D (4 row-groups x 2 col-groups -> per-XCD A+B fits 4MB L2)
    const int gx = gridDim.x, gy = gridDim.y, nbk = gx * gy;
    int bx = blockIdx.x, by = blockIdx.y;
    if (!(gy & 3) && !(gx & 1)) {
        int id = by * gx + bx;
        int xcd = id & 7, j = id >> 3;
        int cols = gx >> 1;
        int rows = gy >> 2;
        int jr = j / cols, jc = j % cols;
        by = (xcd >> 1) * rows + jr;
        bx = (xcd & 1) * cols + jc;
    } else if (!(nbk & 7)) {
        int id  = by * gx + bx;
        int id2 = (id & 7) * (nbk >> 3) + (id >> 3);
        by = id2 / gx; bx = id2 % gx;
    }
    const int row0 = by * 128;
    const int col0 = bx * BN;

    // staging: rows of 32 halfs = 4 x 16B chunks; lane l: row = l>>2, phys chunk
    // l&3, source logical chunk = (l&3)^(row&3).
    const int srow = lane >> 2;
    const int skof = ((lane & 3) ^ (srow & 3)) * 8;

    auto stage = [&](int b, int kt) {
        const int k0 = kt << 5;
        #pragma unroll
        for (int j = 0; j < 2; ++j)
            async16(A + (size_t)(row0 + j * 64 + wave * 16 + srow) * K + k0 + skof,
                    &Al[b][(j * 64 + wave * 16) * 32]);
        #pragma unroll
        for (int j = 0; j < NBJ; ++j)
            async16(Bt + (size_t)(col0 + j * 64 + wave * 16 + srow) * K + k0 + skof,
                    &Bl[b][(j * 64 + wave * 16) * 32]);
    };

    float4v acc[4][FN];
    #pragma unroll
    for (int i = 0; i < 4; ++i)
        #pragma unroll
        for (int j = 0; j < FN; ++j) {
            float4v z = {0.f, 0.f, 0.f, 0.f};
            acc[i][j] = z;
        }

    auto compute = [&](int cb) {
        const int cA = (quad ^ (lr & 3)) * 8;   // swizzled chunk (halfs)
        half8 af[4], bf[FN];
        #pragma unroll
        for (int i = 0; i < 4; ++i)
            af[i] = *(const half8*)&Al[cb][(wr * 64 + i * 16 + lr) * 32 + cA];
        #pragma unroll
        for (int j = 0; j < FN; ++j)
            bf[j] = *(const half8*)&Bl[cb][(wc * WN + j * 16 + lr) * 32 + cA];
        #pragma unroll
        for (int i = 0; i < 4; ++i)
            #pragma unroll
            for (int j = 0; j < FN; ++j)
                acc[i][j] = __builtin_amdgcn_mfma_f32_16x16x32_f16(af[i], bf[j], acc[i][j], 0, 0, 0);
    };

    const int KT = K >> 5;                // K >= 768 -> KT >= 24 (always > 4)
    stage(0, 0); stage(1, 1); stage(2, 2);
    int kt = 0;
    for (; kt < KT - 3; ++kt) {
        stage((kt + 3) & 3, kt + 3);
        if constexpr (LPT == 4) asm volatile("s_waitcnt vmcnt(12)" ::: "memory");
        else                    asm volatile("s_waitcnt vmcnt(9)"  ::: "memory");
        __builtin_amdgcn_s_barrier();
        compute(kt & 3);
        asm volatile("" ::: "memory");
        __builtin_amdgcn_s_barrier();
    }
    // tail: 3 tiles in flight, no more staging; drain 2L -> L -> 0
    if constexpr (LPT == 4) asm volatile("s_waitcnt vmcnt(8)" ::: "memory");
    else                    asm volatile("s_waitcnt vmcnt(6)" ::: "memory");
    __builtin_amdgcn_s_barrier();
    compute(kt & 3); ++kt;
    asm volatile("" ::: "memory");
    __builtin_amdgcn_s_barrier();
    if constexpr (LPT == 4) asm volatile("s_waitcnt vmcnt(4)" ::: "memory");
    else                    asm volatile("s_waitcnt vmcnt(3)" ::: "memory");
    __builtin_amdgcn_s_barrier();
    compute(kt & 3); ++kt;
    asm volatile("" ::: "memory");
    __builtin_amdgcn_s_barrier();
    asm volatile("s_waitcnt vmcnt(0)" ::: "memory");
    __builtin_amdgcn_s_barrier();
    compute(kt & 3);

    if constexpr (OUT_MODE == 4) {
        // fc2 epilogue: f16 write + stage tile + fused forward W-DFT
        __shared__ alignas(16) _Float16 Tl[4 * 64 * 32];   // [h][c][w]
        __shared__ alignas(16) _Float16 ECl[1024], ESl[1024];
        for (int i = tid; i < 1024; i += 256) {
            int kw = i >> 5, w = i & 31;
            float a = ((kw * w) & 31) * STEP32;
            ECl[i] = (_Float16)(cosf(a) * 0.03125f);
            ESl[i] = (_Float16)(-sinf(a) * 0.03125f);
        }
        #pragma unroll
        for (int j = 0; j < FN; ++j) {
            int col = col0 + wc * WN + j * 16 + lr;
            float bj = bias[col];
            #pragma unroll
            for (int i = 0; i < 4; ++i) {
                int row = row0 + wr * 64 + i * 16 + quad * 4;
                #pragma unroll
                for (int r = 0; r < 4; ++r) {
                    float v = acc[i][j][r] + bj;
                    size_t gi = (size_t)(row + r) * N + col;
                    C16[gi] = (_Float16)v;
                    int lrow = row + r - row0;
                    Tl[(((lrow >> 5) * 64) + (col - col0)) * 32 + (lrow & 31)] = (_Float16)v;
                }
            }
        }
        __syncthreads();
        // per-wave h-row DFT: X[kw][c] = E @ T   (wave = local h)
        const int b  = row0 >> 10;
        const int hp = ((row0 >> 5) & 31) + wave;
        half8 eC0 = *(const half8*)&ECl[lr * 32 + quad * 8];
        half8 eC1 = *(const half8*)&ECl[(16 + lr) * 32 + quad * 8];
        half8 eS0 = *(const half8*)&ESl[lr * 32 + quad * 8];
        half8 eS1 = *(const half8*)&ESl[(16 + lr) * 32 + quad * 8];
        float4v xr[2][4], xi[2][4];
        #pragma unroll
        for (int m = 0; m < 2; ++m)
            #pragma unroll
            for (int nj = 0; nj < 4; ++nj) {
                float4v z = {0.f, 0.f, 0.f, 0.f};
                xr[m][nj] = z; xi[m][nj] = z;
            }
        #pragma unroll
        for (int nj = 0; nj < 4; ++nj) {
            half8 tb = *(const half8*)&Tl[((wave * 64) + nj * 16 + lr) * 32 + quad * 8];
            xr[0][nj] = __builtin_amdgcn_mfma_f32_16x16x32_f16(eC0, tb, xr[0][nj], 0, 0, 0);
            xr[1][nj] = __builtin_amdgcn_mfma_f32_16x16x32_f16(eC1, tb, xr[1][nj], 0, 0, 0);
            xi[0][nj] = __builtin_amdgcn_mfma_f32_16x16x32_f16(eS0, tb, xi[0][nj], 0, 0, 0);
            xi[1][nj] = __builtin_amdgcn_mfma_f32_16x16x32_f16(eS1, tb, xi[1][nj], 0, 0, 0);
        }
        #pragma unroll
        for (int m = 0; m < 2; ++m)
            #pragma unroll
            for (int r = 0; r < 4; ++r) {
                int kw = m * 16 + quad * 4 + r;
                if (kw < 17) {
                    #pragma unroll
                    for (int nj = 0; nj < 4; ++nj) {
                        int c = col0 + nj * 16 + lr;
                        size_t g = ((size_t)(b * 17 + kw) * 32 + hp) * 768 + c;
                        XR[g] = (_Float16)xr[m][nj][r];
                        XI[g] = (_Float16)xi[m][nj][r];
                    }
                }
            }
    } else {
        #pragma unroll
        for (int j = 0; j < FN; ++j) {
            int col = col0 + wc * WN + j * 16 + lr;
            float bj = bias[col];
            #pragma unroll
            for (int i = 0; i < 4; ++i) {
                int row = row0 + wr * 64 + i * 16 + quad * 4;
                #pragma unroll
                for (int r = 0; r < 4; ++r) {
                    float v = acc[i][j][r] + bj;
                    if (pos) v += pos[(size_t)((row + r) & 1023) * N + col];
                    if (ACT) v = gelu_f(v);
                    if (OUT_MODE == 3) {
                        int rowv = row + r;
                        int bq = rowv >> 10, hp = (rowv >> 5) & 31, wp = rowv & 31;
                        int p = col >> 3, q = col & 7;
                        C32[(((size_t)(bq * 256 + hp * 8 + p)) * 256 + wp * 8 + q) * 4 + f_idx] = v;
                    } else {
                        C16[(size_t)(row + r) * N + col] = (_Float16)v;
                    }
                }
            }
        }
    }
}

// ---------------- launch ----------------
extern "C" void kernel_launch(void* const* d_in, const int* in_sizes, int n_in,
                              void* d_out, int out_size, void* d_ws, size_t ws_size,
                              hipStream_t stream) {
    const float* x        = (const float*)d_in[0];
    const float* grd      = (const float*)d_in[1];
    const float* conv_w   = (const float*)d_in[2];
    const float* conv_b   = (const float*)d_in[3];
    const float* pos_emb  = (const float*)d_in[4];
    const float* w1       = (const float*)d_in[5];
    const float* b1       = (const float*)d_in[6];
    const float* w2       = (const float*)d_in[7];
    const float* b2       = (const float*)d_in[8];
    const float* fc1_w    = (const float*)d_in[9];
    const float* fc1_b    = (const float*)d_in[10];
    const float* fc2_w    = (const float*)d_in[11];
    const float* fc2_b    = (const float*)d_in[12];
    const float* head_w1  = (const float*)d_in[13];
    const float* head_b1  = (const float*)d_in[14];
    const float* head_w2  = (const float*)d_in[15];
    const float* head_b2  = (const float*)d_in[16];
    float* out = (float*)d_out;
    float* ws  = (float*)d_ws;

    // ---- workspace layout, sizes in float units ----
    float* pf = ws;
    _Float16* t_h     = (_Float16*)pf; pf += 1572864;   // 4096x768 f16 (residual state)
    _Float16* Wsp     = (_Float16*)pf; pf += 589824;    // 128x9216 f16 spectral weights
    _Float16* h1t     = (_Float16*)pf; pf += 589824;    // [1536][768] f16
    _Float16* h2t     = (_Float16*)pf; pf += 49152;     // [64][1536] f16
    _Float16* convw_h = (_Float16*)pf; pf += 294912;    // 768x768 f16 (prepass only)
    float* alias    = pf;              pf += 6291456;   // hid_h 4096x3072 f16
    _Float16* hid_h = (_Float16*)alias;
    _Float16* WtAll = (_Float16*)pf;   pf += 9437184;   // 8 x [N][K] fc weights f16
    // fallback xa inside alias (hid dead when xa live); full mode: dedicated xa after WtAll
    _Float16* xa_r_fb = (_Float16*)alias;
    _Float16* xa_i_fb = (_Float16*)(alias + 835584);
    _Float16* xa_r_fu = (_Float16*)pf;                  // +835,584 f
    _Float16* xa_i_fu = (_Float16*)(pf + 835584);       // +835,584 f
    size_t full_total = (size_t)(pf - ws) + 1671168;    // 20,496,384 f = 82.0 MB
    bool full = ws_size >= full_total * 4ull;
    _Float16* xa_r = full ? xa_r_fu : xa_r_fb;
    _Float16* xa_i = full ? xa_i_fu : xa_i_fb;
    _Float16* A_h  = (_Float16*)alias;                  // prepass-only (gather input, dead after)

    // ---- prepass ----
    prep_specw<<<dim3(128), 256, 0, stream>>>(w1, w2, Wsp);
    cvt_f16<<<dim3(576), 256, 0, stream>>>(conv_w, convw_h);
    cvt_transpose<<<dim3(24, 48), 256, 0, stream>>>(head_w1, h1t, 768, 1536);
    cvt_transpose<<<dim3(48, 2), 256, 0, stream>>>(head_w2, h2t, 1536, 64);
    for (int d = 0; d < 4; ++d) {
        cvt_transpose<<<dim3(24, 96), 256, 0, stream>>>(
            fc1_w + (size_t)d * 2359296, WtAll + (size_t)(2 * d) * 2359296, 768, 3072);
        cvt_transpose<<<dim3(96, 24), 256, 0, stream>>>(
            fc2_w + (size_t)d * 2359296, WtAll + (size_t)(2 * d + 1) * 2359296, 3072, 768);
    }
    gather_patch<<<dim3(12288), 256, 0, stream>>>(x, grd, A_h);
    gemm_h<128, 1, 0><<<dim3(6, 32), 256, 0, stream>>>(
        A_h, convw_h, conv_b, pos_emb, nullptr, t_h, nullptr, nullptr, 4096, 768, 768, 0);
    dft_fwd_w<<<dim3(128, 3), 256, 0, stream>>>(t_h, xa_r, xa_i);

    for (int f = 0; f < 4; ++f) {
        for (int d = 0; d < 4; ++d) {
            // fused H-DFT + complex MLP + H-IDFT (in-place on xa)
            spec_fused<<<dim3(68, 8), 256, 0, stream>>>(
                xa_r, xa_i,
                Wsp + (size_t)(d * 4 + 0) * 73728, Wsp + (size_t)(d * 4 + 1) * 73728,
                Wsp + (size_t)(d * 4 + 2) * 73728, Wsp + (size_t)(d * 4 + 3) * 73728,
                b1 + d * 1536, b1 + d * 1536 + 768,
                b2 + d * 1536, b2 + d * 1536 + 768);
            // irfft2 W-pass + f16 residual (in place on t_h)
            dft_inv_w<<<dim3(128, 3), 256, 0, stream>>>(xa_r, xa_i, t_h);
            // channel MLP fc1: 128x192 tile, 512 blocks = 2/CU
            gemm128d<192, 1><<<dim3(16, 32), 512, 0, stream>>>(
                t_h, WtAll + (size_t)(2 * d) * 2359296, fc1_b + d * 3072,
                hid_h, 4096, 3072, 768);
            if (full) {
                // fc2 + fused forward W-DFT (seeds xa for the next spectral block)
                gemm_h<64, 4, 0><<<dim3(12, 32), 256, 0, stream>>>(
                    hid_h, WtAll + (size_t)(2 * d + 1) * 2359296, fc2_b + d * 768,
                    nullptr, nullptr, t_h, xa_r, xa_i, 4096, 768, 3072, 0);
            } else {
                gemm_h<64, 1, 0><<<dim3(12, 32), 256, 0, stream>>>(
                    hid_h, WtAll + (size_t)(2 * d + 1) * 2359296, fc2_b + d * 768,
                    nullptr, nullptr, t_h, nullptr, nullptr, 4096, 768, 3072, 0);
                dft_fwd_w<<<dim3(128, 3), 256, 0, stream>>>(t_h, xa_r, xa_i);
            }
        }
        // head on current state (t_h from fc2)
        gemm128d<192, 1><<<dim3(8, 32), 512, 0, stream>>>(
            t_h, h1t, head_b1, hid_h, 4096, 1536, 768);
        gemm_h<64, 3, 0><<<dim3(1, 32), 256, 0, stream>>>(
            hid_h, h2t, head_b2, nullptr, out, nullptr, nullptr, nullptr, 4096, 64, 1536, f);
    }
}

// Round 4
// 2173.239 us; speedup vs baseline: 1.2587x; 1.0641x over previous
//
#include <hip/hip_runtime.h>
#include <hip/hip_bf16.h>
#include <math.h>

// ---------------- static config ----------------
// B=4, H=W=256, TIN=10, F=4, P=8, CIN=12, E=768, NB=8, BS=96,
// HP=WP=32, MID=3072, DEPTH=4, LAM=0.01, WF=17, TOK=4096, POS=B*32*17=2176
// Spectral layout: X[((b*17+kw)*32 + h)*768 + c]   (h-rows contiguous per kw)
// R11/R12: gemm128d (128x192, 8 waves, 2 blk/CU, counted vmcnt) for fc1/head1.
// R13: fc2_fused replaces gemm_h<64,4>: 64x192 tile, 8 waves (32x48/wave,
//   12 MFMA per BK=64 window, 48 windows), grid (4,64)=256 blocks=1/CU,
//   depth-2 counted vmcnt(4), XOR-swizzled K-loop LDS; epilogue Tl pad-40
//   (spec_fused-proven) kills the 4.19M bank conflicts of the old epilogue.
//   gemm_h kept for conv (prepass), fallback fc2, head2.

typedef __attribute__((ext_vector_type(8))) _Float16 half8;
typedef __attribute__((ext_vector_type(4))) _Float16 half4v;
typedef __attribute__((ext_vector_type(4))) float float4v;

__device__ __forceinline__ float gelu_f(float v) {
    return 0.5f * v * (1.0f + erff(v * 0.70710678118654752f));
}
__device__ __forceinline__ float shrink_f(float v) {
    return (v > 0.01f) ? (v - 0.01f) : ((v < -0.01f) ? (v + 0.01f) : 0.0f);
}

#define STEP32 0.19634954084936207f  // 2*pi/32

// async 16B global->LDS (lds dest wave-uniform; HW adds lane*16)
__device__ __forceinline__ void async16(const void* g, void* l) {
    __builtin_amdgcn_global_load_lds(
        (const __attribute__((address_space(1))) unsigned int*)g,
        (__attribute__((address_space(3))) unsigned int*)l, 16, 0, 0);
}

// ---------------- gather patches into A_h [4096][768] f16 ----------------
__global__ __launch_bounds__(256) void gather_patch(const float* __restrict__ x,
        const float* __restrict__ grd, _Float16* __restrict__ A)
{
    int idx = blockIdx.x * 256 + threadIdx.x;
    int j   = idx % 768;
    int tok = idx / 768;
    int c = j >> 6, p = (j >> 3) & 7, q = j & 7;
    int wp = tok & 31, hp = (tok >> 5) & 31, b = tok >> 10;
    int hh = hp * 8 + p, ww = wp * 8 + q;
    float v;
    if (c < 10) v = x[((b * 256 + hh) * 256 + ww) * 10 + c];
    else        v = grd[((b * 256 + hh) * 256 + ww) * 2 + (c - 10)];
    A[idx] = (_Float16)v;
}

// ---------------- forward DFT along W (f16 in -> 17 complex f16), scale 1/32 ----------------
// prepass + fallback path. out layout [b,kw,h,c]
__global__ __launch_bounds__(256) void dft_fwd_w(const _Float16* __restrict__ th,
        _Float16* __restrict__ Xr, _Float16* __restrict__ Xi)
{
    __shared__ float2 lut[32];
    int bh = blockIdx.x;            // b*32 + h
    int tid = threadIdx.x;
    if (tid < 32) { float a = tid * STEP32; lut[tid] = make_float2(cosf(a), sinf(a)); }
    __syncthreads();
    int b = bh >> 5, h = bh & 31;
    int c = blockIdx.y * 256 + tid;
    float v[32];
    #pragma unroll
    for (int w = 0; w < 32; ++w) v[w] = (float)th[(bh * 32 + w) * 768 + c];
    for (int kw = 0; kw <= 16; ++kw) {
        float ar = 0.f, ai = 0.f;
        #pragma unroll
        for (int w = 0; w < 32; ++w) {
            float2 cs = lut[(kw * w) & 31];
            ar += v[w] * cs.x;
            ai -= v[w] * cs.y;
        }
        size_t g = ((size_t)(b * 17 + kw) * 32 + h) * 768 + c;
        Xr[g] = (_Float16)(ar * 0.03125f);
        Xi[g] = (_Float16)(ai * 0.03125f);
    }
}

// ---------------- inverse DFT along W (f16 in, [b,kw,h,c]) + f16 residual in-place ----------------
__global__ __launch_bounds__(256) void dft_inv_w(const _Float16* __restrict__ Yr,
        const _Float16* __restrict__ Yi, _Float16* __restrict__ th)
{
    __shared__ float2 lut[32];
    int bh = blockIdx.x;
    int tid = threadIdx.x;
    if (tid < 32) { float a = tid * STEP32; lut[tid] = make_float2(cosf(a), sinf(a)); }
    __syncthreads();
    int b = bh >> 5, h = bh & 31;
    int c = blockIdx.y * 256 + tid;
    float yr[17], yi[16];
    #pragma unroll
    for (int k = 0; k <= 16; ++k) yr[k] = (float)Yr[((size_t)(b * 17 + k) * 32 + h) * 768 + c];
    #pragma unroll
    for (int k = 1; k <= 15; ++k) yi[k] = (float)Yi[((size_t)(b * 17 + k) * 32 + h) * 768 + c];
    for (int w = 0; w < 32; ++w) {
        float val = yr[0] + ((w & 1) ? -yr[16] : yr[16]);
        #pragma unroll
        for (int k = 1; k <= 15; ++k) {
            float2 cs = lut[(k * w) & 31];
            val += 2.f * (yr[k] * cs.x - yi[k] * cs.y);
        }
        int gi = (bh * 32 + w) * 768 + c;
        th[gi] = (_Float16)(val * 0.03125f + (float)th[gi]);
    }
}

// ---------------- spectral weight prep: [i][o] fp32 -> [o][i] f16, 128 matrices ----------------
__global__ __launch_bounds__(256) void prep_specw(const float* __restrict__ w1,
        const float* __restrict__ w2, _Float16* __restrict__ out)
{
    __shared__ float tile[96][97];
    int mid = blockIdx.x;
    int n  = mid & 7;
    int ri = (mid >> 3) & 1;
    int l  = (mid >> 4) & 1;
    int d  = mid >> 5;
    const float* src = (l ? w2 : w1) + ((size_t)(d * 2 + ri) * 8 + n) * 9216;
    for (int idx = threadIdx.x; idx < 9216; idx += 256)
        tile[idx / 96][idx % 96] = src[idx];
    __syncthreads();
    _Float16* dst = out + (size_t)mid * 9216;
    for (int idx = threadIdx.x; idx < 9216; idx += 256)
        dst[idx] = (_Float16)tile[idx % 96][idx / 96];   // dst[o][i] = src[i][o]
}

// ---------------- fused spectral: H-DFT -> spec1(gelu) -> spec2(shrink) -> H-IDFT ----------------
// IN-PLACE on X ([b,kw,h,c] layout). grid (68 = b*17+kw, 8 = n); 256 thr = 4 waves.
__global__ __launch_bounds__(256) void spec_fused(
        _Float16* __restrict__ Xr, _Float16* __restrict__ Xi,
        const _Float16* __restrict__ W1r, const _Float16* __restrict__ W1i,
        const _Float16* __restrict__ W2r, const _Float16* __restrict__ W2i,
        const float* __restrict__ b1r, const float* __restrict__ b1i,
        const float* __restrict__ b2r, const float* __restrict__ b2i)
{
    __shared__ alignas(16) _Float16 Ec[1024], Es[1024];       // [m][k] twiddle 32x32
    __shared__ alignas(16) _Float16 XTr[3840], XTi[3840];     // [c][h] pad40; stage C: [o][kh]
    __shared__ alignas(16) _Float16 Zr[3328], Zi[3328];       // [kh][c] pad104; stage D out [h][c]
    __shared__ alignas(16) _Float16 Sr[3328], Si[3328];       // [kh][o] pad104

    const int bk = blockIdx.x;       // b*17 + kw
    const int n  = blockIdx.y;
    const int tid = threadIdx.x;
    const int wave = tid >> 6, lane = tid & 63;
    const int wr = wave >> 1, wc = wave & 1;
    const int lr = lane & 15, quad = lane >> 4;
    const size_t base = (size_t)bk * 24576 + n * 96;    // + h*768 + c

    for (int i = tid; i < 1024; i += 256) {
        int kh = i >> 5, h = i & 31;
        float a = ((kh * h) & 31) * STEP32;
        Ec[i] = (_Float16)cosf(a);
        Es[i] = (_Float16)sinf(a);
    }
    // vector load -> LDS transpose [c][h]
    for (int i = tid; i < 384; i += 256) {
        int h = i / 12, cc = (i % 12) * 8;
        half8 vr = *(const half8*)(Xr + base + (size_t)h * 768 + cc);
        half8 vi = *(const half8*)(Xi + base + (size_t)h * 768 + cc);
        #pragma unroll
        for (int e = 0; e < 8; ++e) {
            XTr[(cc + e) * 40 + h] = vr[e];
            XTi[(cc + e) * 40 + h] = vi[e];
        }
    }
    __syncthreads();

    const _Float16* w1r = W1r + (size_t)n * 9216;
    const _Float16* w1i = W1i + (size_t)n * 9216;
    const _Float16* w2r = W2r + (size_t)n * 9216;
    const _Float16* w2i = W2i + (size_t)n * 9216;

    half8 eC = *(const half8*)&Ec[(wr * 16 + lr) * 32 + quad * 8];
    half8 eS = *(const half8*)&Es[(wr * 16 + lr) * 32 + quad * 8];
    half8 eSn = -eS;

    // stage A: Z[kh][c] = DFT_h(X)
    {
        float4v zr[3], zi[3];
        #pragma unroll
        for (int j = 0; j < 3; ++j) { float4v z = {0,0,0,0}; zr[j] = z; zi[j] = z; }
        #pragma unroll
        for (int j = 0; j < 3; ++j) {
            int c = wc * 48 + j * 16 + lr;
            half8 xr = *(const half8*)&XTr[c * 40 + quad * 8];
            half8 xi = *(const half8*)&XTi[c * 40 + quad * 8];
            zr[j] = __builtin_amdgcn_mfma_f32_16x16x32_f16(eC,  xr, zr[j], 0, 0, 0);
            zr[j] = __builtin_amdgcn_mfma_f32_16x16x32_f16(eS,  xi, zr[j], 0, 0, 0);
            zi[j] = __builtin_amdgcn_mfma_f32_16x16x32_f16(eC,  xi, zi[j], 0, 0, 0);
            zi[j] = __builtin_amdgcn_mfma_f32_16x16x32_f16(eSn, xr, zi[j], 0, 0, 0);
        }
        #pragma unroll
        for (int j = 0; j < 3; ++j) {
            int c = wc * 48 + j * 16 + lr;
            #pragma unroll
            for (int r = 0; r < 4; ++r) {
                int kh = wr * 16 + quad * 4 + r;
                Zr[kh * 104 + c] = (_Float16)zr[j][r];
                Zi[kh * 104 + c] = (_Float16)zi[j][r];
            }
        }
    }
    __syncthreads();

    // stage B: S = gelu(Z @ W1 + b1)
    {
        float4v sr[3], si[3];
        #pragma unroll
        for (int j = 0; j < 3; ++j) { float4v z = {0,0,0,0}; sr[j] = z; si[j] = z; }
        #pragma unroll
        for (int kc = 0; kc < 3; ++kc) {
            half8 ar = *(const half8*)&Zr[(wr * 16 + lr) * 104 + kc * 32 + quad * 8];
            half8 ai = *(const half8*)&Zi[(wr * 16 + lr) * 104 + kc * 32 + quad * 8];
            half8 ain = -ai;
            #pragma unroll
            for (int j = 0; j < 3; ++j) {
                int o = wc * 48 + j * 16 + lr;
                half8 br = *(const half8*)&w1r[o * 96 + kc * 32 + quad * 8];
                half8 bi = *(const half8*)&w1i[o * 96 + kc * 32 + quad * 8];
                sr[j] = __builtin_amdgcn_mfma_f32_16x16x32_f16(ar,  br, sr[j], 0, 0, 0);
                sr[j] = __builtin_amdgcn_mfma_f32_16x16x32_f16(ain, bi, sr[j], 0, 0, 0);
                si[j] = __builtin_amdgcn_mfma_f32_16x16x32_f16(ai,  br, si[j], 0, 0, 0);
                si[j] = __builtin_amdgcn_mfma_f32_16x16x32_f16(ar,  bi, si[j], 0, 0, 0);
            }
        }
        #pragma unroll
        for (int j = 0; j < 3; ++j) {
            int o = wc * 48 + j * 16 + lr;
            float br = b1r[n * 96 + o], bi = b1i[n * 96 + o];
            #pragma unroll
            for (int r = 0; r < 4; ++r) {
                int kh = wr * 16 + quad * 4 + r;
                Sr[kh * 104 + o] = (_Float16)gelu_f(sr[j][r] + br);
                Si[kh * 104 + o] = (_Float16)gelu_f(si[j][r] + bi);
            }
        }
    }
    __syncthreads();

    // stage C: T = shrink(S @ W2 + b2) -> transposed T2T[o][kh] (alias XT)
    {
        float4v tr[3], ti[3];
        #pragma unroll
        for (int j = 0; j < 3; ++j) { float4v z = {0,0,0,0}; tr[j] = z; ti[j] = z; }
        #pragma unroll
        for (int kc = 0; kc < 3; ++kc) {
            half8 ar = *(const half8*)&Sr[(wr * 16 + lr) * 104 + kc * 32 + quad * 8];
            half8 ai = *(const half8*)&Si[(wr * 16 + lr) * 104 + kc * 32 + quad * 8];
            half8 ain = -ai;
            #pragma unroll
            for (int j = 0; j < 3; ++j) {
                int o = wc * 48 + j * 16 + lr;
                half8 br = *(const half8*)&w2r[o * 96 + kc * 32 + quad * 8];
                half8 bi = *(const half8*)&w2i[o * 96 + kc * 32 + quad * 8];
                tr[j] = __builtin_amdgcn_mfma_f32_16x16x32_f16(ar,  br, tr[j], 0, 0, 0);
                tr[j] = __builtin_amdgcn_mfma_f32_16x16x32_f16(ain, bi, tr[j], 0, 0, 0);
                ti[j] = __builtin_amdgcn_mfma_f32_16x16x32_f16(ai,  br, ti[j], 0, 0, 0);
                ti[j] = __builtin_amdgcn_mfma_f32_16x16x32_f16(ar,  bi, ti[j], 0, 0, 0);
            }
        }
        #pragma unroll
        for (int j = 0; j < 3; ++j) {
            int o = wc * 48 + j * 16 + lr;
            float br = b2r[n * 96 + o], bi = b2i[n * 96 + o];
            #pragma unroll
            for (int r = 0; r < 4; ++r) {
                int kh = wr * 16 + quad * 4 + r;
                XTr[o * 40 + kh] = (_Float16)shrink_f(tr[j][r] + br);
                XTi[o * 40 + kh] = (_Float16)shrink_f(ti[j][r] + bi);
            }
        }
    }
    __syncthreads();

    // stage D: Y[h][c] = IDFT_h(T2) -> Zr/Zi as [h][c] pad104
    {
        float4v yr[3], yi[3];
        #pragma unroll
        for (int j = 0; j < 3; ++j) { float4v z = {0,0,0,0}; yr[j] = z; yi[j] = z; }
        #pragma unroll
        for (int j = 0; j < 3; ++j) {
            int c = wc * 48 + j * 16 + lr;
            half8 t2r = *(const half8*)&XTr[c * 40 + quad * 8];
            half8 t2i = *(const half8*)&XTi[c * 40 + quad * 8];
            yr[j] = __builtin_amdgcn_mfma_f32_16x16x32_f16(eC,  t2r, yr[j], 0, 0, 0);
            yr[j] = __builtin_amdgcn_mfma_f32_16x16x32_f16(eSn, t2i, yr[j], 0, 0, 0);
            yi[j] = __builtin_amdgcn_mfma_f32_16x16x32_f16(eC,  t2i, yi[j], 0, 0, 0);
            yi[j] = __builtin_amdgcn_mfma_f32_16x16x32_f16(eS,  t2r, yi[j], 0, 0, 0);
        }
        #pragma unroll
        for (int j = 0; j < 3; ++j) {
            int c = wc * 48 + j * 16 + lr;
            #pragma unroll
            for (int r = 0; r < 4; ++r) {
                int h = wr * 16 + quad * 4 + r;
                Zr[h * 104 + c] = (_Float16)yr[j][r];
                Zi[h * 104 + c] = (_Float16)yi[j][r];
            }
        }
    }
    __syncthreads();

    // vector store back (in-place)
    for (int i = tid; i < 384; i += 256) {
        int h = i / 12, cc = (i % 12) * 8;
        half8 vr = *(const half8*)&Zr[h * 104 + cc];
        half8 vi = *(const half8*)&Zi[h * 104 + cc];
        *(half8*)(Xr + base + (size_t)h * 768 + cc) = vr;
        *(half8*)(Xi + base + (size_t)h * 768 + cc) = vi;
    }
}

// ---------------- f32 -> f16 elementwise (vectorized x4) ----------------
__global__ __launch_bounds__(256) void cvt_f16(const float* __restrict__ in,
        _Float16* __restrict__ out)
{
    int i = blockIdx.x * 256 + threadIdx.x;
    float4 v = ((const float4*)in)[i];
    half4v o;
    o.x = (_Float16)v.x; o.y = (_Float16)v.y; o.z = (_Float16)v.z; o.w = (_Float16)v.w;
    ((half4v*)out)[i] = o;
}

// ---------------- f32 [K][N] -> f16 [N][K] transpose ----------------
__global__ __launch_bounds__(256) void cvt_transpose(const float* __restrict__ in,
        _Float16* __restrict__ out, int K, int N)
{
    __shared__ float tile[32][33];
    int kb = blockIdx.x * 32, nb = blockIdx.y * 32;
    int tx = threadIdx.x & 31, ty = threadIdx.x >> 5;
    #pragma unroll
    for (int r = 0; r < 32; r += 8)
        tile[ty + r][tx] = in[(size_t)(kb + ty + r) * N + nb + tx];
    __syncthreads();
    #pragma unroll
    for (int r = 0; r < 32; r += 8)
        out[(size_t)(nb + ty + r) * K + kb + tx] = (_Float16)tile[tx][ty + r];
}

// ---------------- R12: 128x192-tile 8-wave GEMM, 2 blocks/CU (fc1 / head1) ----------------
// 8 waves = 2M x 4N, per-wave 64x48 (4 m-frags x 3 n-frags, 24 MFMA / K64-tile).
// BK=64, 2 LDS buffers: A 2x16KB + B 2x24KB = 80KB exactly -> 2 blocks/CU.
// Per tile: vmcnt(5) counted (never 0 mid-loop) -> barrier -> ds_read+MFMA -> barrier
// -> stage tile t+2 into just-freed buffer. 128B rows: full 8-chunk XOR swizzle
// (chunk ^= row&7) on BOTH gload_lds source and ds_read addr (rule #21).
template<int BN, int ACT>
__global__ __launch_bounds__(512, 4) void gemm128d(const _Float16* __restrict__ A,
        const _Float16* __restrict__ Bt, const float* __restrict__ bias,
        _Float16* __restrict__ C16, int M, int N, int K)
{
    constexpr int WN  = BN / 4;           // 48
    constexpr int FN  = WN / 16;          // 3
    constexpr int AU  = 2;                // A: 2 x 64-row units
    constexpr int BU  = BN / 64;          // 3
    constexpr int LPT = AU + BU;          // 5 loads/thread/K-tile
    __shared__ _Float16 Al[2][128 * 64];
    __shared__ _Float16 Bl[2][BN * 64];

    const int tid  = threadIdx.x;
    const int wave = tid >> 6;            // 0..7
    const int lane = tid & 63;
    const int wr   = wave >> 2;           // 0..1 (M)
    const int wc   = wave & 3;            // 0..3 (N)
    const int lr   = lane & 15;
    const int quad = lane >> 4;

    // XCD swizzle (2D): per-XCD contiguous patch for L2 reuse
    const int gx = gridDim.x, gy = gridDim.y, nbk = gx * gy;
    int bx = blockIdx.x, by = blockIdx.y;
    if (!(gy & 3) && !(gx & 1)) {
        int id = by * gx + bx;
        int xcd = id & 7, j = id >> 3;
        int cols = gx >> 1;
        int rows = gy >> 2;
        int jr = j / cols, jc = j % cols;
        by = (xcd >> 1) * rows + jr;
        bx = (xcd & 1) * cols + jc;
    } else if (!(nbk & 7)) {
        int id  = by * gx + bx;
        int id2 = (id & 7) * (nbk >> 3) + (id >> 3);
        by = id2 / gx; bx = id2 % gx;
    }
    const int row0 = by * 128;
    const int col0 = bx * BN;

    // staging: per 64-row unit (64x64 halfs = 8KB) each wave covers 8 rows.
    // lane l: row = l>>3, phys chunk = l&7, source logical chunk = (l&7)^(row&7).
    const int srow = lane >> 3;
    const int schk = (lane & 7) ^ (srow & 7);
    const _Float16* Ab = A  + (size_t)(row0 + wave * 8 + srow) * K + schk * 8;
    const _Float16* Bb = Bt + (size_t)(col0 + wave * 8 + srow) * K + schk * 8;

    auto stage = [&](int b, int kt) {
        const int k0 = kt * 64;
        #pragma unroll
        for (int u = 0; u < AU; ++u)
            async16(Ab + (size_t)u * 64 * K + k0, &Al[b][(u * 64 + wave * 8) * 64]);
        #pragma unroll
        for (int u = 0; u < BU; ++u)
            async16(Bb + (size_t)u * 64 * K + k0, &Bl[b][(u * 64 + wave * 8) * 64]);
    };

    float4v acc[4][FN];
    #pragma unroll
    for (int m = 0; m < 4; ++m)
        #pragma unroll
        for (int n = 0; n < FN; ++n) {
            float4v z = {0.f, 0.f, 0.f, 0.f};
            acc[m][n] = z;
        }

    auto compute = [&](int cb) {
        #pragma unroll
        for (int ks = 0; ks < 2; ++ks) {
            const int cA = ((ks * 4 + quad) ^ (lr & 7)) * 8;   // swizzled chunk (halfs)
            half8 bf[FN];
            #pragma unroll
            for (int n = 0; n < FN; ++n)
                bf[n] = *(const half8*)&Bl[cb][(wc * WN + n * 16 + lr) * 64 + cA];
            half8 af[4];
            #pragma unroll
            for (int m = 0; m < 4; ++m)
                af[m] = *(const half8*)&Al[cb][(wr * 64 + m * 16 + lr) * 64 + cA];
            __builtin_amdgcn_s_setprio(1);
            #pragma unroll
            for (int m = 0; m < 4; ++m)
                #pragma unroll
                for (int n = 0; n < FN; ++n)
                    acc[m][n] = __builtin_amdgcn_mfma_f32_16x16x32_f16(af[m], bf[n], acc[m][n], 0, 0, 0);
            __builtin_amdgcn_s_setprio(0);
        }
    };

    const int NT = K >> 6;                // K=768 -> 12 tiles
    stage(0, 0);
    stage(1, 1);
    for (int t = 0; t < NT; ++t) {
        if (t + 1 < NT) asm volatile("s_waitcnt vmcnt(5)" ::: "memory");
        else            asm volatile("s_waitcnt vmcnt(0)" ::: "memory");
        __builtin_amdgcn_s_barrier();     // all waves' tile-t loads visible
        compute(t & 1);
        __builtin_amdgcn_s_barrier();     // all waves done reading buf[t&1]
        if (t + 2 < NT) stage(t & 1, t + 2);   // prefetch into just-freed buffer
    }

    // epilogue: bias (+GELU) -> f16 store
    #pragma unroll
    for (int n = 0; n < FN; ++n) {
        int col = col0 + wc * WN + n * 16 + lr;
        float bj = bias[col];
        #pragma unroll
        for (int m = 0; m < 4; ++m) {
            int row = row0 + wr * 64 + m * 16 + quad * 4;
            #pragma unroll
            for (int r = 0; r < 4; ++r) {
                float v = acc[m][n][r] + bj;
                if (ACT) v = gelu_f(v);
                C16[(size_t)(row + r) * N + col] = (_Float16)v;
            }
        }
    }
}

// ---------------- R13: fc2 + fused forward W-DFT, 64x192 tile, 8 waves ----------------
// M=4096, N=768, K=3072 fixed. grid (4, 64) = 256 blocks = 1/CU.
// 8 waves = 2M x 4N, per-wave 32x48 (2 m x 3 n frags, 12 MFMA / BK=64 window).
// depth-2 counted vmcnt(4) (never 0 mid-loop); XOR-swizzled K-loop LDS (chunk^row&7
// on both gload_lds source and ds_read). Epilogue: t_h write + Tl[2][192][40]
// (pad-40 spreads banks; spec_fused-proven) + per-wave h-row DFT -> XR/XI.
__global__ __launch_bounds__(512, 2) void fc2_fused(const _Float16* __restrict__ A,
        const _Float16* __restrict__ Bt, const float* __restrict__ bias,
        _Float16* __restrict__ C16, _Float16* __restrict__ XR,
        _Float16* __restrict__ XI)
{
    constexpr int K = 3072;
    constexpr int NT = 48;
    __shared__ _Float16 Al[2][64 * 64];        // 16 KB
    __shared__ _Float16 Bl[2][192 * 64];       // 48 KB
    __shared__ alignas(16) _Float16 Tl[2 * 192 * 40];          // 30 KB  [h][c][w pad40]
    __shared__ alignas(16) _Float16 ECl[1024], ESl[1024];      // 4 KB

    const int tid  = threadIdx.x;
    const int wave = tid >> 6;            // 0..7
    const int lane = tid & 63;
    const int wr   = wave >> 2;           // 0..1 (M: 32-row half)
    const int wc   = wave & 3;            // 0..3 (N: 48-col quarter)
    const int lr   = lane & 15;
    const int quad = lane >> 4;

    // twiddle fill early (hides under prologue load latency)
    for (int i = tid; i < 1024; i += 512) {
        int kw = i >> 5, w = i & 31;
        float a = ((kw * w) & 31) * STEP32;
        ECl[i] = (_Float16)(cosf(a) * 0.03125f);
        ESl[i] = (_Float16)(-sinf(a) * 0.03125f);
    }

    // XCD swizzle (2D): gx=4, gy=64 -> cols=2, rows=16 per XCD patch
    const int gx = gridDim.x, gy = gridDim.y;
    int bx = blockIdx.x, by = blockIdx.y;
    {
        int id = by * gx + bx;
        int xcd = id & 7, j = id >> 3;
        int cols = gx >> 1;
        int rows = gy >> 2;
        int jr = j / cols, jc = j % cols;
        by = (xcd >> 1) * rows + jr;
        bx = (xcd & 1) * cols + jc;
    }
    const int row0 = by * 64;
    const int col0 = bx * 192;

    // staging: A 1 unit (64 rows), B 3 units; wave covers 8 rows/unit.
    const int srow = lane >> 3;
    const int schk = (lane & 7) ^ srow;
    const _Float16* Ab = A  + (size_t)(row0 + wave * 8 + srow) * K + schk * 8;
    const _Float16* Bb = Bt + (size_t)(col0 + wave * 8 + srow) * K + schk * 8;

    auto stage = [&](int b, int kt) {
        const int k0 = kt * 64;
        async16(Ab + k0, &Al[b][(wave * 8) * 64]);
        #pragma unroll
        for (int u = 0; u < 3; ++u)
            async16(Bb + (size_t)u * 64 * K + k0, &Bl[b][(u * 64 + wave * 8) * 64]);
    };

    float4v acc[2][3];
    #pragma unroll
    for (int m = 0; m < 2; ++m)
        #pragma unroll
        for (int n = 0; n < 3; ++n) {
            float4v z = {0.f, 0.f, 0.f, 0.f};
            acc[m][n] = z;
        }

    auto compute = [&](int cb) {
        #pragma unroll
        for (int ks = 0; ks < 2; ++ks) {
            const int cA = ((ks * 4 + quad) ^ (lr & 7)) * 8;   // swizzled chunk (halfs)
            half8 bf[3];
            #pragma unroll
            for (int n = 0; n < 3; ++n)
                bf[n] = *(const half8*)&Bl[cb][(wc * 48 + n * 16 + lr) * 64 + cA];
            half8 af[2];
            #pragma unroll
            for (int m = 0; m < 2; ++m)
                af[m] = *(const half8*)&Al[cb][(wr * 32 + m * 16 + lr) * 64 + cA];
            __builtin_amdgcn_s_setprio(1);
            #pragma unroll
            for (int m = 0; m < 2; ++m)
                #pragma unroll
                for (int n = 0; n < 3; ++n)
                    acc[m][n] = __builtin_amdgcn_mfma_f32_16x16x32_f16(af[m], bf[n], acc[m][n], 0, 0, 0);
            __builtin_amdgcn_s_setprio(0);
        }
    };

    stage(0, 0);
    stage(1, 1);
    for (int t = 0; t < NT; ++t) {
        if (t + 1 < NT) asm volatile("s_waitcnt vmcnt(4)" ::: "memory");
        else            asm volatile("s_waitcnt vmcnt(0)" ::: "memory");
        __builtin_amdgcn_s_barrier();
        compute(t & 1);
        __builtin_amdgcn_s_barrier();
        if (t + 2 < NT) stage(t & 1, t + 2);
    }

    // epilogue: bias -> t_h write + Tl staging ([h][c][w] pad40)
    #pragma unroll
    for (int n = 0; n < 3; ++n) {
        int cc  = wc * 48 + n * 16 + lr;
        int col = col0 + cc;
        float bj = bias[col];
        #pragma unroll
        for (int m = 0; m < 2; ++m) {
            int row = row0 + wr * 32 + m * 16 + quad * 4;
            #pragma unroll
            for (int r = 0; r < 4; ++r) {
                float v = acc[m][n][r] + bj;
                C16[(size_t)(row + r) * 768 + col] = (_Float16)v;
                int lrow = row + r - row0;
                Tl[((lrow >> 5) * 192 + cc) * 40 + (lrow & 31)] = (_Float16)v;
            }
        }
    }
    __syncthreads();

    // per-wave h-row DFT: wave handles h = wave>>2, cols (wave&3)*48..+47
    const int h     = wave >> 2;
    const int cbase = (wave & 3) * 48;
    const int b     = row0 >> 10;
    const int hp    = ((row0 >> 5) & 31) + h;
    half8 eC0 = *(const half8*)&ECl[lr * 32 + quad * 8];
    half8 eC1 = *(const half8*)&ECl[(16 + lr) * 32 + quad * 8];
    half8 eS0 = *(const half8*)&ESl[lr * 32 + quad * 8];
    half8 eS1 = *(const half8*)&ESl[(16 + lr) * 32 + quad * 8];
    float4v xr[2][3], xi[2][3];
    #pragma unroll
    for (int m = 0; m < 2; ++m)
        #pragma unroll
        for (int nj = 0; nj < 3; ++nj) {
            float4v z = {0.f, 0.f, 0.f, 0.f};
            xr[m][nj] = z; xi[m][nj] = z;
        }
    #pragma unroll
    for (int nj = 0; nj < 3; ++nj) {
        half8 tb = *(const half8*)&Tl[(h * 192 + cbase + nj * 16 + lr) * 40 + quad * 8];
        xr[0][nj] = __builtin_amdgcn_mfma_f32_16x16x32_f16(eC0, tb, xr[0][nj], 0, 0, 0);
        xr[1][nj] = __builtin_amdgcn_mfma_f32_16x16x32_f16(eC1, tb, xr[1][nj], 0, 0, 0);
        xi[0][nj] = __builtin_amdgcn_mfma_f32_16x16x32_f16(eS0, tb, xi[0][nj], 0, 0, 0);
        xi[1][nj] = __builtin_amdgcn_mfma_f32_16x16x32_f16(eS1, tb, xi[1][nj], 0, 0, 0);
    }
    #pragma unroll
    for (int m = 0; m < 2; ++m)
        #pragma unroll
        for (int r = 0; r < 4; ++r) {
            int kw = m * 16 + quad * 4 + r;
            if (kw < 17) {
                #pragma unroll
                for (int nj = 0; nj < 3; ++nj) {
                    int c = col0 + cbase + nj * 16 + lr;
                    size_t g = ((size_t)(b * 17 + kw) * 32 + hp) * 768 + c;
                    XR[g] = (_Float16)xr[m][nj][r];
                    XI[g] = (_Float16)xi[m][nj][r];
                }
            }
        }
}

// ---------------- fp16 MFMA GEMM, depth-3 counted-vmcnt pipeline, 2D-XCD swizzle ----------------
// OUT_MODE: 1 = f16, 3 = f32 pixel-shuffle scatter (head2).
template<int BN, int OUT_MODE, int ACT>
__global__ __launch_bounds__(256) void gemm_h(const _Float16* __restrict__ A,
        const _Float16* __restrict__ Bt, const float* __restrict__ bias,
        const float* __restrict__ pos, float* __restrict__ C32,
        _Float16* __restrict__ C16, _Float16* __restrict__ XR,
        _Float16* __restrict__ XI, int M, int N, int K, int f_idx)
{
    constexpr int WN  = BN / 2;
    constexpr int FN  = WN / 16;
    constexpr int NBJ = BN / 64;
    constexpr int LPT = 2 + NBJ;          // vmem loads per thread per K-tile
    __shared__ _Float16 Al[4][128 * 32];
    __shared__ _Float16 Bl[4][BN * 32];

    const int tid  = threadIdx.x;
    const int wave = tid >> 6;
    const int lane = tid & 63;
    const int wr   = wave >> 1;
    const int wc   = wave & 1;
    const int lr   = lane & 15;
    const int quad = lane >> 4;

    // XCD swizzle: prefer 2D (4 row-groups x 2 col-groups -> per-XCD A+B fits 4MB L2)
    const int gx = gridDim.x, gy = gridDim.y, nbk = gx * gy;
    int bx = blockIdx.x, by = blockIdx.y;
    if (!(gy & 3) && !(gx & 1)) {
        int id = by * gx + bx;
        int xcd = id & 7, j = id >> 3;
        int cols = gx >> 1;
        int rows = gy >> 2;
        int jr = j / cols, jc = j % cols;
        by = (xcd >> 1) * rows + jr;
        bx = (xcd & 1) * cols + jc;
    } else if (!(nbk & 7)) {
        int id  = by * gx + bx;
        int id2 = (id & 7) * (nbk >> 3) + (id >> 3);
        by = id2 / gx; bx = id2 % gx;
    }
    const int row0 = by * 128;
    const int col0 = bx * BN;

    // staging: rows of 32 halfs = 4 x 16B chunks; lane l: row = l>>2, phys chunk
    // l&3, source logical chunk = (l&3)^(row&3).
    const int srow = lane >> 2;
    const int skof = ((lane & 3) ^ (srow & 3)) * 8;

    auto stage = [&](int b, int kt) {
        const int k0 = kt << 5;
        #pragma unroll
        for (int j = 0; j < 2; ++j)
            async16(A + (size_t)(row0 + j * 64 + wave * 16 + srow) * K + k0 + skof,
                    &Al[b][(j * 64 + wave * 16) * 32]);
        #pragma unroll
        for (int j = 0; j < NBJ; ++j)
            async16(Bt + (size_t)(col0 + j * 64 + wave * 16 + srow) * K + k0 + skof,
                    &Bl[b][(j * 64 + wave * 16) * 32]);
    };

    float4v acc[4][FN];
    #pragma unroll
    for (int i = 0; i < 4; ++i)
        #pragma unroll
        for (int j = 0; j < FN; ++j) {
            float4v z = {0.f, 0.f, 0.f, 0.f};
            acc[i][j] = z;
        }

    auto compute = [&](int cb) {
        const int cA = (quad ^ (lr & 3)) * 8;   // swizzled chunk (halfs)
        half8 af[4], bf[FN];
        #pragma unroll
        for (int i = 0; i < 4; ++i)
            af[i] = *(const half8*)&Al[cb][(wr * 64 + i * 16 + lr) * 32 + cA];
        #pragma unroll
        for (int j = 0; j < FN; ++j)
            bf[j] = *(const half8*)&Bl[cb][(wc * WN + j * 16 + lr) * 32 + cA];
        #pragma unroll
        for (int i = 0; i < 4; ++i)
            #pragma unroll
            for (int j = 0; j < FN; ++j)
                acc[i][j] = __builtin_amdgcn_mfma_f32_16x16x32_f16(af[i], bf[j], acc[i][j], 0, 0, 0);
    };

    const int KT = K >> 5;                // K >= 768 -> KT >= 24 (always > 4)
    stage(0, 0); stage(1, 1); stage(2, 2);
    int kt = 0;
    for (; kt < KT - 3; ++kt) {
        stage((kt + 3) & 3, kt + 3);
        if constexpr (LPT == 4) asm volatile("s_waitcnt vmcnt(12)" ::: "memory");
        else                    asm volatile("s_waitcnt vmcnt(9)"  ::: "memory");
        __builtin_amdgcn_s_barrier();
        compute(kt & 3);
        asm volatile("" ::: "memory");
        __builtin_amdgcn_s_barrier();
    }
    // tail: 3 tiles in flight, no more staging; drain 2L -> L -> 0
    if constexpr (LPT == 4) asm volatile("s_waitcnt vmcnt(8)" ::: "memory");
    else                    asm volatile("s_waitcnt vmcnt(6)" ::: "memory");
    __builtin_amdgcn_s_barrier();
    compute(kt & 3); ++kt;
    asm volatile("" ::: "memory");
    __builtin_amdgcn_s_barrier();
    if constexpr (LPT == 4) asm volatile("s_waitcnt vmcnt(4)" ::: "memory");
    else                    asm volatile("s_waitcnt vmcnt(3)" ::: "memory");
    __builtin_amdgcn_s_barrier();
    compute(kt & 3); ++kt;
    asm volatile("" ::: "memory");
    __builtin_amdgcn_s_barrier();
    asm volatile("s_waitcnt vmcnt(0)" ::: "memory");
    __builtin_amdgcn_s_barrier();
    compute(kt & 3);

    #pragma unroll
    for (int j = 0; j < FN; ++j) {
        int col = col0 + wc * WN + j * 16 + lr;
        float bj = bias[col];
        #pragma unroll
        for (int i = 0; i < 4; ++i) {
            int row = row0 + wr * 64 + i * 16 + quad * 4;
            #pragma unroll
            for (int r = 0; r < 4; ++r) {
                float v = acc[i][j][r] + bj;
                if (pos) v += pos[(size_t)((row + r) & 1023) * N + col];
                if (ACT) v = gelu_f(v);
                if (OUT_MODE == 3) {
                    int rowv = row + r;
                    int bq = rowv >> 10, hp = (rowv >> 5) & 31, wp = rowv & 31;
                    int p = col >> 3, q = col & 7;
                    C32[(((size_t)(bq * 256 + hp * 8 + p)) * 256 + wp * 8 + q) * 4 + f_idx] = v;
                } else {
                    C16[(size_t)(row + r) * N + col] = (_Float16)v;
                }
            }
        }
    }
}

// ---------------- launch ----------------
extern "C" void kernel_launch(void* const* d_in, const int* in_sizes, int n_in,
                              void* d_out, int out_size, void* d_ws, size_t ws_size,
                              hipStream_t stream) {
    const float* x        = (const float*)d_in[0];
    const float* grd      = (const float*)d_in[1];
    const float* conv_w   = (const float*)d_in[2];
    const float* conv_b   = (const float*)d_in[3];
    const float* pos_emb  = (const float*)d_in[4];
    const float* w1       = (const float*)d_in[5];
    const float* b1       = (const float*)d_in[6];
    const float* w2       = (const float*)d_in[7];
    const float* b2       = (const float*)d_in[8];
    const float* fc1_w    = (const float*)d_in[9];
    const float* fc1_b    = (const float*)d_in[10];
    const float* fc2_w    = (const float*)d_in[11];
    const float* fc2_b    = (const float*)d_in[12];
    const float* head_w1  = (const float*)d_in[13];
    const float* head_b1  = (const float*)d_in[14];
    const float* head_w2  = (const float*)d_in[15];
    const float* head_b2  = (const float*)d_in[16];
    float* out = (float*)d_out;
    float* ws  = (float*)d_ws;

    // ---- workspace layout, sizes in float units ----
    float* pf = ws;
    _Float16* t_h     = (_Float16*)pf; pf += 1572864;   // 4096x768 f16 (residual state)
    _Float16* Wsp     = (_Float16*)pf; pf += 589824;    // 128x9216 f16 spectral weights
    _Float16* h1t     = (_Float16*)pf; pf += 589824;    // [1536][768] f16
    _Float16* h2t     = (_Float16*)pf; pf += 49152;     // [64][1536] f16
    _Float16* convw_h = (_Float16*)pf; pf += 294912;    // 768x768 f16 (prepass only)
    float* alias    = pf;              pf += 6291456;   // hid_h 4096x3072 f16
    _Float16* hid_h = (_Float16*)alias;
    _Float16* WtAll = (_Float16*)pf;   pf += 9437184;   // 8 x [N][K] fc weights f16
    // fallback xa inside alias (hid dead when xa live); full mode: dedicated xa after WtAll
    _Float16* xa_r_fb = (_Float16*)alias;
    _Float16* xa_i_fb = (_Float16*)(alias + 835584);
    _Float16* xa_r_fu = (_Float16*)pf;                  // +835,584 f
    _Float16* xa_i_fu = (_Float16*)(pf + 835584);       // +835,584 f
    size_t full_total = (size_t)(pf - ws) + 1671168;    // 20,496,384 f = 82.0 MB
    bool full = ws_size >= full_total * 4ull;
    _Float16* xa_r = full ? xa_r_fu : xa_r_fb;
    _Float16* xa_i = full ? xa_i_fu : xa_i_fb;
    _Float16* A_h  = (_Float16*)alias;                  // prepass-only (gather input, dead after)

    // ---- prepass ----
    prep_specw<<<dim3(128), 256, 0, stream>>>(w1, w2, Wsp);
    cvt_f16<<<dim3(576), 256, 0, stream>>>(conv_w, convw_h);
    cvt_transpose<<<dim3(24, 48), 256, 0, stream>>>(head_w1, h1t, 768, 1536);
    cvt_transpose<<<dim3(48, 2), 256, 0, stream>>>(head_w2, h2t, 1536, 64);
    for (int d = 0; d < 4; ++d) {
        cvt_transpose<<<dim3(24, 96), 256, 0, stream>>>(
            fc1_w + (size_t)d * 2359296, WtAll + (size_t)(2 * d) * 2359296, 768, 3072);
        cvt_transpose<<<dim3(96, 24), 256, 0, stream>>>(
            fc2_w + (size_t)d * 2359296, WtAll + (size_t)(2 * d + 1) * 2359296, 3072, 768);
    }
    gather_patch<<<dim3(12288), 256, 0, stream>>>(x, grd, A_h);
    gemm_h<128, 1, 0><<<dim3(6, 32), 256, 0, stream>>>(
        A_h, convw_h, conv_b, pos_emb, nullptr, t_h, nullptr, nullptr, 4096, 768, 768, 0);
    dft_fwd_w<<<dim3(128, 3), 256, 0, stream>>>(t_h, xa_r, xa_i);

    for (int f = 0; f < 4; ++f) {
        for (int d = 0; d < 4; ++d) {
            // fused H-DFT + complex MLP + H-IDFT (in-place on xa)
            spec_fused<<<dim3(68, 8), 256, 0, stream>>>(
                xa_r, xa_i,
                Wsp + (size_t)(d * 4 + 0) * 73728, Wsp + (size_t)(d * 4 + 1) * 73728,
                Wsp + (size_t)(d * 4 + 2) * 73728, Wsp + (size_t)(d * 4 + 3) * 73728,
                b1 + d * 1536, b1 + d * 1536 + 768,
                b2 + d * 1536, b2 + d * 1536 + 768);
            // irfft2 W-pass + f16 residual (in place on t_h)
            dft_inv_w<<<dim3(128, 3), 256, 0, stream>>>(xa_r, xa_i, t_h);
            // channel MLP fc1: 128x192 tile, 512 blocks = 2/CU
            gemm128d<192, 1><<<dim3(16, 32), 512, 0, stream>>>(
                t_h, WtAll + (size_t)(2 * d) * 2359296, fc1_b + d * 3072,
                hid_h, 4096, 3072, 768);
            if (full) {
                // fc2 + fused forward W-DFT (seeds xa for the next spectral block)
                fc2_fused<<<dim3(4, 64), 512, 0, stream>>>(
                    hid_h, WtAll + (size_t)(2 * d + 1) * 2359296, fc2_b + d * 768,
                    t_h, xa_r, xa_i);
            } else {
                gemm_h<64, 1, 0><<<dim3(12, 32), 256, 0, stream>>>(
                    hid_h, WtAll + (size_t)(2 * d + 1) * 2359296, fc2_b + d * 768,
                    nullptr, nullptr, t_h, nullptr, nullptr, 4096, 768, 3072, 0);
                dft_fwd_w<<<dim3(128, 3), 256, 0, stream>>>(t_h, xa_r, xa_i);
            }
        }
        // head on current state (t_h from fc2)
        gemm128d<192, 1><<<dim3(8, 32), 512, 0, stream>>>(
            t_h, h1t, head_b1, hid_h, 4096, 1536, 768);
        gemm_h<64, 3, 0><<<dim3(1, 32), 256, 0, stream>>>(
            hid_h, h2t, head_b2, nullptr, out, nullptr, nullptr, nullptr, 4096, 64, 1536, f);
    }
}

// Round 5
// 2023.504 us; speedup vs baseline: 1.3518x; 1.0740x over previous
//
#include <hip/hip_runtime.h>
#include <hip/hip_bf16.h>
#include <math.h>

// ---------------- static config ----------------
// B=4, H=W=256, TIN=10, F=4, P=8, CIN=12, E=768, NB=8, BS=96,
// HP=WP=32, MID=3072, DEPTH=4, LAM=0.01, WF=17, TOK=4096, POS=B*32*17=2176
// Spectral layout: X[((b*17+kw)*32 + h)*768 + c]   (h-rows contiguous per kw)
// R11/R12: gemm128d (128x192, 8 waves, 2 blk/CU, counted vmcnt) for fc1/head1.
// R13: fc2_fused 64x192 1blk/CU: bank conflicts 4.19M->156K (pad-40 Tl).
// R14: fc2_fused v2 -> 64x96 tile, 4 waves, grid (8,64)=512 blocks=2 blk/CU
//   (TLP covers the 2-phase barrier stall, same lever as R12 fc1). head2_k
//   replaces gemm_h<64,3> (32-block 12.5% fill -> 64 blocks, 4 blk/CU-capable).

typedef __attribute__((ext_vector_type(8))) _Float16 half8;
typedef __attribute__((ext_vector_type(4))) _Float16 half4v;
typedef __attribute__((ext_vector_type(4))) float float4v;

__device__ __forceinline__ float gelu_f(float v) {
    return 0.5f * v * (1.0f + erff(v * 0.70710678118654752f));
}
__device__ __forceinline__ float shrink_f(float v) {
    return (v > 0.01f) ? (v - 0.01f) : ((v < -0.01f) ? (v + 0.01f) : 0.0f);
}

#define STEP32 0.19634954084936207f  // 2*pi/32

// async 16B global->LDS (lds dest wave-uniform; HW adds lane*16)
__device__ __forceinline__ void async16(const void* g, void* l) {
    __builtin_amdgcn_global_load_lds(
        (const __attribute__((address_space(1))) unsigned int*)g,
        (__attribute__((address_space(3))) unsigned int*)l, 16, 0, 0);
}

// ---------------- gather patches into A_h [4096][768] f16 ----------------
__global__ __launch_bounds__(256) void gather_patch(const float* __restrict__ x,
        const float* __restrict__ grd, _Float16* __restrict__ A)
{
    int idx = blockIdx.x * 256 + threadIdx.x;
    int j   = idx % 768;
    int tok = idx / 768;
    int c = j >> 6, p = (j >> 3) & 7, q = j & 7;
    int wp = tok & 31, hp = (tok >> 5) & 31, b = tok >> 10;
    int hh = hp * 8 + p, ww = wp * 8 + q;
    float v;
    if (c < 10) v = x[((b * 256 + hh) * 256 + ww) * 10 + c];
    else        v = grd[((b * 256 + hh) * 256 + ww) * 2 + (c - 10)];
    A[idx] = (_Float16)v;
}

// ---------------- forward DFT along W (f16 in -> 17 complex f16), scale 1/32 ----------------
// prepass + fallback path. out layout [b,kw,h,c]
__global__ __launch_bounds__(256) void dft_fwd_w(const _Float16* __restrict__ th,
        _Float16* __restrict__ Xr, _Float16* __restrict__ Xi)
{
    __shared__ float2 lut[32];
    int bh = blockIdx.x;            // b*32 + h
    int tid = threadIdx.x;
    if (tid < 32) { float a = tid * STEP32; lut[tid] = make_float2(cosf(a), sinf(a)); }
    __syncthreads();
    int b = bh >> 5, h = bh & 31;
    int c = blockIdx.y * 256 + tid;
    float v[32];
    #pragma unroll
    for (int w = 0; w < 32; ++w) v[w] = (float)th[(bh * 32 + w) * 768 + c];
    for (int kw = 0; kw <= 16; ++kw) {
        float ar = 0.f, ai = 0.f;
        #pragma unroll
        for (int w = 0; w < 32; ++w) {
            float2 cs = lut[(kw * w) & 31];
            ar += v[w] * cs.x;
            ai -= v[w] * cs.y;
        }
        size_t g = ((size_t)(b * 17 + kw) * 32 + h) * 768 + c;
        Xr[g] = (_Float16)(ar * 0.03125f);
        Xi[g] = (_Float16)(ai * 0.03125f);
    }
}

// ---------------- inverse DFT along W (f16 in, [b,kw,h,c]) + f16 residual in-place ----------------
__global__ __launch_bounds__(256) void dft_inv_w(const _Float16* __restrict__ Yr,
        const _Float16* __restrict__ Yi, _Float16* __restrict__ th)
{
    __shared__ float2 lut[32];
    int bh = blockIdx.x;
    int tid = threadIdx.x;
    if (tid < 32) { float a = tid * STEP32; lut[tid] = make_float2(cosf(a), sinf(a)); }
    __syncthreads();
    int b = bh >> 5, h = bh & 31;
    int c = blockIdx.y * 256 + tid;
    float yr[17], yi[16];
    #pragma unroll
    for (int k = 0; k <= 16; ++k) yr[k] = (float)Yr[((size_t)(b * 17 + k) * 32 + h) * 768 + c];
    #pragma unroll
    for (int k = 1; k <= 15; ++k) yi[k] = (float)Yi[((size_t)(b * 17 + k) * 32 + h) * 768 + c];
    for (int w = 0; w < 32; ++w) {
        float val = yr[0] + ((w & 1) ? -yr[16] : yr[16]);
        #pragma unroll
        for (int k = 1; k <= 15; ++k) {
            float2 cs = lut[(k * w) & 31];
            val += 2.f * (yr[k] * cs.x - yi[k] * cs.y);
        }
        int gi = (bh * 32 + w) * 768 + c;
        th[gi] = (_Float16)(val * 0.03125f + (float)th[gi]);
    }
}

// ---------------- spectral weight prep: [i][o] fp32 -> [o][i] f16, 128 matrices ----------------
__global__ __launch_bounds__(256) void prep_specw(const float* __restrict__ w1,
        const float* __restrict__ w2, _Float16* __restrict__ out)
{
    __shared__ float tile[96][97];
    int mid = blockIdx.x;
    int n  = mid & 7;
    int ri = (mid >> 3) & 1;
    int l  = (mid >> 4) & 1;
    int d  = mid >> 5;
    const float* src = (l ? w2 : w1) + ((size_t)(d * 2 + ri) * 8 + n) * 9216;
    for (int idx = threadIdx.x; idx < 9216; idx += 256)
        tile[idx / 96][idx % 96] = src[idx];
    __syncthreads();
    _Float16* dst = out + (size_t)mid * 9216;
    for (int idx = threadIdx.x; idx < 9216; idx += 256)
        dst[idx] = (_Float16)tile[idx % 96][idx / 96];   // dst[o][i] = src[i][o]
}

// ---------------- fused spectral: H-DFT -> spec1(gelu) -> spec2(shrink) -> H-IDFT ----------------
// IN-PLACE on X ([b,kw,h,c] layout). grid (68 = b*17+kw, 8 = n); 256 thr = 4 waves.
__global__ __launch_bounds__(256) void spec_fused(
        _Float16* __restrict__ Xr, _Float16* __restrict__ Xi,
        const _Float16* __restrict__ W1r, const _Float16* __restrict__ W1i,
        const _Float16* __restrict__ W2r, const _Float16* __restrict__ W2i,
        const float* __restrict__ b1r, const float* __restrict__ b1i,
        const float* __restrict__ b2r, const float* __restrict__ b2i)
{
    __shared__ alignas(16) _Float16 Ec[1024], Es[1024];       // [m][k] twiddle 32x32
    __shared__ alignas(16) _Float16 XTr[3840], XTi[3840];     // [c][h] pad40; stage C: [o][kh]
    __shared__ alignas(16) _Float16 Zr[3328], Zi[3328];       // [kh][c] pad104; stage D out [h][c]
    __shared__ alignas(16) _Float16 Sr[3328], Si[3328];       // [kh][o] pad104

    const int bk = blockIdx.x;       // b*17 + kw
    const int n  = blockIdx.y;
    const int tid = threadIdx.x;
    const int wave = tid >> 6, lane = tid & 63;
    const int wr = wave >> 1, wc = wave & 1;
    const int lr = lane & 15, quad = lane >> 4;
    const size_t base = (size_t)bk * 24576 + n * 96;    // + h*768 + c

    for (int i = tid; i < 1024; i += 256) {
        int kh = i >> 5, h = i & 31;
        float a = ((kh * h) & 31) * STEP32;
        Ec[i] = (_Float16)cosf(a);
        Es[i] = (_Float16)sinf(a);
    }
    // vector load -> LDS transpose [c][h]
    for (int i = tid; i < 384; i += 256) {
        int h = i / 12, cc = (i % 12) * 8;
        half8 vr = *(const half8*)(Xr + base + (size_t)h * 768 + cc);
        half8 vi = *(const half8*)(Xi + base + (size_t)h * 768 + cc);
        #pragma unroll
        for (int e = 0; e < 8; ++e) {
            XTr[(cc + e) * 40 + h] = vr[e];
            XTi[(cc + e) * 40 + h] = vi[e];
        }
    }
    __syncthreads();

    const _Float16* w1r = W1r + (size_t)n * 9216;
    const _Float16* w1i = W1i + (size_t)n * 9216;
    const _Float16* w2r = W2r + (size_t)n * 9216;
    const _Float16* w2i = W2i + (size_t)n * 9216;

    half8 eC = *(const half8*)&Ec[(wr * 16 + lr) * 32 + quad * 8];
    half8 eS = *(const half8*)&Es[(wr * 16 + lr) * 32 + quad * 8];
    half8 eSn = -eS;

    // stage A: Z[kh][c] = DFT_h(X)
    {
        float4v zr[3], zi[3];
        #pragma unroll
        for (int j = 0; j < 3; ++j) { float4v z = {0,0,0,0}; zr[j] = z; zi[j] = z; }
        #pragma unroll
        for (int j = 0; j < 3; ++j) {
            int c = wc * 48 + j * 16 + lr;
            half8 xr = *(const half8*)&XTr[c * 40 + quad * 8];
            half8 xi = *(const half8*)&XTi[c * 40 + quad * 8];
            zr[j] = __builtin_amdgcn_mfma_f32_16x16x32_f16(eC,  xr, zr[j], 0, 0, 0);
            zr[j] = __builtin_amdgcn_mfma_f32_16x16x32_f16(eS,  xi, zr[j], 0, 0, 0);
            zi[j] = __builtin_amdgcn_mfma_f32_16x16x32_f16(eC,  xi, zi[j], 0, 0, 0);
            zi[j] = __builtin_amdgcn_mfma_f32_16x16x32_f16(eSn, xr, zi[j], 0, 0, 0);
        }
        #pragma unroll
        for (int j = 0; j < 3; ++j) {
            int c = wc * 48 + j * 16 + lr;
            #pragma unroll
            for (int r = 0; r < 4; ++r) {
                int kh = wr * 16 + quad * 4 + r;
                Zr[kh * 104 + c] = (_Float16)zr[j][r];
                Zi[kh * 104 + c] = (_Float16)zi[j][r];
            }
        }
    }
    __syncthreads();

    // stage B: S = gelu(Z @ W1 + b1)
    {
        float4v sr[3], si[3];
        #pragma unroll
        for (int j = 0; j < 3; ++j) { float4v z = {0,0,0,0}; sr[j] = z; si[j] = z; }
        #pragma unroll
        for (int kc = 0; kc < 3; ++kc) {
            half8 ar = *(const half8*)&Zr[(wr * 16 + lr) * 104 + kc * 32 + quad * 8];
            half8 ai = *(const half8*)&Zi[(wr * 16 + lr) * 104 + kc * 32 + quad * 8];
            half8 ain = -ai;
            #pragma unroll
            for (int j = 0; j < 3; ++j) {
                int o = wc * 48 + j * 16 + lr;
                half8 br = *(const half8*)&w1r[o * 96 + kc * 32 + quad * 8];
                half8 bi = *(const half8*)&w1i[o * 96 + kc * 32 + quad * 8];
                sr[j] = __builtin_amdgcn_mfma_f32_16x16x32_f16(ar,  br, sr[j], 0, 0, 0);
                sr[j] = __builtin_amdgcn_mfma_f32_16x16x32_f16(ain, bi, sr[j], 0, 0, 0);
                si[j] = __builtin_amdgcn_mfma_f32_16x16x32_f16(ai,  br, si[j], 0, 0, 0);
                si[j] = __builtin_amdgcn_mfma_f32_16x16x32_f16(ar,  bi, si[j], 0, 0, 0);
            }
        }
        #pragma unroll
        for (int j = 0; j < 3; ++j) {
            int o = wc * 48 + j * 16 + lr;
            float br = b1r[n * 96 + o], bi = b1i[n * 96 + o];
            #pragma unroll
            for (int r = 0; r < 4; ++r) {
                int kh = wr * 16 + quad * 4 + r;
                Sr[kh * 104 + o] = (_Float16)gelu_f(sr[j][r] + br);
                Si[kh * 104 + o] = (_Float16)gelu_f(si[j][r] + bi);
            }
        }
    }
    __syncthreads();

    // stage C: T = shrink(S @ W2 + b2) -> transposed T2T[o][kh] (alias XT)
    {
        float4v tr[3], ti[3];
        #pragma unroll
        for (int j = 0; j < 3; ++j) { float4v z = {0,0,0,0}; tr[j] = z; ti[j] = z; }
        #pragma unroll
        for (int kc = 0; kc < 3; ++kc) {
            half8 ar = *(const half8*)&Sr[(wr * 16 + lr) * 104 + kc * 32 + quad * 8];
            half8 ai = *(const half8*)&Si[(wr * 16 + lr) * 104 + kc * 32 + quad * 8];
            half8 ain = -ai;
            #pragma unroll
            for (int j = 0; j < 3; ++j) {
                int o = wc * 48 + j * 16 + lr;
                half8 br = *(const half8*)&w2r[o * 96 + kc * 32 + quad * 8];
                half8 bi = *(const half8*)&w2i[o * 96 + kc * 32 + quad * 8];
                tr[j] = __builtin_amdgcn_mfma_f32_16x16x32_f16(ar,  br, tr[j], 0, 0, 0);
                tr[j] = __builtin_amdgcn_mfma_f32_16x16x32_f16(ain, bi, tr[j], 0, 0, 0);
                ti[j] = __builtin_amdgcn_mfma_f32_16x16x32_f16(ai,  br, ti[j], 0, 0, 0);
                ti[j] = __builtin_amdgcn_mfma_f32_16x16x32_f16(ar,  bi, ti[j], 0, 0, 0);
            }
        }
        #pragma unroll
        for (int j = 0; j < 3; ++j) {
            int o = wc * 48 + j * 16 + lr;
            float br = b2r[n * 96 + o], bi = b2i[n * 96 + o];
            #pragma unroll
            for (int r = 0; r < 4; ++r) {
                int kh = wr * 16 + quad * 4 + r;
                XTr[o * 40 + kh] = (_Float16)shrink_f(tr[j][r] + br);
                XTi[o * 40 + kh] = (_Float16)shrink_f(ti[j][r] + bi);
            }
        }
    }
    __syncthreads();

    // stage D: Y[h][c] = IDFT_h(T2) -> Zr/Zi as [h][c] pad104
    {
        float4v yr[3], yi[3];
        #pragma unroll
        for (int j = 0; j < 3; ++j) { float4v z = {0,0,0,0}; yr[j] = z; yi[j] = z; }
        #pragma unroll
        for (int j = 0; j < 3; ++j) {
            int c = wc * 48 + j * 16 + lr;
            half8 t2r = *(const half8*)&XTr[c * 40 + quad * 8];
            half8 t2i = *(const half8*)&XTi[c * 40 + quad * 8];
            yr[j] = __builtin_amdgcn_mfma_f32_16x16x32_f16(eC,  t2r, yr[j], 0, 0, 0);
            yr[j] = __builtin_amdgcn_mfma_f32_16x16x32_f16(eSn, t2i, yr[j], 0, 0, 0);
            yi[j] = __builtin_amdgcn_mfma_f32_16x16x32_f16(eC,  t2i, yi[j], 0, 0, 0);
            yi[j] = __builtin_amdgcn_mfma_f32_16x16x32_f16(eS,  t2r, yi[j], 0, 0, 0);
        }
        #pragma unroll
        for (int j = 0; j < 3; ++j) {
            int c = wc * 48 + j * 16 + lr;
            #pragma unroll
            for (int r = 0; r < 4; ++r) {
                int h = wr * 16 + quad * 4 + r;
                Zr[h * 104 + c] = (_Float16)yr[j][r];
                Zi[h * 104 + c] = (_Float16)yi[j][r];
            }
        }
    }
    __syncthreads();

    // vector store back (in-place)
    for (int i = tid; i < 384; i += 256) {
        int h = i / 12, cc = (i % 12) * 8;
        half8 vr = *(const half8*)&Zr[h * 104 + cc];
        half8 vi = *(const half8*)&Zi[h * 104 + cc];
        *(half8*)(Xr + base + (size_t)h * 768 + cc) = vr;
        *(half8*)(Xi + base + (size_t)h * 768 + cc) = vi;
    }
}

// ---------------- f32 -> f16 elementwise (vectorized x4) ----------------
__global__ __launch_bounds__(256) void cvt_f16(const float* __restrict__ in,
        _Float16* __restrict__ out)
{
    int i = blockIdx.x * 256 + threadIdx.x;
    float4 v = ((const float4*)in)[i];
    half4v o;
    o.x = (_Float16)v.x; o.y = (_Float16)v.y; o.z = (_Float16)v.z; o.w = (_Float16)v.w;
    ((half4v*)out)[i] = o;
}

// ---------------- f32 [K][N] -> f16 [N][K] transpose ----------------
__global__ __launch_bounds__(256) void cvt_transpose(const float* __restrict__ in,
        _Float16* __restrict__ out, int K, int N)
{
    __shared__ float tile[32][33];
    int kb = blockIdx.x * 32, nb = blockIdx.y * 32;
    int tx = threadIdx.x & 31, ty = threadIdx.x >> 5;
    #pragma unroll
    for (int r = 0; r < 32; r += 8)
        tile[ty + r][tx] = in[(size_t)(kb + ty + r) * N + nb + tx];
    __syncthreads();
    #pragma unroll
    for (int r = 0; r < 32; r += 8)
        out[(size_t)(nb + ty + r) * K + kb + tx] = (_Float16)tile[tx][ty + r];
}

// ---------------- R12: 128x192-tile 8-wave GEMM, 2 blocks/CU (fc1 / head1) ----------------
// 8 waves = 2M x 4N, per-wave 64x48 (4 m-frags x 3 n-frags, 24 MFMA / K64-tile).
// BK=64, 2 LDS buffers: A 2x16KB + B 2x24KB = 80KB exactly -> 2 blocks/CU.
// Per tile: vmcnt(5) counted (never 0 mid-loop) -> barrier -> ds_read+MFMA -> barrier
// -> stage tile t+2 into just-freed buffer. 128B rows: full 8-chunk XOR swizzle
// (chunk ^= row&7) on BOTH gload_lds source and ds_read addr (rule #21).
template<int BN, int ACT>
__global__ __launch_bounds__(512, 4) void gemm128d(const _Float16* __restrict__ A,
        const _Float16* __restrict__ Bt, const float* __restrict__ bias,
        _Float16* __restrict__ C16, int M, int N, int K)
{
    constexpr int WN  = BN / 4;           // 48
    constexpr int FN  = WN / 16;          // 3
    constexpr int AU  = 2;                // A: 2 x 64-row units
    constexpr int BU  = BN / 64;          // 3
    constexpr int LPT = AU + BU;          // 5 loads/thread/K-tile
    __shared__ _Float16 Al[2][128 * 64];
    __shared__ _Float16 Bl[2][BN * 64];

    const int tid  = threadIdx.x;
    const int wave = tid >> 6;            // 0..7
    const int lane = tid & 63;
    const int wr   = wave >> 2;           // 0..1 (M)
    const int wc   = wave & 3;            // 0..3 (N)
    const int lr   = lane & 15;
    const int quad = lane >> 4;

    // XCD swizzle (2D): per-XCD contiguous patch for L2 reuse
    const int gx = gridDim.x, gy = gridDim.y, nbk = gx * gy;
    int bx = blockIdx.x, by = blockIdx.y;
    if (!(gy & 3) && !(gx & 1)) {
        int id = by * gx + bx;
        int xcd = id & 7, j = id >> 3;
        int cols = gx >> 1;
        int rows = gy >> 2;
        int jr = j / cols, jc = j % cols;
        by = (xcd >> 1) * rows + jr;
        bx = (xcd & 1) * cols + jc;
    } else if (!(nbk & 7)) {
        int id  = by * gx + bx;
        int id2 = (id & 7) * (nbk >> 3) + (id >> 3);
        by = id2 / gx; bx = id2 % gx;
    }
    const int row0 = by * 128;
    const int col0 = bx * BN;

    // staging: per 64-row unit (64x64 halfs = 8KB) each wave covers 8 rows.
    // lane l: row = l>>3, phys chunk = l&7, source logical chunk = (l&7)^(row&7).
    const int srow = lane >> 3;
    const int schk = (lane & 7) ^ (srow & 7);
    const _Float16* Ab = A  + (size_t)(row0 + wave * 8 + srow) * K + schk * 8;
    const _Float16* Bb = Bt + (size_t)(col0 + wave * 8 + srow) * K + schk * 8;

    auto stage = [&](int b, int kt) {
        const int k0 = kt * 64;
        #pragma unroll
        for (int u = 0; u < AU; ++u)
            async16(Ab + (size_t)u * 64 * K + k0, &Al[b][(u * 64 + wave * 8) * 64]);
        #pragma unroll
        for (int u = 0; u < BU; ++u)
            async16(Bb + (size_t)u * 64 * K + k0, &Bl[b][(u * 64 + wave * 8) * 64]);
    };

    float4v acc[4][FN];
    #pragma unroll
    for (int m = 0; m < 4; ++m)
        #pragma unroll
        for (int n = 0; n < FN; ++n) {
            float4v z = {0.f, 0.f, 0.f, 0.f};
            acc[m][n] = z;
        }

    auto compute = [&](int cb) {
        #pragma unroll
        for (int ks = 0; ks < 2; ++ks) {
            const int cA = ((ks * 4 + quad) ^ (lr & 7)) * 8;   // swizzled chunk (halfs)
            half8 bf[FN];
            #pragma unroll
            for (int n = 0; n < FN; ++n)
                bf[n] = *(const half8*)&Bl[cb][(wc * WN + n * 16 + lr) * 64 + cA];
            half8 af[4];
            #pragma unroll
            for (int m = 0; m < 4; ++m)
                af[m] = *(const half8*)&Al[cb][(wr * 64 + m * 16 + lr) * 64 + cA];
            __builtin_amdgcn_s_setprio(1);
            #pragma unroll
            for (int m = 0; m < 4; ++m)
                #pragma unroll
                for (int n = 0; n < FN; ++n)
                    acc[m][n] = __builtin_amdgcn_mfma_f32_16x16x32_f16(af[m], bf[n], acc[m][n], 0, 0, 0);
            __builtin_amdgcn_s_setprio(0);
        }
    };

    const int NT = K >> 6;                // K=768 -> 12 tiles
    stage(0, 0);
    stage(1, 1);
    for (int t = 0; t < NT; ++t) {
        if (t + 1 < NT) asm volatile("s_waitcnt vmcnt(5)" ::: "memory");
        else            asm volatile("s_waitcnt vmcnt(0)" ::: "memory");
        __builtin_amdgcn_s_barrier();     // all waves' tile-t loads visible
        compute(t & 1);
        __builtin_amdgcn_s_barrier();     // all waves done reading buf[t&1]
        if (t + 2 < NT) stage(t & 1, t + 2);   // prefetch into just-freed buffer
    }

    // epilogue: bias (+GELU) -> f16 store
    #pragma unroll
    for (int n = 0; n < FN; ++n) {
        int col = col0 + wc * WN + n * 16 + lr;
        float bj = bias[col];
        #pragma unroll
        for (int m = 0; m < 4; ++m) {
            int row = row0 + wr * 64 + m * 16 + quad * 4;
            #pragma unroll
            for (int r = 0; r < 4; ++r) {
                float v = acc[m][n][r] + bj;
                if (ACT) v = gelu_f(v);
                C16[(size_t)(row + r) * N + col] = (_Float16)v;
            }
        }
    }
}

// ---------------- R14: fc2 + fused forward W-DFT, 64x96 tile, 4 waves, 2 blk/CU ----------------
// M=4096, N=768, K=3072 fixed. grid (8, 64) = 512 blocks = 2/CU.
// 4 waves = 2M x 2N, per-wave 32x48 (2 m x 3 n frags, 12 MFMA / BK=64 window).
// depth-2 counted vmcnt(5); XOR-swizzled K-loop LDS. LDS 59KB -> 2 blocks/CU:
// co-resident block covers the 2-phase barrier stall (R12-proven lever).
// Epilogue: t_h write + Tl[2][96][40] pad-40 + per-wave h-row DFT -> XR/XI.
__global__ __launch_bounds__(256, 2) void fc2_fused(const _Float16* __restrict__ A,
        const _Float16* __restrict__ Bt, const float* __restrict__ bias,
        _Float16* __restrict__ C16, _Float16* __restrict__ XR,
        _Float16* __restrict__ XI)
{
    constexpr int K = 3072;
    constexpr int NT = 48;
    __shared__ _Float16 Al[2][64 * 64];        // 16 KB
    __shared__ _Float16 Bl[2][96 * 64];        // 24 KB
    __shared__ alignas(16) _Float16 Tl[2 * 96 * 40];           // 15 KB  [h][c][w pad40]
    __shared__ alignas(16) _Float16 ECl[1024], ESl[1024];      // 4 KB

    const int tid  = threadIdx.x;
    const int wave = tid >> 6;            // 0..3
    const int lane = tid & 63;
    const int wr   = wave >> 1;           // 0..1 (M: 32-row half)
    const int wc   = wave & 1;            // 0..1 (N: 48-col half)
    const int lr   = lane & 15;
    const int quad = lane >> 4;

    // twiddle fill early (hides under prologue load latency)
    for (int i = tid; i < 1024; i += 256) {
        int kw = i >> 5, w = i & 31;
        float a = ((kw * w) & 31) * STEP32;
        ECl[i] = (_Float16)(cosf(a) * 0.03125f);
        ESl[i] = (_Float16)(-sinf(a) * 0.03125f);
    }

    // XCD swizzle (2D): gx=8, gy=64 -> cols=4, rows=16 per XCD patch
    const int gx = gridDim.x, gy = gridDim.y;
    int bx = blockIdx.x, by = blockIdx.y;
    {
        int id = by * gx + bx;
        int xcd = id & 7, j = id >> 3;
        int cols = gx >> 1;
        int rows = gy >> 2;
        int jr = j / cols, jc = j % cols;
        by = (xcd >> 1) * rows + jr;
        bx = (xcd & 1) * cols + jc;
    }
    const int row0 = by * 64;
    const int col0 = bx * 96;

    // staging: 4 waves x 8 rows = 32 rows per issue-unit.
    const int srow = lane >> 3;
    const int schk = (lane & 7) ^ srow;
    const _Float16* Ab = A  + (size_t)(row0 + wave * 8 + srow) * K + schk * 8;
    const _Float16* Bb = Bt + (size_t)(col0 + wave * 8 + srow) * K + schk * 8;

    auto stage = [&](int b, int kt) {
        const int k0 = kt * 64;
        #pragma unroll
        for (int u = 0; u < 2; ++u)
            async16(Ab + (size_t)u * 32 * K + k0, &Al[b][(u * 32 + wave * 8) * 64]);
        #pragma unroll
        for (int u = 0; u < 3; ++u)
            async16(Bb + (size_t)u * 32 * K + k0, &Bl[b][(u * 32 + wave * 8) * 64]);
    };

    float4v acc[2][3];
    #pragma unroll
    for (int m = 0; m < 2; ++m)
        #pragma unroll
        for (int n = 0; n < 3; ++n) {
            float4v z = {0.f, 0.f, 0.f, 0.f};
            acc[m][n] = z;
        }

    auto compute = [&](int cb) {
        #pragma unroll
        for (int ks = 0; ks < 2; ++ks) {
            const int cA = ((ks * 4 + quad) ^ (lr & 7)) * 8;   // swizzled chunk (halfs)
            half8 bf[3];
            #pragma unroll
            for (int n = 0; n < 3; ++n)
                bf[n] = *(const half8*)&Bl[cb][(wc * 48 + n * 16 + lr) * 64 + cA];
            half8 af[2];
            #pragma unroll
            for (int m = 0; m < 2; ++m)
                af[m] = *(const half8*)&Al[cb][(wr * 32 + m * 16 + lr) * 64 + cA];
            __builtin_amdgcn_s_setprio(1);
            #pragma unroll
            for (int m = 0; m < 2; ++m)
                #pragma unroll
                for (int n = 0; n < 3; ++n)
                    acc[m][n] = __builtin_amdgcn_mfma_f32_16x16x32_f16(af[m], bf[n], acc[m][n], 0, 0, 0);
            __builtin_amdgcn_s_setprio(0);
        }
    };

    stage(0, 0);
    stage(1, 1);
    for (int t = 0; t < NT; ++t) {
        if (t + 1 < NT) asm volatile("s_waitcnt vmcnt(5)" ::: "memory");
        else            asm volatile("s_waitcnt vmcnt(0)" ::: "memory");
        __builtin_amdgcn_s_barrier();
        compute(t & 1);
        __builtin_amdgcn_s_barrier();
        if (t + 2 < NT) stage(t & 1, t + 2);
    }

    // epilogue: bias -> t_h write + Tl staging ([h][c][w] pad40)
    #pragma unroll
    for (int n = 0; n < 3; ++n) {
        int cc  = wc * 48 + n * 16 + lr;
        int col = col0 + cc;
        float bj = bias[col];
        #pragma unroll
        for (int m = 0; m < 2; ++m) {
            int row = row0 + wr * 32 + m * 16 + quad * 4;
            #pragma unroll
            for (int r = 0; r < 4; ++r) {
                float v = acc[m][n][r] + bj;
                C16[(size_t)(row + r) * 768 + col] = (_Float16)v;
                int lrow = row + r - row0;
                Tl[((lrow >> 5) * 96 + cc) * 40 + (lrow & 31)] = (_Float16)v;
            }
        }
    }
    __syncthreads();

    // per-wave h-row DFT: wave handles h = wave>>1, cols (wave&1)*48..+47
    const int h     = wave >> 1;
    const int cbase = (wave & 1) * 48;
    const int b     = row0 >> 10;
    const int hp    = ((row0 >> 5) & 31) + h;
    half8 eC0 = *(const half8*)&ECl[lr * 32 + quad * 8];
    half8 eC1 = *(const half8*)&ECl[(16 + lr) * 32 + quad * 8];
    half8 eS0 = *(const half8*)&ESl[lr * 32 + quad * 8];
    half8 eS1 = *(const half8*)&ESl[(16 + lr) * 32 + quad * 8];
    float4v xr[2][3], xi[2][3];
    #pragma unroll
    for (int m = 0; m < 2; ++m)
        #pragma unroll
        for (int nj = 0; nj < 3; ++nj) {
            float4v z = {0.f, 0.f, 0.f, 0.f};
            xr[m][nj] = z; xi[m][nj] = z;
        }
    #pragma unroll
    for (int nj = 0; nj < 3; ++nj) {
        half8 tb = *(const half8*)&Tl[(h * 96 + cbase + nj * 16 + lr) * 40 + quad * 8];
        xr[0][nj] = __builtin_amdgcn_mfma_f32_16x16x32_f16(eC0, tb, xr[0][nj], 0, 0, 0);
        xr[1][nj] = __builtin_amdgcn_mfma_f32_16x16x32_f16(eC1, tb, xr[1][nj], 0, 0, 0);
        xi[0][nj] = __builtin_amdgcn_mfma_f32_16x16x32_f16(eS0, tb, xi[0][nj], 0, 0, 0);
        xi[1][nj] = __builtin_amdgcn_mfma_f32_16x16x32_f16(eS1, tb, xi[1][nj], 0, 0, 0);
    }
    #pragma unroll
    for (int m = 0; m < 2; ++m)
        #pragma unroll
        for (int r = 0; r < 4; ++r) {
            int kw = m * 16 + quad * 4 + r;
            if (kw < 17) {
                #pragma unroll
                for (int nj = 0; nj < 3; ++nj) {
                    int c = col0 + cbase + nj * 16 + lr;
                    size_t g = ((size_t)(b * 17 + kw) * 32 + hp) * 768 + c;
                    XR[g] = (_Float16)xr[m][nj][r];
                    XI[g] = (_Float16)xi[m][nj][r];
                }
            }
        }
}

// ---------------- R14: head2 64x64 tile, 4 waves, counted-vmcnt, scatter out ----------------
// M=4096, N=64, K=1536. grid (64) blocks (vs old 32-block 12.5% fill).
// 4 waves = 2M x 2N, per-wave 32x32 (2m x 2n, 8 MFMA / BK=64 window). LDS 32KB.
__global__ __launch_bounds__(256, 4) void head2_k(const _Float16* __restrict__ A,
        const _Float16* __restrict__ Bt, const float* __restrict__ bias,
        float* __restrict__ C32, int f_idx)
{
    constexpr int K = 1536;
    constexpr int NT = 24;
    __shared__ _Float16 Al[2][64 * 64];   // 16 KB
    __shared__ _Float16 Bl[2][64 * 64];   // 16 KB

    const int tid  = threadIdx.x;
    const int wave = tid >> 6;            // 0..3
    const int lane = tid & 63;
    const int wr   = wave >> 1;
    const int wc   = wave & 1;
    const int lr   = lane & 15;
    const int quad = lane >> 4;

    const int row0 = blockIdx.x * 64;

    const int srow = lane >> 3;
    const int schk = (lane & 7) ^ srow;
    const _Float16* Ab = A  + (size_t)(row0 + wave * 8 + srow) * K + schk * 8;
    const _Float16* Bb = Bt + (size_t)(wave * 8 + srow) * K + schk * 8;

    auto stage = [&](int b, int kt) {
        const int k0 = kt * 64;
        #pragma unroll
        for (int u = 0; u < 2; ++u)
            async16(Ab + (size_t)u * 32 * K + k0, &Al[b][(u * 32 + wave * 8) * 64]);
        #pragma unroll
        for (int u = 0; u < 2; ++u)
            async16(Bb + (size_t)u * 32 * K + k0, &Bl[b][(u * 32 + wave * 8) * 64]);
    };

    float4v acc[2][2];
    #pragma unroll
    for (int m = 0; m < 2; ++m)
        #pragma unroll
        for (int n = 0; n < 2; ++n) {
            float4v z = {0.f, 0.f, 0.f, 0.f};
            acc[m][n] = z;
        }

    auto compute = [&](int cb) {
        #pragma unroll
        for (int ks = 0; ks < 2; ++ks) {
            const int cA = ((ks * 4 + quad) ^ (lr & 7)) * 8;
            half8 bf[2], af[2];
            #pragma unroll
            for (int n = 0; n < 2; ++n)
                bf[n] = *(const half8*)&Bl[cb][(wc * 32 + n * 16 + lr) * 64 + cA];
            #pragma unroll
            for (int m = 0; m < 2; ++m)
                af[m] = *(const half8*)&Al[cb][(wr * 32 + m * 16 + lr) * 64 + cA];
            #pragma unroll
            for (int m = 0; m < 2; ++m)
                #pragma unroll
                for (int n = 0; n < 2; ++n)
                    acc[m][n] = __builtin_amdgcn_mfma_f32_16x16x32_f16(af[m], bf[n], acc[m][n], 0, 0, 0);
        }
    };

    stage(0, 0);
    stage(1, 1);
    for (int t = 0; t < NT; ++t) {
        if (t + 1 < NT) asm volatile("s_waitcnt vmcnt(4)" ::: "memory");
        else            asm volatile("s_waitcnt vmcnt(0)" ::: "memory");
        __builtin_amdgcn_s_barrier();
        compute(t & 1);
        __builtin_amdgcn_s_barrier();
        if (t + 2 < NT) stage(t & 1, t + 2);
    }

    // scatter epilogue: out[b][h][w][f] pixel-shuffle
    #pragma unroll
    for (int n = 0; n < 2; ++n) {
        int col = wc * 32 + n * 16 + lr;
        float bj = bias[col];
        int p = col >> 3, q = col & 7;
        #pragma unroll
        for (int m = 0; m < 2; ++m) {
            int row = row0 + wr * 32 + m * 16 + quad * 4;
            #pragma unroll
            for (int r = 0; r < 4; ++r) {
                float v = acc[m][n][r] + bj;
                int rowv = row + r;
                int bq = rowv >> 10, hp = (rowv >> 5) & 31, wp = rowv & 31;
                C32[(((size_t)(bq * 256 + hp * 8 + p)) * 256 + wp * 8 + q) * 4 + f_idx] = v;
            }
        }
    }
}

// ---------------- fp16 MFMA GEMM, depth-3 counted-vmcnt pipeline, 2D-XCD swizzle ----------------
// OUT_MODE: 1 = f16 (conv prepass, fallback fc2).
template<int BN, int OUT_MODE, int ACT>
__global__ __launch_bounds__(256) void gemm_h(const _Float16* __restrict__ A,
        const _Float16* __restrict__ Bt, const float* __restrict__ bias,
        const float* __restrict__ pos, float* __restrict__ C32,
        _Float16* __restrict__ C16, _Float16* __restrict__ XR,
        _Float16* __restrict__ XI, int M, int N, int K, int f_idx)
{
    constexpr int WN  = BN / 2;
    constexpr int FN  = WN / 16;
    constexpr int NBJ = BN / 64;
    constexpr int LPT = 2 + NBJ;          // vmem loads per thread per K-tile
    __shared__ _Float16 Al[4][128 * 32];
    __shared__ _Float16 Bl[4][BN * 32];

    const int tid  = threadIdx.x;
    const int wave = tid >> 6;
    const int lane = tid & 63;
    const int wr   = wave >> 1;
    const int wc   = wave & 1;
    const int lr   = lane & 15;
    const int quad = lane >> 4;

    // XCD swizzle: prefer 2D (4 row-groups x 2 col-groups -> per-XCD A+B fits 4MB L2)
    const int gx = gridDim.x, gy = gridDim.y, nbk = gx * gy;
    int bx = blockIdx.x, by = blockIdx.y;
    if (!(gy & 3) && !(gx & 1)) {
        int id = by * gx + bx;
        int xcd = id & 7, j = id >> 3;
        int cols = gx >> 1;
        int rows = gy >> 2;
        int jr = j / cols, jc = j % cols;
        by = (xcd >> 1) * rows + jr;
        bx = (xcd & 1) * cols + jc;
    } else if (!(nbk & 7)) {
        int id  = by * gx + bx;
        int id2 = (id & 7) * (nbk >> 3) + (id >> 3);
        by = id2 / gx; bx = id2 % gx;
    }
    const int row0 = by * 128;
    const int col0 = bx * BN;

    // staging: rows of 32 halfs = 4 x 16B chunks; lane l: row = l>>2, phys chunk
    // l&3, source logical chunk = (l&3)^(row&3).
    const int srow = lane >> 2;
    const int skof = ((lane & 3) ^ (srow & 3)) * 8;

    auto stage = [&](int b, int kt) {
        const int k0 = kt << 5;
        #pragma unroll
        for (int j = 0; j < 2; ++j)
            async16(A + (size_t)(row0 + j * 64 + wave * 16 + srow) * K + k0 + skof,
                    &Al[b][(j * 64 + wave * 16) * 32]);
        #pragma unroll
        for (int j = 0; j < NBJ; ++j)
            async16(Bt + (size_t)(col0 + j * 64 + wave * 16 + srow) * K + k0 + skof,
                    &Bl[b][(j * 64 + wave * 16) * 32]);
    };

    float4v acc[4][FN];
    #pragma unroll
    for (int i = 0; i < 4; ++i)
        #pragma unroll
        for (int j = 0; j < FN; ++j) {
            float4v z = {0.f, 0.f, 0.f, 0.f};
            acc[i][j] = z;
        }

    auto compute = [&](int cb) {
        const int cA = (quad ^ (lr & 3)) * 8;   // swizzled chunk (halfs)
        half8 af[4], bf[FN];
        #pragma unroll
        for (int i = 0; i < 4; ++i)
            af[i] = *(const half8*)&Al[cb][(wr * 64 + i * 16 + lr) * 32 + cA];
        #pragma unroll
        for (int j = 0; j < FN; ++j)
            bf[j] = *(const half8*)&Bl[cb][(wc * WN + j * 16 + lr) * 32 + cA];
        #pragma unroll
        for (int i = 0; i < 4; ++i)
            #pragma unroll
            for (int j = 0; j < FN; ++j)
                acc[i][j] = __builtin_amdgcn_mfma_f32_16x16x32_f16(af[i], bf[j], acc[i][j], 0, 0, 0);
    };

    const int KT = K >> 5;                // K >= 768 -> KT >= 24 (always > 4)
    stage(0, 0); stage(1, 1); stage(2, 2);
    int kt = 0;
    for (; kt < KT - 3; ++kt) {
        stage((kt + 3) & 3, kt + 3);
        if constexpr (LPT == 4) asm volatile("s_waitcnt vmcnt(12)" ::: "memory");
        else                    asm volatile("s_waitcnt vmcnt(9)"  ::: "memory");
        __builtin_amdgcn_s_barrier();
        compute(kt & 3);
        asm volatile("" ::: "memory");
        __builtin_amdgcn_s_barrier();
    }
    // tail: 3 tiles in flight, no more staging; drain 2L -> L -> 0
    if constexpr (LPT == 4) asm volatile("s_waitcnt vmcnt(8)" ::: "memory");
    else                    asm volatile("s_waitcnt vmcnt(6)" ::: "memory");
    __builtin_amdgcn_s_barrier();
    compute(kt & 3); ++kt;
    asm volatile("" ::: "memory");
    __builtin_amdgcn_s_barrier();
    if constexpr (LPT == 4) asm volatile("s_waitcnt vmcnt(4)" ::: "memory");
    else                    asm volatile("s_waitcnt vmcnt(3)" ::: "memory");
    __builtin_amdgcn_s_barrier();
    compute(kt & 3); ++kt;
    asm volatile("" ::: "memory");
    __builtin_amdgcn_s_barrier();
    asm volatile("s_waitcnt vmcnt(0)" ::: "memory");
    __builtin_amdgcn_s_barrier();
    compute(kt & 3);

    #pragma unroll
    for (int j = 0; j < FN; ++j) {
        int col = col0 + wc * WN + j * 16 + lr;
        float bj = bias[col];
        #pragma unroll
        for (int i = 0; i < 4; ++i) {
            int row = row0 + wr * 64 + i * 16 + quad * 4;
            #pragma unroll
            for (int r = 0; r < 4; ++r) {
                float v = acc[i][j][r] + bj;
                if (pos) v += pos[(size_t)((row + r) & 1023) * N + col];
                if (ACT) v = gelu_f(v);
                if (OUT_MODE == 3) {
                    int rowv = row + r;
                    int bq = rowv >> 10, hp = (rowv >> 5) & 31, wp = rowv & 31;
                    int p = col >> 3, q = col & 7;
                    C32[(((size_t)(bq * 256 + hp * 8 + p)) * 256 + wp * 8 + q) * 4 + f_idx] = v;
                } else {
                    C16[(size_t)(row + r) * N + col] = (_Float16)v;
                }
            }
        }
    }
}

// ---------------- launch ----------------
extern "C" void kernel_launch(void* const* d_in, const int* in_sizes, int n_in,
                              void* d_out, int out_size, void* d_ws, size_t ws_size,
                              hipStream_t stream) {
    const float* x        = (const float*)d_in[0];
    const float* grd      = (const float*)d_in[1];
    const float* conv_w   = (const float*)d_in[2];
    const float* conv_b   = (const float*)d_in[3];
    const float* pos_emb  = (const float*)d_in[4];
    const float* w1       = (const float*)d_in[5];
    const float* b1       = (const float*)d_in[6];
    const float* w2       = (const float*)d_in[7];
    const float* b2       = (const float*)d_in[8];
    const float* fc1_w    = (const float*)d_in[9];
    const float* fc1_b    = (const float*)d_in[10];
    const float* fc2_w    = (const float*)d_in[11];
    const float* fc2_b    = (const float*)d_in[12];
    const float* head_w1  = (const float*)d_in[13];
    const float* head_b1  = (const float*)d_in[14];
    const float* head_w2  = (const float*)d_in[15];
    const float* head_b2  = (const float*)d_in[16];
    float* out = (float*)d_out;
    float* ws  = (float*)d_ws;

    // ---- workspace layout, sizes in float units ----
    float* pf = ws;
    _Float16* t_h     = (_Float16*)pf; pf += 1572864;   // 4096x768 f16 (residual state)
    _Float16* Wsp     = (_Float16*)pf; pf += 589824;    // 128x9216 f16 spectral weights
    _Float16* h1t     = (_Float16*)pf; pf += 589824;    // [1536][768] f16
    _Float16* h2t     = (_Float16*)pf; pf += 49152;     // [64][1536] f16
    _Float16* convw_h = (_Float16*)pf; pf += 294912;    // 768x768 f16 (prepass only)
    float* alias    = pf;              pf += 6291456;   // hid_h 4096x3072 f16
    _Float16* hid_h = (_Float16*)alias;
    _Float16* WtAll = (_Float16*)pf;   pf += 9437184;   // 8 x [N][K] fc weights f16
    // fallback xa inside alias (hid dead when xa live); full mode: dedicated xa after WtAll
    _Float16* xa_r_fb = (_Float16*)alias;
    _Float16* xa_i_fb = (_Float16*)(alias + 835584);
    _Float16* xa_r_fu = (_Float16*)pf;                  // +835,584 f
    _Float16* xa_i_fu = (_Float16*)(pf + 835584);       // +835,584 f
    size_t full_total = (size_t)(pf - ws) + 1671168;    // 20,496,384 f = 82.0 MB
    bool full = ws_size >= full_total * 4ull;
    _Float16* xa_r = full ? xa_r_fu : xa_r_fb;
    _Float16* xa_i = full ? xa_i_fu : xa_i_fb;
    _Float16* A_h  = (_Float16*)alias;                  // prepass-only (gather input, dead after)

    // ---- prepass ----
    prep_specw<<<dim3(128), 256, 0, stream>>>(w1, w2, Wsp);
    cvt_f16<<<dim3(576), 256, 0, stream>>>(conv_w, convw_h);
    cvt_transpose<<<dim3(24, 48), 256, 0, stream>>>(head_w1, h1t, 768, 1536);
    cvt_transpose<<<dim3(48, 2), 256, 0, stream>>>(head_w2, h2t, 1536, 64);
    for (int d = 0; d < 4; ++d) {
        cvt_transpose<<<dim3(24, 96), 256, 0, stream>>>(
            fc1_w + (size_t)d * 2359296, WtAll + (size_t)(2 * d) * 2359296, 768, 3072);
        cvt_transpose<<<dim3(96, 24), 256, 0, stream>>>(
            fc2_w + (size_t)d * 2359296, WtAll + (size_t)(2 * d + 1) * 2359296, 3072, 768);
    }
    gather_patch<<<dim3(12288), 256, 0, stream>>>(x, grd, A_h);
    gemm_h<128, 1, 0><<<dim3(6, 32), 256, 0, stream>>>(
        A_h, convw_h, conv_b, pos_emb, nullptr, t_h, nullptr, nullptr, 4096, 768, 768, 0);
    dft_fwd_w<<<dim3(128, 3), 256, 0, stream>>>(t_h, xa_r, xa_i);

    for (int f = 0; f < 4; ++f) {
        for (int d = 0; d < 4; ++d) {
            // fused H-DFT + complex MLP + H-IDFT (in-place on xa)
            spec_fused<<<dim3(68, 8), 256, 0, stream>>>(
                xa_r, xa_i,
                Wsp + (size_t)(d * 4 + 0) * 73728, Wsp + (size_t)(d * 4 + 1) * 73728,
                Wsp + (size_t)(d * 4 + 2) * 73728, Wsp + (size_t)(d * 4 + 3) * 73728,
                b1 + d * 1536, b1 + d * 1536 + 768,
                b2 + d * 1536, b2 + d * 1536 + 768);
            // irfft2 W-pass + f16 residual (in place on t_h)
            dft_inv_w<<<dim3(128, 3), 256, 0, stream>>>(xa_r, xa_i, t_h);
            // channel MLP fc1: 128x192 tile, 512 blocks = 2/CU
            gemm128d<192, 1><<<dim3(16, 32), 512, 0, stream>>>(
                t_h, WtAll + (size_t)(2 * d) * 2359296, fc1_b + d * 3072,
                hid_h, 4096, 3072, 768);
            if (full) {
                // fc2 + fused forward W-DFT (seeds xa for the next spectral block)
                fc2_fused<<<dim3(8, 64), 256, 0, stream>>>(
                    hid_h, WtAll + (size_t)(2 * d + 1) * 2359296, fc2_b + d * 768,
                    t_h, xa_r, xa_i);
            } else {
                gemm_h<64, 1, 0><<<dim3(12, 32), 256, 0, stream>>>(
                    hid_h, WtAll + (size_t)(2 * d + 1) * 2359296, fc2_b + d * 768,
                    nullptr, nullptr, t_h, nullptr, nullptr, 4096, 768, 3072, 0);
                dft_fwd_w<<<dim3(128, 3), 256, 0, stream>>>(t_h, xa_r, xa_i);
            }
        }
        // head on current state (t_h from fc2)
        gemm128d<192, 1><<<dim3(8, 32), 512, 0, stream>>>(
            t_h, h1t, head_b1, hid_h, 4096, 1536, 768);
        head2_k<<<dim3(64), 256, 0, stream>>>(
            hid_h, h2t, head_b2, out, f);
    }
}

// Round 7
// 1755.255 us; speedup vs baseline: 1.5584x; 1.1528x over previous
//
#include <hip/hip_runtime.h>
#include <hip/hip_bf16.h>
#include <math.h>

// ---------------- static config ----------------
// B=4, H=W=256, TIN=10, F=4, P=8, CIN=12, E=768, NB=8, BS=96,
// HP=WP=32, MID=3072, DEPTH=4, LAM=0.01, WF=17, TOK=4096, POS=B*32*17=2176
// Spectral layout: X[((b*17+kw)*32 + h)*768 + c]   (h-rows contiguous per kw)
// R12: gemm128d (128x192, 8 waves, 2 blk/CU, counted vmcnt) for fc1/head1.
// R13/R14: fc2_fused 64x96, 4 waves, 512 blocks = 2 blk/CU, pad-40 Tl epilogue.
// R15: idft_w_mfma replaces dft_inv_w in the main loop: the 32-point W-IDFT is
//   out[w][c] = E'[32x32slots] @ Y'[32slots][c], K=32 = ONE mfma_16x16x32 step.
//   grid (128 bh, 4 c-quarters) = 512 blocks, 4 waves; Y staged [c][slot] pad-40
//   (spec_fused-proven) with e^lane write perm (32->8-way banks); E' f16 with
//   1/32, x2 and -sin signs folded (same f16-twiddle precision as spec_fused).
// R16: resubmit of R15 (bench infra failed: container acquisition, no verdict).

typedef __attribute__((ext_vector_type(8))) _Float16 half8;
typedef __attribute__((ext_vector_type(4))) _Float16 half4v;
typedef __attribute__((ext_vector_type(4))) float float4v;

__device__ __forceinline__ float gelu_f(float v) {
    return 0.5f * v * (1.0f + erff(v * 0.70710678118654752f));
}
__device__ __forceinline__ float shrink_f(float v) {
    return (v > 0.01f) ? (v - 0.01f) : ((v < -0.01f) ? (v + 0.01f) : 0.0f);
}

#define STEP32 0.19634954084936207f  // 2*pi/32

// async 16B global->LDS (lds dest wave-uniform; HW adds lane*16)
__device__ __forceinline__ void async16(const void* g, void* l) {
    __builtin_amdgcn_global_load_lds(
        (const __attribute__((address_space(1))) unsigned int*)g,
        (__attribute__((address_space(3))) unsigned int*)l, 16, 0, 0);
}

// ---------------- gather patches into A_h [4096][768] f16 ----------------
__global__ __launch_bounds__(256) void gather_patch(const float* __restrict__ x,
        const float* __restrict__ grd, _Float16* __restrict__ A)
{
    int idx = blockIdx.x * 256 + threadIdx.x;
    int j   = idx % 768;
    int tok = idx / 768;
    int c = j >> 6, p = (j >> 3) & 7, q = j & 7;
    int wp = tok & 31, hp = (tok >> 5) & 31, b = tok >> 10;
    int hh = hp * 8 + p, ww = wp * 8 + q;
    float v;
    if (c < 10) v = x[((b * 256 + hh) * 256 + ww) * 10 + c];
    else        v = grd[((b * 256 + hh) * 256 + ww) * 2 + (c - 10)];
    A[idx] = (_Float16)v;
}

// ---------------- forward DFT along W (f16 in -> 17 complex f16), scale 1/32 ----------------
// prepass + fallback path. out layout [b,kw,h,c]
__global__ __launch_bounds__(256) void dft_fwd_w(const _Float16* __restrict__ th,
        _Float16* __restrict__ Xr, _Float16* __restrict__ Xi)
{
    __shared__ float2 lut[32];
    int bh = blockIdx.x;            // b*32 + h
    int tid = threadIdx.x;
    if (tid < 32) { float a = tid * STEP32; lut[tid] = make_float2(cosf(a), sinf(a)); }
    __syncthreads();
    int b = bh >> 5, h = bh & 31;
    int c = blockIdx.y * 256 + tid;
    float v[32];
    #pragma unroll
    for (int w = 0; w < 32; ++w) v[w] = (float)th[(bh * 32 + w) * 768 + c];
    for (int kw = 0; kw <= 16; ++kw) {
        float ar = 0.f, ai = 0.f;
        #pragma unroll
        for (int w = 0; w < 32; ++w) {
            float2 cs = lut[(kw * w) & 31];
            ar += v[w] * cs.x;
            ai -= v[w] * cs.y;
        }
        size_t g = ((size_t)(b * 17 + kw) * 32 + h) * 768 + c;
        Xr[g] = (_Float16)(ar * 0.03125f);
        Xi[g] = (_Float16)(ai * 0.03125f);
    }
}

// ---------------- R15: MFMA inverse W-DFT + f16 residual ----------------
// out[w][c] = sum_s E'[w][s] * Y'[s][c], slots s: 0..16 = yr[k=s] (x g_k),
// 17..31 = yi[k=s-16] (x -2). 1/32 folded into E'. K=32 = one 16x16x32 step.
// grid (128 = b*32+h, 4 = c-quarter of 192), 256 thr = 4 waves.
// Each wave: 48 c (3 n-frags) x 32 w (2 m-frags) = 6 MFMA.
// th updated in place: th += IDFT (same semantics as old dft_inv_w).
__global__ __launch_bounds__(256) void idft_w_mfma(const _Float16* __restrict__ Yr,
        const _Float16* __restrict__ Yi, _Float16* __restrict__ th)
{
    __shared__ alignas(16) _Float16 Yt[192 * 40];   // [c_local][slot] pad-40, 15 KB
    __shared__ alignas(16) _Float16 El[32 * 40];    // [w][slot] pad-40, 2.5 KB

    const int tid  = threadIdx.x;
    const int wave = tid >> 6;          // 0..3
    const int lane = tid & 63;
    const int lr   = lane & 15;
    const int quad = lane >> 4;

    const int bh = blockIdx.x;
    const int b  = bh >> 5, h = bh & 31;
    const int c0 = blockIdx.y * 192;

    // E' twiddles (f16, factors folded)
    for (int i = tid; i < 1024; i += 256) {
        int w = i >> 5, s = i & 31;
        float val;
        if (s <= 16) {
            float g = (s == 0 || s == 16) ? 1.f : 2.f;
            val = g * cosf(((w * s) & 31) * STEP32) * 0.03125f;
        } else {
            int k = s - 16;
            val = -2.f * sinf(((w * k) & 31) * STEP32) * 0.03125f;
        }
        El[w * 40 + s] = (_Float16)val;
    }

    // stage Y' -> Yt[c][slot]: 32 slots x 24 half8-groups = 768 units, 3/thread.
    // coalesced half8 loads; transpose scalar writes with e^(cg&7) perm
    // (spreads the 32-way same-bank write pattern to 8-way).
    #pragma unroll
    for (int i = 0; i < 3; ++i) {
        int u    = tid + i * 256;
        int slot = u / 24;
        int cg   = u % 24;
        const _Float16* src;
        if (slot < 17) src = Yr + ((size_t)(b * 17 + slot) * 32 + h) * 768;
        else           src = Yi + ((size_t)(b * 17 + (slot - 16)) * 32 + h) * 768;
        half8 v = *(const half8*)(src + c0 + cg * 8);
        #pragma unroll
        for (int e = 0; e < 8; ++e) {
            int el = e ^ (cg & 7);
            Yt[(cg * 8 + el) * 40 + slot] = v[el];
        }
    }
    __syncthreads();

    // MFMA: acc[m][n], m = w-half (0..1), n = c-frag (0..2)
    half8 af[2], bf[3];
    #pragma unroll
    for (int m = 0; m < 2; ++m)
        af[m] = *(const half8*)&El[(m * 16 + lr) * 40 + quad * 8];
    #pragma unroll
    for (int n = 0; n < 3; ++n)
        bf[n] = *(const half8*)&Yt[(wave * 48 + n * 16 + lr) * 40 + quad * 8];
    float4v acc[2][3];
    #pragma unroll
    for (int m = 0; m < 2; ++m)
        #pragma unroll
        for (int n = 0; n < 3; ++n) {
            float4v z = {0.f, 0.f, 0.f, 0.f};
            acc[m][n] = __builtin_amdgcn_mfma_f32_16x16x32_f16(af[m], bf[n], z, 0, 0, 0);
        }

    // residual RMW (same pattern as old dft_inv_w)
    #pragma unroll
    for (int m = 0; m < 2; ++m)
        #pragma unroll
        for (int n = 0; n < 3; ++n) {
            int c = c0 + wave * 48 + n * 16 + lr;
            #pragma unroll
            for (int r = 0; r < 4; ++r) {
                int w = m * 16 + quad * 4 + r;
                size_t gi = (size_t)(bh * 32 + w) * 768 + c;
                th[gi] = (_Float16)(acc[m][n][r] + (float)th[gi]);
            }
        }
}

// ---------------- spectral weight prep: [i][o] fp32 -> [o][i] f16, 128 matrices ----------------
__global__ __launch_bounds__(256) void prep_specw(const float* __restrict__ w1,
        const float* __restrict__ w2, _Float16* __restrict__ out)
{
    __shared__ float tile[96][97];
    int mid = blockIdx.x;
    int n  = mid & 7;
    int ri = (mid >> 3) & 1;
    int l  = (mid >> 4) & 1;
    int d  = mid >> 5;
    const float* src = (l ? w2 : w1) + ((size_t)(d * 2 + ri) * 8 + n) * 9216;
    for (int idx = threadIdx.x; idx < 9216; idx += 256)
        tile[idx / 96][idx % 96] = src[idx];
    __syncthreads();
    _Float16* dst = out + (size_t)mid * 9216;
    for (int idx = threadIdx.x; idx < 9216; idx += 256)
        dst[idx] = (_Float16)tile[idx % 96][idx / 96];   // dst[o][i] = src[i][o]
}

// ---------------- fused spectral: H-DFT -> spec1(gelu) -> spec2(shrink) -> H-IDFT ----------------
// IN-PLACE on X ([b,kw,h,c] layout). grid (68 = b*17+kw, 8 = n); 256 thr = 4 waves.
__global__ __launch_bounds__(256) void spec_fused(
        _Float16* __restrict__ Xr, _Float16* __restrict__ Xi,
        const _Float16* __restrict__ W1r, const _Float16* __restrict__ W1i,
        const _Float16* __restrict__ W2r, const _Float16* __restrict__ W2i,
        const float* __restrict__ b1r, const float* __restrict__ b1i,
        const float* __restrict__ b2r, const float* __restrict__ b2i)
{
    __shared__ alignas(16) _Float16 Ec[1024], Es[1024];       // [m][k] twiddle 32x32
    __shared__ alignas(16) _Float16 XTr[3840], XTi[3840];     // [c][h] pad40; stage C: [o][kh]
    __shared__ alignas(16) _Float16 Zr[3328], Zi[3328];       // [kh][c] pad104; stage D out [h][c]
    __shared__ alignas(16) _Float16 Sr[3328], Si[3328];       // [kh][o] pad104

    const int bk = blockIdx.x;       // b*17 + kw
    const int n  = blockIdx.y;
    const int tid = threadIdx.x;
    const int wave = tid >> 6, lane = tid & 63;
    const int wr = wave >> 1, wc = wave & 1;
    const int lr = lane & 15, quad = lane >> 4;
    const size_t base = (size_t)bk * 24576 + n * 96;    // + h*768 + c

    for (int i = tid; i < 1024; i += 256) {
        int kh = i >> 5, h = i & 31;
        float a = ((kh * h) & 31) * STEP32;
        Ec[i] = (_Float16)cosf(a);
        Es[i] = (_Float16)sinf(a);
    }
    // vector load -> LDS transpose [c][h]
    for (int i = tid; i < 384; i += 256) {
        int h = i / 12, cc = (i % 12) * 8;
        half8 vr = *(const half8*)(Xr + base + (size_t)h * 768 + cc);
        half8 vi = *(const half8*)(Xi + base + (size_t)h * 768 + cc);
        #pragma unroll
        for (int e = 0; e < 8; ++e) {
            XTr[(cc + e) * 40 + h] = vr[e];
            XTi[(cc + e) * 40 + h] = vi[e];
        }
    }
    __syncthreads();

    const _Float16* w1r = W1r + (size_t)n * 9216;
    const _Float16* w1i = W1i + (size_t)n * 9216;
    const _Float16* w2r = W2r + (size_t)n * 9216;
    const _Float16* w2i = W2i + (size_t)n * 9216;

    half8 eC = *(const half8*)&Ec[(wr * 16 + lr) * 32 + quad * 8];
    half8 eS = *(const half8*)&Es[(wr * 16 + lr) * 32 + quad * 8];
    half8 eSn = -eS;

    // stage A: Z[kh][c] = DFT_h(X)
    {
        float4v zr[3], zi[3];
        #pragma unroll
        for (int j = 0; j < 3; ++j) { float4v z = {0,0,0,0}; zr[j] = z; zi[j] = z; }
        #pragma unroll
        for (int j = 0; j < 3; ++j) {
            int c = wc * 48 + j * 16 + lr;
            half8 xr = *(const half8*)&XTr[c * 40 + quad * 8];
            half8 xi = *(const half8*)&XTi[c * 40 + quad * 8];
            zr[j] = __builtin_amdgcn_mfma_f32_16x16x32_f16(eC,  xr, zr[j], 0, 0, 0);
            zr[j] = __builtin_amdgcn_mfma_f32_16x16x32_f16(eS,  xi, zr[j], 0, 0, 0);
            zi[j] = __builtin_amdgcn_mfma_f32_16x16x32_f16(eC,  xi, zi[j], 0, 0, 0);
            zi[j] = __builtin_amdgcn_mfma_f32_16x16x32_f16(eSn, xr, zi[j], 0, 0, 0);
        }
        #pragma unroll
        for (int j = 0; j < 3; ++j) {
            int c = wc * 48 + j * 16 + lr;
            #pragma unroll
            for (int r = 0; r < 4; ++r) {
                int kh = wr * 16 + quad * 4 + r;
                Zr[kh * 104 + c] = (_Float16)zr[j][r];
                Zi[kh * 104 + c] = (_Float16)zi[j][r];
            }
        }
    }
    __syncthreads();

    // stage B: S = gelu(Z @ W1 + b1)
    {
        float4v sr[3], si[3];
        #pragma unroll
        for (int j = 0; j < 3; ++j) { float4v z = {0,0,0,0}; sr[j] = z; si[j] = z; }
        #pragma unroll
        for (int kc = 0; kc < 3; ++kc) {
            half8 ar = *(const half8*)&Zr[(wr * 16 + lr) * 104 + kc * 32 + quad * 8];
            half8 ai = *(const half8*)&Zi[(wr * 16 + lr) * 104 + kc * 32 + quad * 8];
            half8 ain = -ai;
            #pragma unroll
            for (int j = 0; j < 3; ++j) {
                int o = wc * 48 + j * 16 + lr;
                half8 br = *(const half8*)&w1r[o * 96 + kc * 32 + quad * 8];
                half8 bi = *(const half8*)&w1i[o * 96 + kc * 32 + quad * 8];
                sr[j] = __builtin_amdgcn_mfma_f32_16x16x32_f16(ar,  br, sr[j], 0, 0, 0);
                sr[j] = __builtin_amdgcn_mfma_f32_16x16x32_f16(ain, bi, sr[j], 0, 0, 0);
                si[j] = __builtin_amdgcn_mfma_f32_16x16x32_f16(ai,  br, si[j], 0, 0, 0);
                si[j] = __builtin_amdgcn_mfma_f32_16x16x32_f16(ar,  bi, si[j], 0, 0, 0);
            }
        }
        #pragma unroll
        for (int j = 0; j < 3; ++j) {
            int o = wc * 48 + j * 16 + lr;
            float br = b1r[n * 96 + o], bi = b1i[n * 96 + o];
            #pragma unroll
            for (int r = 0; r < 4; ++r) {
                int kh = wr * 16 + quad * 4 + r;
                Sr[kh * 104 + o] = (_Float16)gelu_f(sr[j][r] + br);
                Si[kh * 104 + o] = (_Float16)gelu_f(si[j][r] + bi);
            }
        }
    }
    __syncthreads();

    // stage C: T = shrink(S @ W2 + b2) -> transposed T2T[o][kh] (alias XT)
    {
        float4v tr[3], ti[3];
        #pragma unroll
        for (int j = 0; j < 3; ++j) { float4v z = {0,0,0,0}; tr[j] = z; ti[j] = z; }
        #pragma unroll
        for (int kc = 0; kc < 3; ++kc) {
            half8 ar = *(const half8*)&Sr[(wr * 16 + lr) * 104 + kc * 32 + quad * 8];
            half8 ai = *(const half8*)&Si[(wr * 16 + lr) * 104 + kc * 32 + quad * 8];
            half8 ain = -ai;
            #pragma unroll
            for (int j = 0; j < 3; ++j) {
                int o = wc * 48 + j * 16 + lr;
                half8 br = *(const half8*)&w2r[o * 96 + kc * 32 + quad * 8];
                half8 bi = *(const half8*)&w2i[o * 96 + kc * 32 + quad * 8];
                tr[j] = __builtin_amdgcn_mfma_f32_16x16x32_f16(ar,  br, tr[j], 0, 0, 0);
                tr[j] = __builtin_amdgcn_mfma_f32_16x16x32_f16(ain, bi, tr[j], 0, 0, 0);
                ti[j] = __builtin_amdgcn_mfma_f32_16x16x32_f16(ai,  br, ti[j], 0, 0, 0);
                ti[j] = __builtin_amdgcn_mfma_f32_16x16x32_f16(ar,  bi, ti[j], 0, 0, 0);
            }
        }
        #pragma unroll
        for (int j = 0; j < 3; ++j) {
            int o = wc * 48 + j * 16 + lr;
            float br = b2r[n * 96 + o], bi = b2i[n * 96 + o];
            #pragma unroll
            for (int r = 0; r < 4; ++r) {
                int kh = wr * 16 + quad * 4 + r;
                XTr[o * 40 + kh] = (_Float16)shrink_f(tr[j][r] + br);
                XTi[o * 40 + kh] = (_Float16)shrink_f(ti[j][r] + bi);
            }
        }
    }
    __syncthreads();

    // stage D: Y[h][c] = IDFT_h(T2) -> Zr/Zi as [h][c] pad104
    {
        float4v yr[3], yi[3];
        #pragma unroll
        for (int j = 0; j < 3; ++j) { float4v z = {0,0,0,0}; yr[j] = z; yi[j] = z; }
        #pragma unroll
        for (int j = 0; j < 3; ++j) {
            int c = wc * 48 + j * 16 + lr;
            half8 t2r = *(const half8*)&XTr[c * 40 + quad * 8];
            half8 t2i = *(const half8*)&XTi[c * 40 + quad * 8];
            yr[j] = __builtin_amdgcn_mfma_f32_16x16x32_f16(eC,  t2r, yr[j], 0, 0, 0);
            yr[j] = __builtin_amdgcn_mfma_f32_16x16x32_f16(eSn, t2i, yr[j], 0, 0, 0);
            yi[j] = __builtin_amdgcn_mfma_f32_16x16x32_f16(eC,  t2i, yi[j], 0, 0, 0);
            yi[j] = __builtin_amdgcn_mfma_f32_16x16x32_f16(eS,  t2r, yi[j], 0, 0, 0);
        }
        #pragma unroll
        for (int j = 0; j < 3; ++j) {
            int c = wc * 48 + j * 16 + lr;
            #pragma unroll
            for (int r = 0; r < 4; ++r) {
                int h = wr * 16 + quad * 4 + r;
                Zr[h * 104 + c] = (_Float16)yr[j][r];
                Zi[h * 104 + c] = (_Float16)yi[j][r];
            }
        }
    }
    __syncthreads();

    // vector store back (in-place)
    for (int i = tid; i < 384; i += 256) {
        int h = i / 12, cc = (i % 12) * 8;
        half8 vr = *(const half8*)&Zr[h * 104 + cc];
        half8 vi = *(const half8*)&Zi[h * 104 + cc];
        *(half8*)(Xr + base + (size_t)h * 768 + cc) = vr;
        *(half8*)(Xi + base + (size_t)h * 768 + cc) = vi;
    }
}

// ---------------- f32 -> f16 elementwise (vectorized x4) ----------------
__global__ __launch_bounds__(256) void cvt_f16(const float* __restrict__ in,
        _Float16* __restrict__ out)
{
    int i = blockIdx.x * 256 + threadIdx.x;
    float4 v = ((const float4*)in)[i];
    half4v o;
    o.x = (_Float16)v.x; o.y = (_Float16)v.y; o.z = (_Float16)v.z; o.w = (_Float16)v.w;
    ((half4v*)out)[i] = o;
}

// ---------------- f32 [K][N] -> f16 [N][K] transpose ----------------
__global__ __launch_bounds__(256) void cvt_transpose(const float* __restrict__ in,
        _Float16* __restrict__ out, int K, int N)
{
    __shared__ float tile[32][33];
    int kb = blockIdx.x * 32, nb = blockIdx.y * 32;
    int tx = threadIdx.x & 31, ty = threadIdx.x >> 5;
    #pragma unroll
    for (int r = 0; r < 32; r += 8)
        tile[ty + r][tx] = in[(size_t)(kb + ty + r) * N + nb + tx];
    __syncthreads();
    #pragma unroll
    for (int r = 0; r < 32; r += 8)
        out[(size_t)(nb + ty + r) * K + kb + tx] = (_Float16)tile[tx][ty + r];
}

// ---------------- R12: 128x192-tile 8-wave GEMM, 2 blocks/CU (fc1 / head1) ----------------
template<int BN, int ACT>
__global__ __launch_bounds__(512, 4) void gemm128d(const _Float16* __restrict__ A,
        const _Float16* __restrict__ Bt, const float* __restrict__ bias,
        _Float16* __restrict__ C16, int M, int N, int K)
{
    constexpr int WN  = BN / 4;           // 48
    constexpr int FN  = WN / 16;          // 3
    constexpr int AU  = 2;                // A: 2 x 64-row units
    constexpr int BU  = BN / 64;          // 3
    constexpr int LPT = AU + BU;          // 5 loads/thread/K-tile
    __shared__ _Float16 Al[2][128 * 64];
    __shared__ _Float16 Bl[2][BN * 64];

    const int tid  = threadIdx.x;
    const int wave = tid >> 6;            // 0..7
    const int lane = tid & 63;
    const int wr   = wave >> 2;           // 0..1 (M)
    const int wc   = wave & 3;            // 0..3 (N)
    const int lr   = lane & 15;
    const int quad = lane >> 4;

    // XCD swizzle (2D): per-XCD contiguous patch for L2 reuse
    const int gx = gridDim.x, gy = gridDim.y, nbk = gx * gy;
    int bx = blockIdx.x, by = blockIdx.y;
    if (!(gy & 3) && !(gx & 1)) {
        int id = by * gx + bx;
        int xcd = id & 7, j = id >> 3;
        int cols = gx >> 1;
        int rows = gy >> 2;
        int jr = j / cols, jc = j % cols;
        by = (xcd >> 1) * rows + jr;
        bx = (xcd & 1) * cols + jc;
    } else if (!(nbk & 7)) {
        int id  = by * gx + bx;
        int id2 = (id & 7) * (nbk >> 3) + (id >> 3);
        by = id2 / gx; bx = id2 % gx;
    }
    const int row0 = by * 128;
    const int col0 = bx * BN;

    // staging: per 64-row unit (64x64 halfs = 8KB) each wave covers 8 rows.
    const int srow = lane >> 3;
    const int schk = (lane & 7) ^ (srow & 7);
    const _Float16* Ab = A  + (size_t)(row0 + wave * 8 + srow) * K + schk * 8;
    const _Float16* Bb = Bt + (size_t)(col0 + wave * 8 + srow) * K + schk * 8;

    auto stage = [&](int b, int kt) {
        const int k0 = kt * 64;
        #pragma unroll
        for (int u = 0; u < AU; ++u)
            async16(Ab + (size_t)u * 64 * K + k0, &Al[b][(u * 64 + wave * 8) * 64]);
        #pragma unroll
        for (int u = 0; u < BU; ++u)
            async16(Bb + (size_t)u * 64 * K + k0, &Bl[b][(u * 64 + wave * 8) * 64]);
    };

    float4v acc[4][FN];
    #pragma unroll
    for (int m = 0; m < 4; ++m)
        #pragma unroll
        for (int n = 0; n < FN; ++n) {
            float4v z = {0.f, 0.f, 0.f, 0.f};
            acc[m][n] = z;
        }

    auto compute = [&](int cb) {
        #pragma unroll
        for (int ks = 0; ks < 2; ++ks) {
            const int cA = ((ks * 4 + quad) ^ (lr & 7)) * 8;   // swizzled chunk (halfs)
            half8 bf[FN];
            #pragma unroll
            for (int n = 0; n < FN; ++n)
                bf[n] = *(const half8*)&Bl[cb][(wc * WN + n * 16 + lr) * 64 + cA];
            half8 af[4];
            #pragma unroll
            for (int m = 0; m < 4; ++m)
                af[m] = *(const half8*)&Al[cb][(wr * 64 + m * 16 + lr) * 64 + cA];
            __builtin_amdgcn_s_setprio(1);
            #pragma unroll
            for (int m = 0; m < 4; ++m)
                #pragma unroll
                for (int n = 0; n < FN; ++n)
                    acc[m][n] = __builtin_amdgcn_mfma_f32_16x16x32_f16(af[m], bf[n], acc[m][n], 0, 0, 0);
            __builtin_amdgcn_s_setprio(0);
        }
    };

    const int NT = K >> 6;                // K=768 -> 12 tiles
    stage(0, 0);
    stage(1, 1);
    for (int t = 0; t < NT; ++t) {
        if (t + 1 < NT) asm volatile("s_waitcnt vmcnt(5)" ::: "memory");
        else            asm volatile("s_waitcnt vmcnt(0)" ::: "memory");
        __builtin_amdgcn_s_barrier();     // all waves' tile-t loads visible
        compute(t & 1);
        __builtin_amdgcn_s_barrier();     // all waves done reading buf[t&1]
        if (t + 2 < NT) stage(t & 1, t + 2);   // prefetch into just-freed buffer
    }

    // epilogue: bias (+GELU) -> f16 store
    #pragma unroll
    for (int n = 0; n < FN; ++n) {
        int col = col0 + wc * WN + n * 16 + lr;
        float bj = bias[col];
        #pragma unroll
        for (int m = 0; m < 4; ++m) {
            int row = row0 + wr * 64 + m * 16 + quad * 4;
            #pragma unroll
            for (int r = 0; r < 4; ++r) {
                float v = acc[m][n][r] + bj;
                if (ACT) v = gelu_f(v);
                C16[(size_t)(row + r) * N + col] = (_Float16)v;
            }
        }
    }
}

// ---------------- R14: fc2 + fused forward W-DFT, 64x96 tile, 4 waves, 2 blk/CU ----------------
__global__ __launch_bounds__(256, 2) void fc2_fused(const _Float16* __restrict__ A,
        const _Float16* __restrict__ Bt, const float* __restrict__ bias,
        _Float16* __restrict__ C16, _Float16* __restrict__ XR,
        _Float16* __restrict__ XI)
{
    constexpr int K = 3072;
    constexpr int NT = 48;
    __shared__ _Float16 Al[2][64 * 64];        // 16 KB
    __shared__ _Float16 Bl[2][96 * 64];        // 24 KB
    __shared__ alignas(16) _Float16 Tl[2 * 96 * 40];           // 15 KB  [h][c][w pad40]
    __shared__ alignas(16) _Float16 ECl[1024], ESl[1024];      // 4 KB

    const int tid  = threadIdx.x;
    const int wave = tid >> 6;            // 0..3
    const int lane = tid & 63;
    const int wr   = wave >> 1;           // 0..1 (M: 32-row half)
    const int wc   = wave & 1;            // 0..1 (N: 48-col half)
    const int lr   = lane & 15;
    const int quad = lane >> 4;

    // twiddle fill early (hides under prologue load latency)
    for (int i = tid; i < 1024; i += 256) {
        int kw = i >> 5, w = i & 31;
        float a = ((kw * w) & 31) * STEP32;
        ECl[i] = (_Float16)(cosf(a) * 0.03125f);
        ESl[i] = (_Float16)(-sinf(a) * 0.03125f);
    }

    // XCD swizzle (2D): gx=8, gy=64 -> cols=4, rows=16 per XCD patch
    const int gx = gridDim.x, gy = gridDim.y;
    int bx = blockIdx.x, by = blockIdx.y;
    {
        int id = by * gx + bx;
        int xcd = id & 7, j = id >> 3;
        int cols = gx >> 1;
        int rows = gy >> 2;
        int jr = j / cols, jc = j % cols;
        by = (xcd >> 1) * rows + jr;
        bx = (xcd & 1) * cols + jc;
    }
    const int row0 = by * 64;
    const int col0 = bx * 96;

    // staging: 4 waves x 8 rows = 32 rows per issue-unit.
    const int srow = lane >> 3;
    const int schk = (lane & 7) ^ srow;
    const _Float16* Ab = A  + (size_t)(row0 + wave * 8 + srow) * K + schk * 8;
    const _Float16* Bb = Bt + (size_t)(col0 + wave * 8 + srow) * K + schk * 8;

    auto stage = [&](int b, int kt) {
        const int k0 = kt * 64;
        #pragma unroll
        for (int u = 0; u < 2; ++u)
            async16(Ab + (size_t)u * 32 * K + k0, &Al[b][(u * 32 + wave * 8) * 64]);
        #pragma unroll
        for (int u = 0; u < 3; ++u)
            async16(Bb + (size_t)u * 32 * K + k0, &Bl[b][(u * 32 + wave * 8) * 64]);
    };

    float4v acc[2][3];
    #pragma unroll
    for (int m = 0; m < 2; ++m)
        #pragma unroll
        for (int n = 0; n < 3; ++n) {
            float4v z = {0.f, 0.f, 0.f, 0.f};
            acc[m][n] = z;
        }

    auto compute = [&](int cb) {
        #pragma unroll
        for (int ks = 0; ks < 2; ++ks) {
            const int cA = ((ks * 4 + quad) ^ (lr & 7)) * 8;   // swizzled chunk (halfs)
            half8 bf[3];
            #pragma unroll
            for (int n = 0; n < 3; ++n)
                bf[n] = *(const half8*)&Bl[cb][(wc * 48 + n * 16 + lr) * 64 + cA];
            half8 af[2];
            #pragma unroll
            for (int m = 0; m < 2; ++m)
                af[m] = *(const half8*)&Al[cb][(wr * 32 + m * 16 + lr) * 64 + cA];
            __builtin_amdgcn_s_setprio(1);
            #pragma unroll
            for (int m = 0; m < 2; ++m)
                #pragma unroll
                for (int n = 0; n < 3; ++n)
                    acc[m][n] = __builtin_amdgcn_mfma_f32_16x16x32_f16(af[m], bf[n], acc[m][n], 0, 0, 0);
            __builtin_amdgcn_s_setprio(0);
        }
    };

    stage(0, 0);
    stage(1, 1);
    for (int t = 0; t < NT; ++t) {
        if (t + 1 < NT) asm volatile("s_waitcnt vmcnt(5)" ::: "memory");
        else            asm volatile("s_waitcnt vmcnt(0)" ::: "memory");
        __builtin_amdgcn_s_barrier();
        compute(t & 1);
        __builtin_amdgcn_s_barrier();
        if (t + 2 < NT) stage(t & 1, t + 2);
    }

    // epilogue: bias -> t_h write + Tl staging ([h][c][w] pad40)
    #pragma unroll
    for (int n = 0; n < 3; ++n) {
        int cc  = wc * 48 + n * 16 + lr;
        int col = col0 + cc;
        float bj = bias[col];
        #pragma unroll
        for (int m = 0; m < 2; ++m) {
            int row = row0 + wr * 32 + m * 16 + quad * 4;
            #pragma unroll
            for (int r = 0; r < 4; ++r) {
                float v = acc[m][n][r] + bj;
                C16[(size_t)(row + r) * 768 + col] = (_Float16)v;
                int lrow = row + r - row0;
                Tl[((lrow >> 5) * 96 + cc) * 40 + (lrow & 31)] = (_Float16)v;
            }
        }
    }
    __syncthreads();

    // per-wave h-row DFT: wave handles h = wave>>1, cols (wave&1)*48..+47
    const int h     = wave >> 1;
    const int cbase = (wave & 1) * 48;
    const int b     = row0 >> 10;
    const int hp    = ((row0 >> 5) & 31) + h;
    half8 eC0 = *(const half8*)&ECl[lr * 32 + quad * 8];
    half8 eC1 = *(const half8*)&ECl[(16 + lr) * 32 + quad * 8];
    half8 eS0 = *(const half8*)&ESl[lr * 32 + quad * 8];
    half8 eS1 = *(const half8*)&ESl[(16 + lr) * 32 + quad * 8];
    float4v xr[2][3], xi[2][3];
    #pragma unroll
    for (int m = 0; m < 2; ++m)
        #pragma unroll
        for (int nj = 0; nj < 3; ++nj) {
            float4v z = {0.f, 0.f, 0.f, 0.f};
            xr[m][nj] = z; xi[m][nj] = z;
        }
    #pragma unroll
    for (int nj = 0; nj < 3; ++nj) {
        half8 tb = *(const half8*)&Tl[(h * 96 + cbase + nj * 16 + lr) * 40 + quad * 8];
        xr[0][nj] = __builtin_amdgcn_mfma_f32_16x16x32_f16(eC0, tb, xr[0][nj], 0, 0, 0);
        xr[1][nj] = __builtin_amdgcn_mfma_f32_16x16x32_f16(eC1, tb, xr[1][nj], 0, 0, 0);
        xi[0][nj] = __builtin_amdgcn_mfma_f32_16x16x32_f16(eS0, tb, xi[0][nj], 0, 0, 0);
        xi[1][nj] = __builtin_amdgcn_mfma_f32_16x16x32_f16(eS1, tb, xi[1][nj], 0, 0, 0);
    }
    #pragma unroll
    for (int m = 0; m < 2; ++m)
        #pragma unroll
        for (int r = 0; r < 4; ++r) {
            int kw = m * 16 + quad * 4 + r;
            if (kw < 17) {
                #pragma unroll
                for (int nj = 0; nj < 3; ++nj) {
                    int c = col0 + cbase + nj * 16 + lr;
                    size_t g = ((size_t)(b * 17 + kw) * 32 + hp) * 768 + c;
                    XR[g] = (_Float16)xr[m][nj][r];
                    XI[g] = (_Float16)xi[m][nj][r];
                }
            }
        }
}

// ---------------- R14: head2 64x64 tile, 4 waves, counted-vmcnt, scatter out ----------------
__global__ __launch_bounds__(256, 4) void head2_k(const _Float16* __restrict__ A,
        const _Float16* __restrict__ Bt, const float* __restrict__ bias,
        float* __restrict__ C32, int f_idx)
{
    constexpr int K = 1536;
    constexpr int NT = 24;
    __shared__ _Float16 Al[2][64 * 64];   // 16 KB
    __shared__ _Float16 Bl[2][64 * 64];   // 16 KB

    const int tid  = threadIdx.x;
    const int wave = tid >> 6;            // 0..3
    const int lane = tid & 63;
    const int wr   = wave >> 1;
    const int wc   = wave & 1;
    const int lr   = lane & 15;
    const int quad = lane >> 4;

    const int row0 = blockIdx.x * 64;

    const int srow = lane >> 3;
    const int schk = (lane & 7) ^ srow;
    const _Float16* Ab = A  + (size_t)(row0 + wave * 8 + srow) * K + schk * 8;
    const _Float16* Bb = Bt + (size_t)(wave * 8 + srow) * K + schk * 8;

    auto stage = [&](int b, int kt) {
        const int k0 = kt * 64;
        #pragma unroll
        for (int u = 0; u < 2; ++u)
            async16(Ab + (size_t)u * 32 * K + k0, &Al[b][(u * 32 + wave * 8) * 64]);
        #pragma unroll
        for (int u = 0; u < 2; ++u)
            async16(Bb + (size_t)u * 32 * K + k0, &Bl[b][(u * 32 + wave * 8) * 64]);
    };

    float4v acc[2][2];
    #pragma unroll
    for (int m = 0; m < 2; ++m)
        #pragma unroll
        for (int n = 0; n < 2; ++n) {
            float4v z = {0.f, 0.f, 0.f, 0.f};
            acc[m][n] = z;
        }

    auto compute = [&](int cb) {
        #pragma unroll
        for (int ks = 0; ks < 2; ++ks) {
            const int cA = ((ks * 4 + quad) ^ (lr & 7)) * 8;
            half8 bf[2], af[2];
            #pragma unroll
            for (int n = 0; n < 2; ++n)
                bf[n] = *(const half8*)&Bl[cb][(wc * 32 + n * 16 + lr) * 64 + cA];
            #pragma unroll
            for (int m = 0; m < 2; ++m)
                af[m] = *(const half8*)&Al[cb][(wr * 32 + m * 16 + lr) * 64 + cA];
            #pragma unroll
            for (int m = 0; m < 2; ++m)
                #pragma unroll
                for (int n = 0; n < 2; ++n)
                    acc[m][n] = __builtin_amdgcn_mfma_f32_16x16x32_f16(af[m], bf[n], acc[m][n], 0, 0, 0);
        }
    };

    stage(0, 0);
    stage(1, 1);
    for (int t = 0; t < NT; ++t) {
        if (t + 1 < NT) asm volatile("s_waitcnt vmcnt(4)" ::: "memory");
        else            asm volatile("s_waitcnt vmcnt(0)" ::: "memory");
        __builtin_amdgcn_s_barrier();
        compute(t & 1);
        __builtin_amdgcn_s_barrier();
        if (t + 2 < NT) stage(t & 1, t + 2);
    }

    // scatter epilogue: out[b][h][w][f] pixel-shuffle
    #pragma unroll
    for (int n = 0; n < 2; ++n) {
        int col = wc * 32 + n * 16 + lr;
        float bj = bias[col];
        int p = col >> 3, q = col & 7;
        #pragma unroll
        for (int m = 0; m < 2; ++m) {
            int row = row0 + wr * 32 + m * 16 + quad * 4;
            #pragma unroll
            for (int r = 0; r < 4; ++r) {
                float v = acc[m][n][r] + bj;
                int rowv = row + r;
                int bq = rowv >> 10, hp = (rowv >> 5) & 31, wp = rowv & 31;
                C32[(((size_t)(bq * 256 + hp * 8 + p)) * 256 + wp * 8 + q) * 4 + f_idx] = v;
            }
        }
    }
}

// ---------------- fp16 MFMA GEMM, depth-3 counted-vmcnt pipeline, 2D-XCD swizzle ----------------
// OUT_MODE: 1 = f16 (conv prepass, fallback fc2).
template<int BN, int OUT_MODE, int ACT>
__global__ __launch_bounds__(256) void gemm_h(const _Float16* __restrict__ A,
        const _Float16* __restrict__ Bt, const float* __restrict__ bias,
        const float* __restrict__ pos, float* __restrict__ C32,
        _Float16* __restrict__ C16, _Float16* __restrict__ XR,
        _Float16* __restrict__ XI, int M, int N, int K, int f_idx)
{
    constexpr int WN  = BN / 2;
    constexpr int FN  = WN / 16;
    constexpr int NBJ = BN / 64;
    constexpr int LPT = 2 + NBJ;          // vmem loads per thread per K-tile
    __shared__ _Float16 Al[4][128 * 32];
    __shared__ _Float16 Bl[4][BN * 32];

    const int tid  = threadIdx.x;
    const int wave = tid >> 6;
    const int lane = tid & 63;
    const int wr   = wave >> 1;
    const int wc   = wave & 1;
    const int lr   = lane & 15;
    const int quad = lane >> 4;

    // XCD swizzle: prefer 2D (4 row-groups x 2 col-groups -> per-XCD A+B fits 4MB L2)
    const int gx = gridDim.x, gy = gridDim.y, nbk = gx * gy;
    int bx = blockIdx.x, by = blockIdx.y;
    if (!(gy & 3) && !(gx & 1)) {
        int id = by * gx + bx;
        int xcd = id & 7, j = id >> 3;
        int cols = gx >> 1;
        int rows = gy >> 2;
        int jr = j / cols, jc = j % cols;
        by = (xcd >> 1) * rows + jr;
        bx = (xcd & 1) * cols + jc;
    } else if (!(nbk & 7)) {
        int id  = by * gx + bx;
        int id2 = (id & 7) * (nbk >> 3) + (id >> 3);
        by = id2 / gx; bx = id2 % gx;
    }
    const int row0 = by * 128;
    const int col0 = bx * BN;

    const int srow = lane >> 2;
    const int skof = ((lane & 3) ^ (srow & 3)) * 8;

    auto stage = [&](int b, int kt) {
        const int k0 = kt << 5;
        #pragma unroll
        for (int j = 0; j < 2; ++j)
            async16(A + (size_t)(row0 + j * 64 + wave * 16 + srow) * K + k0 + skof,
                    &Al[b][(j * 64 + wave * 16) * 32]);
        #pragma unroll
        for (int j = 0; j < NBJ; ++j)
            async16(Bt + (size_t)(col0 + j * 64 + wave * 16 + srow) * K + k0 + skof,
                    &Bl[b][(j * 64 + wave * 16) * 32]);
    };

    float4v acc[4][FN];
    #pragma unroll
    for (int i = 0; i < 4; ++i)
        #pragma unroll
        for (int j = 0; j < FN; ++j) {
            float4v z = {0.f, 0.f, 0.f, 0.f};
            acc[i][j] = z;
        }

    auto compute = [&](int cb) {
        const int cA = (quad ^ (lr & 3)) * 8;   // swizzled chunk (halfs)
        half8 af[4], bf[FN];
        #pragma unroll
        for (int i = 0; i < 4; ++i)
            af[i] = *(const half8*)&Al[cb][(wr * 64 + i * 16 + lr) * 32 + cA];
        #pragma unroll
        for (int j = 0; j < FN; ++j)
            bf[j] = *(const half8*)&Bl[cb][(wc * WN + j * 16 + lr) * 32 + cA];
        #pragma unroll
        for (int i = 0; i < 4; ++i)
            #pragma unroll
            for (int j = 0; j < FN; ++j)
                acc[i][j] = __builtin_amdgcn_mfma_f32_16x16x32_f16(af[i], bf[j], acc[i][j], 0, 0, 0);
    };

    const int KT = K >> 5;                // K >= 768 -> KT >= 24 (always > 4)
    stage(0, 0); stage(1, 1); stage(2, 2);
    int kt = 0;
    for (; kt < KT - 3; ++kt) {
        stage((kt + 3) & 3, kt + 3);
        if constexpr (LPT == 4) asm volatile("s_waitcnt vmcnt(12)" ::: "memory");
        else                    asm volatile("s_waitcnt vmcnt(9)"  ::: "memory");
        __builtin_amdgcn_s_barrier();
        compute(kt & 3);
        asm volatile("" ::: "memory");
        __builtin_amdgcn_s_barrier();
    }
    // tail: 3 tiles in flight, no more staging; drain 2L -> L -> 0
    if constexpr (LPT == 4) asm volatile("s_waitcnt vmcnt(8)" ::: "memory");
    else                    asm volatile("s_waitcnt vmcnt(6)" ::: "memory");
    __builtin_amdgcn_s_barrier();
    compute(kt & 3); ++kt;
    asm volatile("" ::: "memory");
    __builtin_amdgcn_s_barrier();
    if constexpr (LPT == 4) asm volatile("s_waitcnt vmcnt(4)" ::: "memory");
    else                    asm volatile("s_waitcnt vmcnt(3)" ::: "memory");
    __builtin_amdgcn_s_barrier();
    compute(kt & 3); ++kt;
    asm volatile("" ::: "memory");
    __builtin_amdgcn_s_barrier();
    asm volatile("s_waitcnt vmcnt(0)" ::: "memory");
    __builtin_amdgcn_s_barrier();
    compute(kt & 3);

    #pragma unroll
    for (int j = 0; j < FN; ++j) {
        int col = col0 + wc * WN + j * 16 + lr;
        float bj = bias[col];
        #pragma unroll
        for (int i = 0; i < 4; ++i) {
            int row = row0 + wr * 64 + i * 16 + quad * 4;
            #pragma unroll
            for (int r = 0; r < 4; ++r) {
                float v = acc[i][j][r] + bj;
                if (pos) v += pos[(size_t)((row + r) & 1023) * N + col];
                if (ACT) v = gelu_f(v);
                if (OUT_MODE == 3) {
                    int rowv = row + r;
                    int bq = rowv >> 10, hp = (rowv >> 5) & 31, wp = rowv & 31;
                    int p = col >> 3, q = col & 7;
                    C32[(((size_t)(bq * 256 + hp * 8 + p)) * 256 + wp * 8 + q) * 4 + f_idx] = v;
                } else {
                    C16[(size_t)(row + r) * N + col] = (_Float16)v;
                }
            }
        }
    }
}

// ---------------- launch ----------------
extern "C" void kernel_launch(void* const* d_in, const int* in_sizes, int n_in,
                              void* d_out, int out_size, void* d_ws, size_t ws_size,
                              hipStream_t stream) {
    const float* x        = (const float*)d_in[0];
    const float* grd      = (const float*)d_in[1];
    const float* conv_w   = (const float*)d_in[2];
    const float* conv_b   = (const float*)d_in[3];
    const float* pos_emb  = (const float*)d_in[4];
    const float* w1       = (const float*)d_in[5];
    const float* b1       = (const float*)d_in[6];
    const float* w2       = (const float*)d_in[7];
    const float* b2       = (const float*)d_in[8];
    const float* fc1_w    = (const float*)d_in[9];
    const float* fc1_b    = (const float*)d_in[10];
    const float* fc2_w    = (const float*)d_in[11];
    const float* fc2_b    = (const float*)d_in[12];
    const float* head_w1  = (const float*)d_in[13];
    const float* head_b1  = (const float*)d_in[14];
    const float* head_w2  = (const float*)d_in[15];
    const float* head_b2  = (const float*)d_in[16];
    float* out = (float*)d_out;
    float* ws  = (float*)d_ws;

    // ---- workspace layout, sizes in float units ----
    float* pf = ws;
    _Float16* t_h     = (_Float16*)pf; pf += 1572864;   // 4096x768 f16 (residual state)
    _Float16* Wsp     = (_Float16*)pf; pf += 589824;    // 128x9216 f16 spectral weights
    _Float16* h1t     = (_Float16*)pf; pf += 589824;    // [1536][768] f16
    _Float16* h2t     = (_Float16*)pf; pf += 49152;     // [64][1536] f16
    _Float16* convw_h = (_Float16*)pf; pf += 294912;    // 768x768 f16 (prepass only)
    float* alias    = pf;              pf += 6291456;   // hid_h 4096x3072 f16
    _Float16* hid_h = (_Float16*)alias;
    _Float16* WtAll = (_Float16*)pf;   pf += 9437184;   // 8 x [N][K] fc weights f16
    // fallback xa inside alias (hid dead when xa live); full mode: dedicated xa after WtAll
    _Float16* xa_r_fb = (_Float16*)alias;
    _Float16* xa_i_fb = (_Float16*)(alias + 835584);
    _Float16* xa_r_fu = (_Float16*)pf;                  // +835,584 f
    _Float16* xa_i_fu = (_Float16*)(pf + 835584);       // +835,584 f
    size_t full_total = (size_t)(pf - ws) + 1671168;    // 20,496,384 f = 82.0 MB
    bool full = ws_size >= full_total * 4ull;
    _Float16* xa_r = full ? xa_r_fu : xa_r_fb;
    _Float16* xa_i = full ? xa_i_fu : xa_i_fb;
    _Float16* A_h  = (_Float16*)alias;                  // prepass-only (gather input, dead after)

    // ---- prepass ----
    prep_specw<<<dim3(128), 256, 0, stream>>>(w1, w2, Wsp);
    cvt_f16<<<dim3(576), 256, 0, stream>>>(conv_w, convw_h);
    cvt_transpose<<<dim3(24, 48), 256, 0, stream>>>(head_w1, h1t, 768, 1536);
    cvt_transpose<<<dim3(48, 2), 256, 0, stream>>>(head_w2, h2t, 1536, 64);
    for (int d = 0; d < 4; ++d) {
        cvt_transpose<<<dim3(24, 96), 256, 0, stream>>>(
            fc1_w + (size_t)d * 2359296, WtAll + (size_t)(2 * d) * 2359296, 768, 3072);
        cvt_transpose<<<dim3(96, 24), 256, 0, stream>>>(
            fc2_w + (size_t)d * 2359296, WtAll + (size_t)(2 * d + 1) * 2359296, 3072, 768);
    }
    gather_patch<<<dim3(12288), 256, 0, stream>>>(x, grd, A_h);
    gemm_h<128, 1, 0><<<dim3(6, 32), 256, 0, stream>>>(
        A_h, convw_h, conv_b, pos_emb, nullptr, t_h, nullptr, nullptr, 4096, 768, 768, 0);
    dft_fwd_w<<<dim3(128, 3), 256, 0, stream>>>(t_h, xa_r, xa_i);

    for (int f = 0; f < 4; ++f) {
        for (int d = 0; d < 4; ++d) {
            // fused H-DFT + complex MLP + H-IDFT (in-place on xa)
            spec_fused<<<dim3(68, 8), 256, 0, stream>>>(
                xa_r, xa_i,
                Wsp + (size_t)(d * 4 + 0) * 73728, Wsp + (size_t)(d * 4 + 1) * 73728,
                Wsp + (size_t)(d * 4 + 2) * 73728, Wsp + (size_t)(d * 4 + 3) * 73728,
                b1 + d * 1536, b1 + d * 1536 + 768,
                b2 + d * 1536, b2 + d * 1536 + 768);
            // irfft2 W-pass + f16 residual (in place on t_h) -- MFMA version (R15)
            idft_w_mfma<<<dim3(128, 4), 256, 0, stream>>>(xa_r, xa_i, t_h);
            // channel MLP fc1: 128x192 tile, 512 blocks = 2/CU
            gemm128d<192, 1><<<dim3(16, 32), 512, 0, stream>>>(
                t_h, WtAll + (size_t)(2 * d) * 2359296, fc1_b + d * 3072,
                hid_h, 4096, 3072, 768);
            if (full) {
                // fc2 + fused forward W-DFT (seeds xa for the next spectral block)
                fc2_fused<<<dim3(8, 64), 256, 0, stream>>>(
                    hid_h, WtAll + (size_t)(2 * d + 1) * 2359296, fc2_b + d * 768,
                    t_h, xa_r, xa_i);
            } else {
                gemm_h<64, 1, 0><<<dim3(12, 32), 256, 0, stream>>>(
                    hid_h, WtAll + (size_t)(2 * d + 1) * 2359296, fc2_b + d * 768,
                    nullptr, nullptr, t_h, nullptr, nullptr, 4096, 768, 3072, 0);
                dft_fwd_w<<<dim3(128, 3), 256, 0, stream>>>(t_h, xa_r, xa_i);
            }
        }
        // head on current state (t_h from fc2)
        gemm128d<192, 1><<<dim3(8, 32), 512, 0, stream>>>(
            t_h, h1t, head_b1, hid_h, 4096, 1536, 768);
        head2_k<<<dim3(64), 256, 0, stream>>>(
            hid_h, h2t, head_b2, out, f);
    }
}

// Round 8
// 1700.963 us; speedup vs baseline: 1.6081x; 1.0319x over previous
//
#include <hip/hip_runtime.h>
#include <hip/hip_bf16.h>
#include <math.h>

// ---------------- static config ----------------
// B=4, H=W=256, TIN=10, F=4, P=8, CIN=12, E=768, NB=8, BS=96,
// HP=WP=32, MID=3072, DEPTH=4, LAM=0.01, WF=17, TOK=4096, POS=B*32*17=2176
// Spectral layout: X[((b*17+kw)*32 + h)*768 + c]   (h-rows contiguous per kw)
// R12: gemm128d (128x192, 8 waves, 2 blk/CU, counted vmcnt) for fc1/head1.
// R15/R16: idft_w_mfma (W-IDFT as one mfma K-step): 2023 -> 1755 us.
// R17: (a) spec_fused 4 -> 12 waves (768 thr): wave=(kh-half, j) -- identical
//   fragment maps, j-loop made wave-parallel (3x shorter per-stage chains,
//   3x waves to hide L2 weight-load latency). (b) fc2_fused 64x96 -> 64x64,
//   grid (12,64)=768 blocks = 3 blk/CU (LDS 46KB), same counted-vmcnt skeleton.

typedef __attribute__((ext_vector_type(8))) _Float16 half8;
typedef __attribute__((ext_vector_type(4))) _Float16 half4v;
typedef __attribute__((ext_vector_type(4))) float float4v;

__device__ __forceinline__ float gelu_f(float v) {
    return 0.5f * v * (1.0f + erff(v * 0.70710678118654752f));
}
__device__ __forceinline__ float shrink_f(float v) {
    return (v > 0.01f) ? (v - 0.01f) : ((v < -0.01f) ? (v + 0.01f) : 0.0f);
}

#define STEP32 0.19634954084936207f  // 2*pi/32

// async 16B global->LDS (lds dest wave-uniform; HW adds lane*16)
__device__ __forceinline__ void async16(const void* g, void* l) {
    __builtin_amdgcn_global_load_lds(
        (const __attribute__((address_space(1))) unsigned int*)g,
        (__attribute__((address_space(3))) unsigned int*)l, 16, 0, 0);
}

// ---------------- gather patches into A_h [4096][768] f16 ----------------
__global__ __launch_bounds__(256) void gather_patch(const float* __restrict__ x,
        const float* __restrict__ grd, _Float16* __restrict__ A)
{
    int idx = blockIdx.x * 256 + threadIdx.x;
    int j   = idx % 768;
    int tok = idx / 768;
    int c = j >> 6, p = (j >> 3) & 7, q = j & 7;
    int wp = tok & 31, hp = (tok >> 5) & 31, b = tok >> 10;
    int hh = hp * 8 + p, ww = wp * 8 + q;
    float v;
    if (c < 10) v = x[((b * 256 + hh) * 256 + ww) * 10 + c];
    else        v = grd[((b * 256 + hh) * 256 + ww) * 2 + (c - 10)];
    A[idx] = (_Float16)v;
}

// ---------------- forward DFT along W (f16 in -> 17 complex f16), scale 1/32 ----------------
// prepass + fallback path. out layout [b,kw,h,c]
__global__ __launch_bounds__(256) void dft_fwd_w(const _Float16* __restrict__ th,
        _Float16* __restrict__ Xr, _Float16* __restrict__ Xi)
{
    __shared__ float2 lut[32];
    int bh = blockIdx.x;            // b*32 + h
    int tid = threadIdx.x;
    if (tid < 32) { float a = tid * STEP32; lut[tid] = make_float2(cosf(a), sinf(a)); }
    __syncthreads();
    int b = bh >> 5, h = bh & 31;
    int c = blockIdx.y * 256 + tid;
    float v[32];
    #pragma unroll
    for (int w = 0; w < 32; ++w) v[w] = (float)th[(bh * 32 + w) * 768 + c];
    for (int kw = 0; kw <= 16; ++kw) {
        float ar = 0.f, ai = 0.f;
        #pragma unroll
        for (int w = 0; w < 32; ++w) {
            float2 cs = lut[(kw * w) & 31];
            ar += v[w] * cs.x;
            ai -= v[w] * cs.y;
        }
        size_t g = ((size_t)(b * 17 + kw) * 32 + h) * 768 + c;
        Xr[g] = (_Float16)(ar * 0.03125f);
        Xi[g] = (_Float16)(ai * 0.03125f);
    }
}

// ---------------- R15: MFMA inverse W-DFT + f16 residual ----------------
__global__ __launch_bounds__(256) void idft_w_mfma(const _Float16* __restrict__ Yr,
        const _Float16* __restrict__ Yi, _Float16* __restrict__ th)
{
    __shared__ alignas(16) _Float16 Yt[192 * 40];   // [c_local][slot] pad-40, 15 KB
    __shared__ alignas(16) _Float16 El[32 * 40];    // [w][slot] pad-40, 2.5 KB

    const int tid  = threadIdx.x;
    const int wave = tid >> 6;          // 0..3
    const int lane = tid & 63;
    const int lr   = lane & 15;
    const int quad = lane >> 4;

    const int bh = blockIdx.x;
    const int b  = bh >> 5, h = bh & 31;
    const int c0 = blockIdx.y * 192;

    // E' twiddles (f16, factors folded)
    for (int i = tid; i < 1024; i += 256) {
        int w = i >> 5, s = i & 31;
        float val;
        if (s <= 16) {
            float g = (s == 0 || s == 16) ? 1.f : 2.f;
            val = g * cosf(((w * s) & 31) * STEP32) * 0.03125f;
        } else {
            int k = s - 16;
            val = -2.f * sinf(((w * k) & 31) * STEP32) * 0.03125f;
        }
        El[w * 40 + s] = (_Float16)val;
    }

    // stage Y' -> Yt[c][slot]: coalesced half8 loads; transpose scalar writes
    // with e^(cg&7) perm (spreads the 32-way same-bank write pattern to 8-way).
    #pragma unroll
    for (int i = 0; i < 3; ++i) {
        int u    = tid + i * 256;
        int slot = u / 24;
        int cg   = u % 24;
        const _Float16* src;
        if (slot < 17) src = Yr + ((size_t)(b * 17 + slot) * 32 + h) * 768;
        else           src = Yi + ((size_t)(b * 17 + (slot - 16)) * 32 + h) * 768;
        half8 v = *(const half8*)(src + c0 + cg * 8);
        #pragma unroll
        for (int e = 0; e < 8; ++e) {
            int el = e ^ (cg & 7);
            Yt[(cg * 8 + el) * 40 + slot] = v[el];
        }
    }
    __syncthreads();

    // MFMA: acc[m][n], m = w-half (0..1), n = c-frag (0..2)
    half8 af[2], bf[3];
    #pragma unroll
    for (int m = 0; m < 2; ++m)
        af[m] = *(const half8*)&El[(m * 16 + lr) * 40 + quad * 8];
    #pragma unroll
    for (int n = 0; n < 3; ++n)
        bf[n] = *(const half8*)&Yt[(wave * 48 + n * 16 + lr) * 40 + quad * 8];
    float4v acc[2][3];
    #pragma unroll
    for (int m = 0; m < 2; ++m)
        #pragma unroll
        for (int n = 0; n < 3; ++n) {
            float4v z = {0.f, 0.f, 0.f, 0.f};
            acc[m][n] = __builtin_amdgcn_mfma_f32_16x16x32_f16(af[m], bf[n], z, 0, 0, 0);
        }

    // residual RMW (same pattern as old dft_inv_w)
    #pragma unroll
    for (int m = 0; m < 2; ++m)
        #pragma unroll
        for (int n = 0; n < 3; ++n) {
            int c = c0 + wave * 48 + n * 16 + lr;
            #pragma unroll
            for (int r = 0; r < 4; ++r) {
                int w = m * 16 + quad * 4 + r;
                size_t gi = (size_t)(bh * 32 + w) * 768 + c;
                th[gi] = (_Float16)(acc[m][n][r] + (float)th[gi]);
            }
        }
}

// ---------------- spectral weight prep: [i][o] fp32 -> [o][i] f16, 128 matrices ----------------
__global__ __launch_bounds__(256) void prep_specw(const float* __restrict__ w1,
        const float* __restrict__ w2, _Float16* __restrict__ out)
{
    __shared__ float tile[96][97];
    int mid = blockIdx.x;
    int n  = mid & 7;
    int ri = (mid >> 3) & 1;
    int l  = (mid >> 4) & 1;
    int d  = mid >> 5;
    const float* src = (l ? w2 : w1) + ((size_t)(d * 2 + ri) * 8 + n) * 9216;
    for (int idx = threadIdx.x; idx < 9216; idx += 256)
        tile[idx / 96][idx % 96] = src[idx];
    __syncthreads();
    _Float16* dst = out + (size_t)mid * 9216;
    for (int idx = threadIdx.x; idx < 9216; idx += 256)
        dst[idx] = (_Float16)tile[idx % 96][idx / 96];   // dst[o][i] = src[i][o]
}

// ---------------- fused spectral: H-DFT -> spec1(gelu) -> spec2(shrink) -> H-IDFT ----------------
// IN-PLACE on X ([b,kw,h,c] layout). grid (68 = b*17+kw, 8 = n).
// R17: 768 thr = 12 waves; wave = (wr = wave/6 kh-half, wo = wave%6 frag idx).
// Fragment maps identical to the verified 4-wave version (j-loop -> wave-parallel).
__global__ __launch_bounds__(768) void spec_fused(
        _Float16* __restrict__ Xr, _Float16* __restrict__ Xi,
        const _Float16* __restrict__ W1r, const _Float16* __restrict__ W1i,
        const _Float16* __restrict__ W2r, const _Float16* __restrict__ W2i,
        const float* __restrict__ b1r, const float* __restrict__ b1i,
        const float* __restrict__ b2r, const float* __restrict__ b2i)
{
    __shared__ alignas(16) _Float16 Ec[1024], Es[1024];       // [m][k] twiddle 32x32
    __shared__ alignas(16) _Float16 XTr[3840], XTi[3840];     // [c][h] pad40; stage C: [o][kh]
    __shared__ alignas(16) _Float16 Zr[3328], Zi[3328];       // [kh][c] pad104; stage D out [h][c]
    __shared__ alignas(16) _Float16 Sr[3328], Si[3328];       // [kh][o] pad104

    const int bk = blockIdx.x;       // b*17 + kw
    const int n  = blockIdx.y;
    const int tid = threadIdx.x;
    const int wave = tid >> 6, lane = tid & 63;
    const int wr = wave / 6;         // kh/h half (0..1)
    const int wo = wave % 6;         // fragment index (0..5), replaces wc*3 + j
    const int lr = lane & 15, quad = lane >> 4;
    const size_t base = (size_t)bk * 24576 + n * 96;    // + h*768 + c

    for (int i = tid; i < 1024; i += 768) {
        int kh = i >> 5, h = i & 31;
        float a = ((kh * h) & 31) * STEP32;
        Ec[i] = (_Float16)cosf(a);
        Es[i] = (_Float16)sinf(a);
    }
    // vector load -> LDS transpose [c][h]
    for (int i = tid; i < 384; i += 768) {
        int h = i / 12, cc = (i % 12) * 8;
        half8 vr = *(const half8*)(Xr + base + (size_t)h * 768 + cc);
        half8 vi = *(const half8*)(Xi + base + (size_t)h * 768 + cc);
        #pragma unroll
        for (int e = 0; e < 8; ++e) {
            XTr[(cc + e) * 40 + h] = vr[e];
            XTi[(cc + e) * 40 + h] = vi[e];
        }
    }
    __syncthreads();

    const _Float16* w1r = W1r + (size_t)n * 9216;
    const _Float16* w1i = W1i + (size_t)n * 9216;
    const _Float16* w2r = W2r + (size_t)n * 9216;
    const _Float16* w2i = W2i + (size_t)n * 9216;

    half8 eC = *(const half8*)&Ec[(wr * 16 + lr) * 32 + quad * 8];
    half8 eS = *(const half8*)&Es[(wr * 16 + lr) * 32 + quad * 8];
    half8 eSn = -eS;

    // stage A: Z[kh][c] = DFT_h(X) -- wave handles c-tile wo
    {
        int c = wo * 16 + lr;
        float4v zr = {0,0,0,0}, zi = {0,0,0,0};
        half8 xr = *(const half8*)&XTr[c * 40 + quad * 8];
        half8 xi = *(const half8*)&XTi[c * 40 + quad * 8];
        zr = __builtin_amdgcn_mfma_f32_16x16x32_f16(eC,  xr, zr, 0, 0, 0);
        zr = __builtin_amdgcn_mfma_f32_16x16x32_f16(eS,  xi, zr, 0, 0, 0);
        zi = __builtin_amdgcn_mfma_f32_16x16x32_f16(eC,  xi, zi, 0, 0, 0);
        zi = __builtin_amdgcn_mfma_f32_16x16x32_f16(eSn, xr, zi, 0, 0, 0);
        #pragma unroll
        for (int r = 0; r < 4; ++r) {
            int kh = wr * 16 + quad * 4 + r;
            Zr[kh * 104 + c] = (_Float16)zr[r];
            Zi[kh * 104 + c] = (_Float16)zi[r];
        }
    }
    __syncthreads();

    // stage B: S = gelu(Z @ W1 + b1) -- wave handles o-tile wo
    {
        int o = wo * 16 + lr;
        float4v sr = {0,0,0,0}, si = {0,0,0,0};
        #pragma unroll
        for (int kc = 0; kc < 3; ++kc) {
            half8 ar = *(const half8*)&Zr[(wr * 16 + lr) * 104 + kc * 32 + quad * 8];
            half8 ai = *(const half8*)&Zi[(wr * 16 + lr) * 104 + kc * 32 + quad * 8];
            half8 ain = -ai;
            half8 br = *(const half8*)&w1r[o * 96 + kc * 32 + quad * 8];
            half8 bi = *(const half8*)&w1i[o * 96 + kc * 32 + quad * 8];
            sr = __builtin_amdgcn_mfma_f32_16x16x32_f16(ar,  br, sr, 0, 0, 0);
            sr = __builtin_amdgcn_mfma_f32_16x16x32_f16(ain, bi, sr, 0, 0, 0);
            si = __builtin_amdgcn_mfma_f32_16x16x32_f16(ai,  br, si, 0, 0, 0);
            si = __builtin_amdgcn_mfma_f32_16x16x32_f16(ar,  bi, si, 0, 0, 0);
        }
        float br = b1r[n * 96 + o], bi = b1i[n * 96 + o];
        #pragma unroll
        for (int r = 0; r < 4; ++r) {
            int kh = wr * 16 + quad * 4 + r;
            Sr[kh * 104 + o] = (_Float16)gelu_f(sr[r] + br);
            Si[kh * 104 + o] = (_Float16)gelu_f(si[r] + bi);
        }
    }
    __syncthreads();

    // stage C: T = shrink(S @ W2 + b2) -> transposed T2T[o][kh] (alias XT)
    {
        int o = wo * 16 + lr;
        float4v tr = {0,0,0,0}, ti = {0,0,0,0};
        #pragma unroll
        for (int kc = 0; kc < 3; ++kc) {
            half8 ar = *(const half8*)&Sr[(wr * 16 + lr) * 104 + kc * 32 + quad * 8];
            half8 ai = *(const half8*)&Si[(wr * 16 + lr) * 104 + kc * 32 + quad * 8];
            half8 ain = -ai;
            half8 br = *(const half8*)&w2r[o * 96 + kc * 32 + quad * 8];
            half8 bi = *(const half8*)&w2i[o * 96 + kc * 32 + quad * 8];
            tr = __builtin_amdgcn_mfma_f32_16x16x32_f16(ar,  br, tr, 0, 0, 0);
            tr = __builtin_amdgcn_mfma_f32_16x16x32_f16(ain, bi, tr, 0, 0, 0);
            ti = __builtin_amdgcn_mfma_f32_16x16x32_f16(ai,  br, ti, 0, 0, 0);
            ti = __builtin_amdgcn_mfma_f32_16x16x32_f16(ar,  bi, ti, 0, 0, 0);
        }
        float br = b2r[n * 96 + o], bi = b2i[n * 96 + o];
        #pragma unroll
        for (int r = 0; r < 4; ++r) {
            int kh = wr * 16 + quad * 4 + r;
            XTr[o * 40 + kh] = (_Float16)shrink_f(tr[r] + br);
            XTi[o * 40 + kh] = (_Float16)shrink_f(ti[r] + bi);
        }
    }
    __syncthreads();

    // stage D: Y[h][c] = IDFT_h(T2) -> Zr/Zi as [h][c] pad104
    {
        int c = wo * 16 + lr;
        float4v yr = {0,0,0,0}, yi = {0,0,0,0};
        half8 t2r = *(const half8*)&XTr[c * 40 + quad * 8];
        half8 t2i = *(const half8*)&XTi[c * 40 + quad * 8];
        yr = __builtin_amdgcn_mfma_f32_16x16x32_f16(eC,  t2r, yr, 0, 0, 0);
        yr = __builtin_amdgcn_mfma_f32_16x16x32_f16(eSn, t2i, yr, 0, 0, 0);
        yi = __builtin_amdgcn_mfma_f32_16x16x32_f16(eC,  t2i, yi, 0, 0, 0);
        yi = __builtin_amdgcn_mfma_f32_16x16x32_f16(eS,  t2r, yi, 0, 0, 0);
        #pragma unroll
        for (int r = 0; r < 4; ++r) {
            int h = wr * 16 + quad * 4 + r;
            Zr[h * 104 + c] = (_Float16)yr[r];
            Zi[h * 104 + c] = (_Float16)yi[r];
        }
    }
    __syncthreads();

    // vector store back (in-place)
    for (int i = tid; i < 384; i += 768) {
        int h = i / 12, cc = (i % 12) * 8;
        half8 vr = *(const half8*)&Zr[h * 104 + cc];
        half8 vi = *(const half8*)&Zi[h * 104 + cc];
        *(half8*)(Xr + base + (size_t)h * 768 + cc) = vr;
        *(half8*)(Xi + base + (size_t)h * 768 + cc) = vi;
    }
}

// ---------------- f32 -> f16 elementwise (vectorized x4) ----------------
__global__ __launch_bounds__(256) void cvt_f16(const float* __restrict__ in,
        _Float16* __restrict__ out)
{
    int i = blockIdx.x * 256 + threadIdx.x;
    float4 v = ((const float4*)in)[i];
    half4v o;
    o.x = (_Float16)v.x; o.y = (_Float16)v.y; o.z = (_Float16)v.z; o.w = (_Float16)v.w;
    ((half4v*)out)[i] = o;
}

// ---------------- f32 [K][N] -> f16 [N][K] transpose ----------------
__global__ __launch_bounds__(256) void cvt_transpose(const float* __restrict__ in,
        _Float16* __restrict__ out, int K, int N)
{
    __shared__ float tile[32][33];
    int kb = blockIdx.x * 32, nb = blockIdx.y * 32;
    int tx = threadIdx.x & 31, ty = threadIdx.x >> 5;
    #pragma unroll
    for (int r = 0; r < 32; r += 8)
        tile[ty + r][tx] = in[(size_t)(kb + ty + r) * N + nb + tx];
    __syncthreads();
    #pragma unroll
    for (int r = 0; r < 32; r += 8)
        out[(size_t)(nb + ty + r) * K + kb + tx] = (_Float16)tile[tx][ty + r];
}

// ---------------- R12: 128x192-tile 8-wave GEMM, 2 blocks/CU (fc1 / head1) ----------------
template<int BN, int ACT>
__global__ __launch_bounds__(512, 4) void gemm128d(const _Float16* __restrict__ A,
        const _Float16* __restrict__ Bt, const float* __restrict__ bias,
        _Float16* __restrict__ C16, int M, int N, int K)
{
    constexpr int WN  = BN / 4;           // 48
    constexpr int FN  = WN / 16;          // 3
    constexpr int AU  = 2;                // A: 2 x 64-row units
    constexpr int BU  = BN / 64;          // 3
    constexpr int LPT = AU + BU;          // 5 loads/thread/K-tile
    __shared__ _Float16 Al[2][128 * 64];
    __shared__ _Float16 Bl[2][BN * 64];

    const int tid  = threadIdx.x;
    const int wave = tid >> 6;            // 0..7
    const int lane = tid & 63;
    const int wr   = wave >> 2;           // 0..1 (M)
    const int wc   = wave & 3;            // 0..3 (N)
    const int lr   = lane & 15;
    const int quad = lane >> 4;

    // XCD swizzle (2D): per-XCD contiguous patch for L2 reuse
    const int gx = gridDim.x, gy = gridDim.y, nbk = gx * gy;
    int bx = blockIdx.x, by = blockIdx.y;
    if (!(gy & 3) && !(gx & 1)) {
        int id = by * gx + bx;
        int xcd = id & 7, j = id >> 3;
        int cols = gx >> 1;
        int rows = gy >> 2;
        int jr = j / cols, jc = j % cols;
        by = (xcd >> 1) * rows + jr;
        bx = (xcd & 1) * cols + jc;
    } else if (!(nbk & 7)) {
        int id  = by * gx + bx;
        int id2 = (id & 7) * (nbk >> 3) + (id >> 3);
        by = id2 / gx; bx = id2 % gx;
    }
    const int row0 = by * 128;
    const int col0 = bx * BN;

    // staging: per 64-row unit (64x64 halfs = 8KB) each wave covers 8 rows.
    const int srow = lane >> 3;
    const int schk = (lane & 7) ^ (srow & 7);
    const _Float16* Ab = A  + (size_t)(row0 + wave * 8 + srow) * K + schk * 8;
    const _Float16* Bb = Bt + (size_t)(col0 + wave * 8 + srow) * K + schk * 8;

    auto stage = [&](int b, int kt) {
        const int k0 = kt * 64;
        #pragma unroll
        for (int u = 0; u < AU; ++u)
            async16(Ab + (size_t)u * 64 * K + k0, &Al[b][(u * 64 + wave * 8) * 64]);
        #pragma unroll
        for (int u = 0; u < BU; ++u)
            async16(Bb + (size_t)u * 64 * K + k0, &Bl[b][(u * 64 + wave * 8) * 64]);
    };

    float4v acc[4][FN];
    #pragma unroll
    for (int m = 0; m < 4; ++m)
        #pragma unroll
        for (int n = 0; n < FN; ++n) {
            float4v z = {0.f, 0.f, 0.f, 0.f};
            acc[m][n] = z;
        }

    auto compute = [&](int cb) {
        #pragma unroll
        for (int ks = 0; ks < 2; ++ks) {
            const int cA = ((ks * 4 + quad) ^ (lr & 7)) * 8;   // swizzled chunk (halfs)
            half8 bf[FN];
            #pragma unroll
            for (int n = 0; n < FN; ++n)
                bf[n] = *(const half8*)&Bl[cb][(wc * WN + n * 16 + lr) * 64 + cA];
            half8 af[4];
            #pragma unroll
            for (int m = 0; m < 4; ++m)
                af[m] = *(const half8*)&Al[cb][(wr * 64 + m * 16 + lr) * 64 + cA];
            __builtin_amdgcn_s_setprio(1);
            #pragma unroll
            for (int m = 0; m < 4; ++m)
                #pragma unroll
                for (int n = 0; n < FN; ++n)
                    acc[m][n] = __builtin_amdgcn_mfma_f32_16x16x32_f16(af[m], bf[n], acc[m][n], 0, 0, 0);
            __builtin_amdgcn_s_setprio(0);
        }
    };

    const int NT = K >> 6;                // K=768 -> 12 tiles
    stage(0, 0);
    stage(1, 1);
    for (int t = 0; t < NT; ++t) {
        if (t + 1 < NT) asm volatile("s_waitcnt vmcnt(5)" ::: "memory");
        else            asm volatile("s_waitcnt vmcnt(0)" ::: "memory");
        __builtin_amdgcn_s_barrier();     // all waves' tile-t loads visible
        compute(t & 1);
        __builtin_amdgcn_s_barrier();     // all waves done reading buf[t&1]
        if (t + 2 < NT) stage(t & 1, t + 2);   // prefetch into just-freed buffer
    }

    // epilogue: bias (+GELU) -> f16 store
    #pragma unroll
    for (int n = 0; n < FN; ++n) {
        int col = col0 + wc * WN + n * 16 + lr;
        float bj = bias[col];
        #pragma unroll
        for (int m = 0; m < 4; ++m) {
            int row = row0 + wr * 64 + m * 16 + quad * 4;
            #pragma unroll
            for (int r = 0; r < 4; ++r) {
                float v = acc[m][n][r] + bj;
                if (ACT) v = gelu_f(v);
                C16[(size_t)(row + r) * N + col] = (_Float16)v;
            }
        }
    }
}

// ---------------- R17: fc2 + fused forward W-DFT, 64x64 tile, 4 waves, 3 blk/CU ----------------
// M=4096, N=768, K=3072 fixed. grid (12, 64) = 768 blocks = 3/CU (LDS 46KB).
// 4 waves = 2M x 2N, per-wave 32x32 (2m x 2n, 8 MFMA / BK=64 window).
// depth-2 counted vmcnt(4); XOR-swizzled K-loop LDS. Epilogue: t_h write +
// Tl[2][64][40] pad-40 + per-wave h-row DFT -> XR/XI.
__global__ __launch_bounds__(256, 3) void fc2_fused(const _Float16* __restrict__ A,
        const _Float16* __restrict__ Bt, const float* __restrict__ bias,
        _Float16* __restrict__ C16, _Float16* __restrict__ XR,
        _Float16* __restrict__ XI)
{
    constexpr int K = 3072;
    constexpr int NT = 48;
    __shared__ _Float16 Al[2][64 * 64];        // 16 KB
    __shared__ _Float16 Bl[2][64 * 64];        // 16 KB
    __shared__ alignas(16) _Float16 Tl[2 * 64 * 40];           // 10 KB  [h][c][w pad40]
    __shared__ alignas(16) _Float16 ECl[1024], ESl[1024];      // 4 KB

    const int tid  = threadIdx.x;
    const int wave = tid >> 6;            // 0..3
    const int lane = tid & 63;
    const int wr   = wave >> 1;           // 0..1 (M: 32-row half)
    const int wc   = wave & 1;            // 0..1 (N: 32-col half)
    const int lr   = lane & 15;
    const int quad = lane >> 4;

    // twiddle fill early (hides under prologue load latency)
    for (int i = tid; i < 1024; i += 256) {
        int kw = i >> 5, w = i & 31;
        float a = ((kw * w) & 31) * STEP32;
        ECl[i] = (_Float16)(cosf(a) * 0.03125f);
        ESl[i] = (_Float16)(-sinf(a) * 0.03125f);
    }

    // XCD swizzle (2D): gx=12, gy=64 -> cols=6, rows=16 per XCD patch
    const int gx = gridDim.x, gy = gridDim.y;
    int bx = blockIdx.x, by = blockIdx.y;
    {
        int id = by * gx + bx;
        int xcd = id & 7, j = id >> 3;
        int cols = gx >> 1;
        int rows = gy >> 2;
        int jr = j / cols, jc = j % cols;
        by = (xcd >> 1) * rows + jr;
        bx = (xcd & 1) * cols + jc;
    }
    const int row0 = by * 64;
    const int col0 = bx * 64;

    // staging: A/B each 2 units of 32 rows; wave covers 8 rows/unit.
    const int srow = lane >> 3;
    const int schk = (lane & 7) ^ srow;
    const _Float16* Ab = A  + (size_t)(row0 + wave * 8 + srow) * K + schk * 8;
    const _Float16* Bb = Bt + (size_t)(col0 + wave * 8 + srow) * K + schk * 8;

    auto stage = [&](int b, int kt) {
        const int k0 = kt * 64;
        #pragma unroll
        for (int u = 0; u < 2; ++u)
            async16(Ab + (size_t)u * 32 * K + k0, &Al[b][(u * 32 + wave * 8) * 64]);
        #pragma unroll
        for (int u = 0; u < 2; ++u)
            async16(Bb + (size_t)u * 32 * K + k0, &Bl[b][(u * 32 + wave * 8) * 64]);
    };

    float4v acc[2][2];
    #pragma unroll
    for (int m = 0; m < 2; ++m)
        #pragma unroll
        for (int n = 0; n < 2; ++n) {
            float4v z = {0.f, 0.f, 0.f, 0.f};
            acc[m][n] = z;
        }

    auto compute = [&](int cb) {
        #pragma unroll
        for (int ks = 0; ks < 2; ++ks) {
            const int cA = ((ks * 4 + quad) ^ (lr & 7)) * 8;   // swizzled chunk (halfs)
            half8 bf[2], af[2];
            #pragma unroll
            for (int n = 0; n < 2; ++n)
                bf[n] = *(const half8*)&Bl[cb][(wc * 32 + n * 16 + lr) * 64 + cA];
            #pragma unroll
            for (int m = 0; m < 2; ++m)
                af[m] = *(const half8*)&Al[cb][(wr * 32 + m * 16 + lr) * 64 + cA];
            __builtin_amdgcn_s_setprio(1);
            #pragma unroll
            for (int m = 0; m < 2; ++m)
                #pragma unroll
                for (int n = 0; n < 2; ++n)
                    acc[m][n] = __builtin_amdgcn_mfma_f32_16x16x32_f16(af[m], bf[n], acc[m][n], 0, 0, 0);
            __builtin_amdgcn_s_setprio(0);
        }
    };

    stage(0, 0);
    stage(1, 1);
    for (int t = 0; t < NT; ++t) {
        if (t + 1 < NT) asm volatile("s_waitcnt vmcnt(4)" ::: "memory");
        else            asm volatile("s_waitcnt vmcnt(0)" ::: "memory");
        __builtin_amdgcn_s_barrier();
        compute(t & 1);
        __builtin_amdgcn_s_barrier();
        if (t + 2 < NT) stage(t & 1, t + 2);
    }

    // epilogue: bias -> t_h write + Tl staging ([h][c][w] pad40)
    #pragma unroll
    for (int n = 0; n < 2; ++n) {
        int cc  = wc * 32 + n * 16 + lr;
        int col = col0 + cc;
        float bj = bias[col];
        #pragma unroll
        for (int m = 0; m < 2; ++m) {
            int row = row0 + wr * 32 + m * 16 + quad * 4;
            #pragma unroll
            for (int r = 0; r < 4; ++r) {
                float v = acc[m][n][r] + bj;
                C16[(size_t)(row + r) * 768 + col] = (_Float16)v;
                int lrow = row + r - row0;
                Tl[((lrow >> 5) * 64 + cc) * 40 + (lrow & 31)] = (_Float16)v;
            }
        }
    }
    __syncthreads();

    // per-wave h-row DFT: wave handles h = wave>>1, cols (wave&1)*32..+31
    const int h     = wave >> 1;
    const int cbase = (wave & 1) * 32;
    const int b     = row0 >> 10;
    const int hp    = ((row0 >> 5) & 31) + h;
    half8 eC0 = *(const half8*)&ECl[lr * 32 + quad * 8];
    half8 eC1 = *(const half8*)&ECl[(16 + lr) * 32 + quad * 8];
    half8 eS0 = *(const half8*)&ESl[lr * 32 + quad * 8];
    half8 eS1 = *(const half8*)&ESl[(16 + lr) * 32 + quad * 8];
    float4v xr[2][2], xi[2][2];
    #pragma unroll
    for (int m = 0; m < 2; ++m)
        #pragma unroll
        for (int nj = 0; nj < 2; ++nj) {
            float4v z = {0.f, 0.f, 0.f, 0.f};
            xr[m][nj] = z; xi[m][nj] = z;
        }
    #pragma unroll
    for (int nj = 0; nj < 2; ++nj) {
        half8 tb = *(const half8*)&Tl[(h * 64 + cbase + nj * 16 + lr) * 40 + quad * 8];
        xr[0][nj] = __builtin_amdgcn_mfma_f32_16x16x32_f16(eC0, tb, xr[0][nj], 0, 0, 0);
        xr[1][nj] = __builtin_amdgcn_mfma_f32_16x16x32_f16(eC1, tb, xr[1][nj], 0, 0, 0);
        xi[0][nj] = __builtin_amdgcn_mfma_f32_16x16x32_f16(eS0, tb, xi[0][nj], 0, 0, 0);
        xi[1][nj] = __builtin_amdgcn_mfma_f32_16x16x32_f16(eS1, tb, xi[1][nj], 0, 0, 0);
    }
    #pragma unroll
    for (int m = 0; m < 2; ++m)
        #pragma unroll
        for (int r = 0; r < 4; ++r) {
            int kw = m * 16 + quad * 4 + r;
            if (kw < 17) {
                #pragma unroll
                for (int nj = 0; nj < 2; ++nj) {
                    int c = col0 + cbase + nj * 16 + lr;
                    size_t g = ((size_t)(b * 17 + kw) * 32 + hp) * 768 + c;
                    XR[g] = (_Float16)xr[m][nj][r];
                    XI[g] = (_Float16)xi[m][nj][r];
                }
            }
        }
}

// ---------------- R14: head2 64x64 tile, 4 waves, counted-vmcnt, scatter out ----------------
__global__ __launch_bounds__(256, 4) void head2_k(const _Float16* __restrict__ A,
        const _Float16* __restrict__ Bt, const float* __restrict__ bias,
        float* __restrict__ C32, int f_idx)
{
    constexpr int K = 1536;
    constexpr int NT = 24;
    __shared__ _Float16 Al[2][64 * 64];   // 16 KB
    __shared__ _Float16 Bl[2][64 * 64];   // 16 KB

    const int tid  = threadIdx.x;
    const int wave = tid >> 6;            // 0..3
    const int lane = tid & 63;
    const int wr   = wave >> 1;
    const int wc   = wave & 1;
    const int lr   = lane & 15;
    const int quad = lane >> 4;

    const int row0 = blockIdx.x * 64;

    const int srow = lane >> 3;
    const int schk = (lane & 7) ^ srow;
    const _Float16* Ab = A  + (size_t)(row0 + wave * 8 + srow) * K + schk * 8;
    const _Float16* Bb = Bt + (size_t)(wave * 8 + srow) * K + schk * 8;

    auto stage = [&](int b, int kt) {
        const int k0 = kt * 64;
        #pragma unroll
        for (int u = 0; u < 2; ++u)
            async16(Ab + (size_t)u * 32 * K + k0, &Al[b][(u * 32 + wave * 8) * 64]);
        #pragma unroll
        for (int u = 0; u < 2; ++u)
            async16(Bb + (size_t)u * 32 * K + k0, &Bl[b][(u * 32 + wave * 8) * 64]);
    };

    float4v acc[2][2];
    #pragma unroll
    for (int m = 0; m < 2; ++m)
        #pragma unroll
        for (int n = 0; n < 2; ++n) {
            float4v z = {0.f, 0.f, 0.f, 0.f};
            acc[m][n] = z;
        }

    auto compute = [&](int cb) {
        #pragma unroll
        for (int ks = 0; ks < 2; ++ks) {
            const int cA = ((ks * 4 + quad) ^ (lr & 7)) * 8;
            half8 bf[2], af[2];
            #pragma unroll
            for (int n = 0; n < 2; ++n)
                bf[n] = *(const half8*)&Bl[cb][(wc * 32 + n * 16 + lr) * 64 + cA];
            #pragma unroll
            for (int m = 0; m < 2; ++m)
                af[m] = *(const half8*)&Al[cb][(wr * 32 + m * 16 + lr) * 64 + cA];
            #pragma unroll
            for (int m = 0; m < 2; ++m)
                #pragma unroll
                for (int n = 0; n < 2; ++n)
                    acc[m][n] = __builtin_amdgcn_mfma_f32_16x16x32_f16(af[m], bf[n], acc[m][n], 0, 0, 0);
        }
    };

    stage(0, 0);
    stage(1, 1);
    for (int t = 0; t < NT; ++t) {
        if (t + 1 < NT) asm volatile("s_waitcnt vmcnt(4)" ::: "memory");
        else            asm volatile("s_waitcnt vmcnt(0)" ::: "memory");
        __builtin_amdgcn_s_barrier();
        compute(t & 1);
        __builtin_amdgcn_s_barrier();
        if (t + 2 < NT) stage(t & 1, t + 2);
    }

    // scatter epilogue: out[b][h][w][f] pixel-shuffle
    #pragma unroll
    for (int n = 0; n < 2; ++n) {
        int col = wc * 32 + n * 16 + lr;
        float bj = bias[col];
        int p = col >> 3, q = col & 7;
        #pragma unroll
        for (int m = 0; m < 2; ++m) {
            int row = row0 + wr * 32 + m * 16 + quad * 4;
            #pragma unroll
            for (int r = 0; r < 4; ++r) {
                float v = acc[m][n][r] + bj;
                int rowv = row + r;
                int bq = rowv >> 10, hp = (rowv >> 5) & 31, wp = rowv & 31;
                C32[(((size_t)(bq * 256 + hp * 8 + p)) * 256 + wp * 8 + q) * 4 + f_idx] = v;
            }
        }
    }
}

// ---------------- fp16 MFMA GEMM, depth-3 counted-vmcnt pipeline, 2D-XCD swizzle ----------------
// OUT_MODE: 1 = f16 (conv prepass, fallback fc2).
template<int BN, int OUT_MODE, int ACT>
__global__ __launch_bounds__(256) void gemm_h(const _Float16* __restrict__ A,
        const _Float16* __restrict__ Bt, const float* __restrict__ bias,
        const float* __restrict__ pos, float* __restrict__ C32,
        _Float16* __restrict__ C16, _Float16* __restrict__ XR,
        _Float16* __restrict__ XI, int M, int N, int K, int f_idx)
{
    constexpr int WN  = BN / 2;
    constexpr int FN  = WN / 16;
    constexpr int NBJ = BN / 64;
    constexpr int LPT = 2 + NBJ;          // vmem loads per thread per K-tile
    __shared__ _Float16 Al[4][128 * 32];
    __shared__ _Float16 Bl[4][BN * 32];

    const int tid  = threadIdx.x;
    const int wave = tid >> 6;
    const int lane = tid & 63;
    const int wr   = wave >> 1;
    const int wc   = wave & 1;
    const int lr   = lane & 15;
    const int quad = lane >> 4;

    // XCD swizzle: prefer 2D (4 row-groups x 2 col-groups -> per-XCD A+B fits 4MB L2)
    const int gx = gridDim.x, gy = gridDim.y, nbk = gx * gy;
    int bx = blockIdx.x, by = blockIdx.y;
    if (!(gy & 3) && !(gx & 1)) {
        int id = by * gx + bx;
        int xcd = id & 7, j = id >> 3;
        int cols = gx >> 1;
        int rows = gy >> 2;
        int jr = j / cols, jc = j % cols;
        by = (xcd >> 1) * rows + jr;
        bx = (xcd & 1) * cols + jc;
    } else if (!(nbk & 7)) {
        int id  = by * gx + bx;
        int id2 = (id & 7) * (nbk >> 3) + (id >> 3);
        by = id2 / gx; bx = id2 % gx;
    }
    const int row0 = by * 128;
    const int col0 = bx * BN;

    const int srow = lane >> 2;
    const int skof = ((lane & 3) ^ (srow & 3)) * 8;

    auto stage = [&](int b, int kt) {
        const int k0 = kt << 5;
        #pragma unroll
        for (int j = 0; j < 2; ++j)
            async16(A + (size_t)(row0 + j * 64 + wave * 16 + srow) * K + k0 + skof,
                    &Al[b][(j * 64 + wave * 16) * 32]);
        #pragma unroll
        for (int j = 0; j < NBJ; ++j)
            async16(Bt + (size_t)(col0 + j * 64 + wave * 16 + srow) * K + k0 + skof,
                    &Bl[b][(j * 64 + wave * 16) * 32]);
    };

    float4v acc[4][FN];
    #pragma unroll
    for (int i = 0; i < 4; ++i)
        #pragma unroll
        for (int j = 0; j < FN; ++j) {
            float4v z = {0.f, 0.f, 0.f, 0.f};
            acc[i][j] = z;
        }

    auto compute = [&](int cb) {
        const int cA = (quad ^ (lr & 3)) * 8;   // swizzled chunk (halfs)
        half8 af[4], bf[FN];
        #pragma unroll
        for (int i = 0; i < 4; ++i)
            af[i] = *(const half8*)&Al[cb][(wr * 64 + i * 16 + lr) * 32 + cA];
        #pragma unroll
        for (int j = 0; j < FN; ++j)
            bf[j] = *(const half8*)&Bl[cb][(wc * WN + j * 16 + lr) * 32 + cA];
        #pragma unroll
        for (int i = 0; i < 4; ++i)
            #pragma unroll
            for (int j = 0; j < FN; ++j)
                acc[i][j] = __builtin_amdgcn_mfma_f32_16x16x32_f16(af[i], bf[j], acc[i][j], 0, 0, 0);
    };

    const int KT = K >> 5;                // K >= 768 -> KT >= 24 (always > 4)
    stage(0, 0); stage(1, 1); stage(2, 2);
    int kt = 0;
    for (; kt < KT - 3; ++kt) {
        stage((kt + 3) & 3, kt + 3);
        if constexpr (LPT == 4) asm volatile("s_waitcnt vmcnt(12)" ::: "memory");
        else                    asm volatile("s_waitcnt vmcnt(9)"  ::: "memory");
        __builtin_amdgcn_s_barrier();
        compute(kt & 3);
        asm volatile("" ::: "memory");
        __builtin_amdgcn_s_barrier();
    }
    // tail: 3 tiles in flight, no more staging; drain 2L -> L -> 0
    if constexpr (LPT == 4) asm volatile("s_waitcnt vmcnt(8)" ::: "memory");
    else                    asm volatile("s_waitcnt vmcnt(6)" ::: "memory");
    __builtin_amdgcn_s_barrier();
    compute(kt & 3); ++kt;
    asm volatile("" ::: "memory");
    __builtin_amdgcn_s_barrier();
    if constexpr (LPT == 4) asm volatile("s_waitcnt vmcnt(4)" ::: "memory");
    else                    asm volatile("s_waitcnt vmcnt(3)" ::: "memory");
    __builtin_amdgcn_s_barrier();
    compute(kt & 3); ++kt;
    asm volatile("" ::: "memory");
    __builtin_amdgcn_s_barrier();
    asm volatile("s_waitcnt vmcnt(0)" ::: "memory");
    __builtin_amdgcn_s_barrier();
    compute(kt & 3);

    #pragma unroll
    for (int j = 0; j < FN; ++j) {
        int col = col0 + wc * WN + j * 16 + lr;
        float bj = bias[col];
        #pragma unroll
        for (int i = 0; i < 4; ++i) {
            int row = row0 + wr * 64 + i * 16 + quad * 4;
            #pragma unroll
            for (int r = 0; r < 4; ++r) {
                float v = acc[i][j][r] + bj;
                if (pos) v += pos[(size_t)((row + r) & 1023) * N + col];
                if (ACT) v = gelu_f(v);
                if (OUT_MODE == 3) {
                    int rowv = row + r;
                    int bq = rowv >> 10, hp = (rowv >> 5) & 31, wp = rowv & 31;
                    int p = col >> 3, q = col & 7;
                    C32[(((size_t)(bq * 256 + hp * 8 + p)) * 256 + wp * 8 + q) * 4 + f_idx] = v;
                } else {
                    C16[(size_t)(row + r) * N + col] = (_Float16)v;
                }
            }
        }
    }
}

// ---------------- launch ----------------
extern "C" void kernel_launch(void* const* d_in, const int* in_sizes, int n_in,
                              void* d_out, int out_size, void* d_ws, size_t ws_size,
                              hipStream_t stream) {
    const float* x        = (const float*)d_in[0];
    const float* grd      = (const float*)d_in[1];
    const float* conv_w   = (const float*)d_in[2];
    const float* conv_b   = (const float*)d_in[3];
    const float* pos_emb  = (const float*)d_in[4];
    const float* w1       = (const float*)d_in[5];
    const float* b1       = (const float*)d_in[6];
    const float* w2       = (const float*)d_in[7];
    const float* b2       = (const float*)d_in[8];
    const float* fc1_w    = (const float*)d_in[9];
    const float* fc1_b    = (const float*)d_in[10];
    const float* fc2_w    = (const float*)d_in[11];
    const float* fc2_b    = (const float*)d_in[12];
    const float* head_w1  = (const float*)d_in[13];
    const float* head_b1  = (const float*)d_in[14];
    const float* head_w2  = (const float*)d_in[15];
    const float* head_b2  = (const float*)d_in[16];
    float* out = (float*)d_out;
    float* ws  = (float*)d_ws;

    // ---- workspace layout, sizes in float units ----
    float* pf = ws;
    _Float16* t_h     = (_Float16*)pf; pf += 1572864;   // 4096x768 f16 (residual state)
    _Float16* Wsp     = (_Float16*)pf; pf += 589824;    // 128x9216 f16 spectral weights
    _Float16* h1t     = (_Float16*)pf; pf += 589824;    // [1536][768] f16
    _Float16* h2t     = (_Float16*)pf; pf += 49152;     // [64][1536] f16
    _Float16* convw_h = (_Float16*)pf; pf += 294912;    // 768x768 f16 (prepass only)
    float* alias    = pf;              pf += 6291456;   // hid_h 4096x3072 f16
    _Float16* hid_h = (_Float16*)alias;
    _Float16* WtAll = (_Float16*)pf;   pf += 9437184;   // 8 x [N][K] fc weights f16
    // fallback xa inside alias (hid dead when xa live); full mode: dedicated xa after WtAll
    _Float16* xa_r_fb = (_Float16*)alias;
    _Float16* xa_i_fb = (_Float16*)(alias + 835584);
    _Float16* xa_r_fu = (_Float16*)pf;                  // +835,584 f
    _Float16* xa_i_fu = (_Float16*)(pf + 835584);       // +835,584 f
    size_t full_total = (size_t)(pf - ws) + 1671168;    // 20,496,384 f = 82.0 MB
    bool full = ws_size >= full_total * 4ull;
    _Float16* xa_r = full ? xa_r_fu : xa_r_fb;
    _Float16* xa_i = full ? xa_i_fu : xa_i_fb;
    _Float16* A_h  = (_Float16*)alias;                  // prepass-only (gather input, dead after)

    // ---- prepass ----
    prep_specw<<<dim3(128), 256, 0, stream>>>(w1, w2, Wsp);
    cvt_f16<<<dim3(576), 256, 0, stream>>>(conv_w, convw_h);
    cvt_transpose<<<dim3(24, 48), 256, 0, stream>>>(head_w1, h1t, 768, 1536);
    cvt_transpose<<<dim3(48, 2), 256, 0, stream>>>(head_w2, h2t, 1536, 64);
    for (int d = 0; d < 4; ++d) {
        cvt_transpose<<<dim3(24, 96), 256, 0, stream>>>(
            fc1_w + (size_t)d * 2359296, WtAll + (size_t)(2 * d) * 2359296, 768, 3072);
        cvt_transpose<<<dim3(96, 24), 256, 0, stream>>>(
            fc2_w + (size_t)d * 2359296, WtAll + (size_t)(2 * d + 1) * 2359296, 3072, 768);
    }
    gather_patch<<<dim3(12288), 256, 0, stream>>>(x, grd, A_h);
    gemm_h<128, 1, 0><<<dim3(6, 32), 256, 0, stream>>>(
        A_h, convw_h, conv_b, pos_emb, nullptr, t_h, nullptr, nullptr, 4096, 768, 768, 0);
    dft_fwd_w<<<dim3(128, 3), 256, 0, stream>>>(t_h, xa_r, xa_i);

    for (int f = 0; f < 4; ++f) {
        for (int d = 0; d < 4; ++d) {
            // fused H-DFT + complex MLP + H-IDFT (in-place on xa), 12 waves
            spec_fused<<<dim3(68, 8), 768, 0, stream>>>(
                xa_r, xa_i,
                Wsp + (size_t)(d * 4 + 0) * 73728, Wsp + (size_t)(d * 4 + 1) * 73728,
                Wsp + (size_t)(d * 4 + 2) * 73728, Wsp + (size_t)(d * 4 + 3) * 73728,
                b1 + d * 1536, b1 + d * 1536 + 768,
                b2 + d * 1536, b2 + d * 1536 + 768);
            // irfft2 W-pass + f16 residual (in place on t_h) -- MFMA version (R15)
            idft_w_mfma<<<dim3(128, 4), 256, 0, stream>>>(xa_r, xa_i, t_h);
            // channel MLP fc1: 128x192 tile, 512 blocks = 2/CU
            gemm128d<192, 1><<<dim3(16, 32), 512, 0, stream>>>(
                t_h, WtAll + (size_t)(2 * d) * 2359296, fc1_b + d * 3072,
                hid_h, 4096, 3072, 768);
            if (full) {
                // fc2 + fused forward W-DFT (seeds xa for the next spectral block)
                fc2_fused<<<dim3(12, 64), 256, 0, stream>>>(
                    hid_h, WtAll + (size_t)(2 * d + 1) * 2359296, fc2_b + d * 768,
                    t_h, xa_r, xa_i);
            } else {
                gemm_h<64, 1, 0><<<dim3(12, 32), 256, 0, stream>>>(
                    hid_h, WtAll + (size_t)(2 * d + 1) * 2359296, fc2_b + d * 768,
                    nullptr, nullptr, t_h, nullptr, nullptr, 4096, 768, 3072, 0);
                dft_fwd_w<<<dim3(128, 3), 256, 0, stream>>>(t_h, xa_r, xa_i);
            }
        }
        // head on current state (t_h from fc2)
        gemm128d<192, 1><<<dim3(8, 32), 512, 0, stream>>>(
            t_h, h1t, head_b1, hid_h, 4096, 1536, 768);
        head2_k<<<dim3(64), 256, 0, stream>>>(
            hid_h, h2t, head_b2, out, f);
    }
}

// Round 9
// 1660.294 us; speedup vs baseline: 1.6475x; 1.0245x over previous
//
#include <hip/hip_runtime.h>
#include <hip/hip_bf16.h>
#include <math.h>

// ---------------- static config ----------------
// B=4, H=W=256, TIN=10, F=4, P=8, CIN=12, E=768, NB=8, BS=96,
// HP=WP=32, MID=3072, DEPTH=4, LAM=0.01, WF=17, TOK=4096, POS=B*32*17=2176
// Spectral layout: X[((b*17+kw)*32 + h)*768 + c]   (h-rows contiguous per kw)
// R12: gemm128d (128-row tile, 8 waves, counted vmcnt) for fc1/head1.
// R15/R16: idft_w_mfma (W-IDFT as one mfma K-step).
// R17: spec_fused 12 waves; fc2_fused 64x64, 3 blk/CU.
// R18: (a) conv prepass gemm_h -> gemm128d<64,ACT=0,POS=1> grid (12,32)
//   (was 40us @ 4% MfmaUtil on the old skeleton); (b) head1 -> gemm128d<64>
//   grid (24,32)=768 blocks=3/CU (BN=192 was exactly 1 blk/CU, no TLP);
//   (c) cvt_transpose8 batches the 8 per-iteration fc-weight transposes.

typedef __attribute__((ext_vector_type(8))) _Float16 half8;
typedef __attribute__((ext_vector_type(4))) _Float16 half4v;
typedef __attribute__((ext_vector_type(4))) float float4v;

__device__ __forceinline__ float gelu_f(float v) {
    return 0.5f * v * (1.0f + erff(v * 0.70710678118654752f));
}
__device__ __forceinline__ float shrink_f(float v) {
    return (v > 0.01f) ? (v - 0.01f) : ((v < -0.01f) ? (v + 0.01f) : 0.0f);
}

#define STEP32 0.19634954084936207f  // 2*pi/32

// async 16B global->LDS (lds dest wave-uniform; HW adds lane*16)
__device__ __forceinline__ void async16(const void* g, void* l) {
    __builtin_amdgcn_global_load_lds(
        (const __attribute__((address_space(1))) unsigned int*)g,
        (__attribute__((address_space(3))) unsigned int*)l, 16, 0, 0);
}

// ---------------- gather patches into A_h [4096][768] f16 ----------------
__global__ __launch_bounds__(256) void gather_patch(const float* __restrict__ x,
        const float* __restrict__ grd, _Float16* __restrict__ A)
{
    int idx = blockIdx.x * 256 + threadIdx.x;
    int j   = idx % 768;
    int tok = idx / 768;
    int c = j >> 6, p = (j >> 3) & 7, q = j & 7;
    int wp = tok & 31, hp = (tok >> 5) & 31, b = tok >> 10;
    int hh = hp * 8 + p, ww = wp * 8 + q;
    float v;
    if (c < 10) v = x[((b * 256 + hh) * 256 + ww) * 10 + c];
    else        v = grd[((b * 256 + hh) * 256 + ww) * 2 + (c - 10)];
    A[idx] = (_Float16)v;
}

// ---------------- forward DFT along W (f16 in -> 17 complex f16), scale 1/32 ----------------
// prepass + fallback path. out layout [b,kw,h,c]
__global__ __launch_bounds__(256) void dft_fwd_w(const _Float16* __restrict__ th,
        _Float16* __restrict__ Xr, _Float16* __restrict__ Xi)
{
    __shared__ float2 lut[32];
    int bh = blockIdx.x;            // b*32 + h
    int tid = threadIdx.x;
    if (tid < 32) { float a = tid * STEP32; lut[tid] = make_float2(cosf(a), sinf(a)); }
    __syncthreads();
    int b = bh >> 5, h = bh & 31;
    int c = blockIdx.y * 256 + tid;
    float v[32];
    #pragma unroll
    for (int w = 0; w < 32; ++w) v[w] = (float)th[(bh * 32 + w) * 768 + c];
    for (int kw = 0; kw <= 16; ++kw) {
        float ar = 0.f, ai = 0.f;
        #pragma unroll
        for (int w = 0; w < 32; ++w) {
            float2 cs = lut[(kw * w) & 31];
            ar += v[w] * cs.x;
            ai -= v[w] * cs.y;
        }
        size_t g = ((size_t)(b * 17 + kw) * 32 + h) * 768 + c;
        Xr[g] = (_Float16)(ar * 0.03125f);
        Xi[g] = (_Float16)(ai * 0.03125f);
    }
}

// ---------------- R15: MFMA inverse W-DFT + f16 residual ----------------
__global__ __launch_bounds__(256) void idft_w_mfma(const _Float16* __restrict__ Yr,
        const _Float16* __restrict__ Yi, _Float16* __restrict__ th)
{
    __shared__ alignas(16) _Float16 Yt[192 * 40];   // [c_local][slot] pad-40, 15 KB
    __shared__ alignas(16) _Float16 El[32 * 40];    // [w][slot] pad-40, 2.5 KB

    const int tid  = threadIdx.x;
    const int wave = tid >> 6;          // 0..3
    const int lane = tid & 63;
    const int lr   = lane & 15;
    const int quad = lane >> 4;

    const int bh = blockIdx.x;
    const int b  = bh >> 5, h = bh & 31;
    const int c0 = blockIdx.y * 192;

    // E' twiddles (f16, factors folded)
    for (int i = tid; i < 1024; i += 256) {
        int w = i >> 5, s = i & 31;
        float val;
        if (s <= 16) {
            float g = (s == 0 || s == 16) ? 1.f : 2.f;
            val = g * cosf(((w * s) & 31) * STEP32) * 0.03125f;
        } else {
            int k = s - 16;
            val = -2.f * sinf(((w * k) & 31) * STEP32) * 0.03125f;
        }
        El[w * 40 + s] = (_Float16)val;
    }

    // stage Y' -> Yt[c][slot]: coalesced half8 loads; transpose scalar writes
    // with e^(cg&7) perm (spreads the 32-way same-bank write pattern to 8-way).
    #pragma unroll
    for (int i = 0; i < 3; ++i) {
        int u    = tid + i * 256;
        int slot = u / 24;
        int cg   = u % 24;
        const _Float16* src;
        if (slot < 17) src = Yr + ((size_t)(b * 17 + slot) * 32 + h) * 768;
        else           src = Yi + ((size_t)(b * 17 + (slot - 16)) * 32 + h) * 768;
        half8 v = *(const half8*)(src + c0 + cg * 8);
        #pragma unroll
        for (int e = 0; e < 8; ++e) {
            int el = e ^ (cg & 7);
            Yt[(cg * 8 + el) * 40 + slot] = v[el];
        }
    }
    __syncthreads();

    // MFMA: acc[m][n], m = w-half (0..1), n = c-frag (0..2)
    half8 af[2], bf[3];
    #pragma unroll
    for (int m = 0; m < 2; ++m)
        af[m] = *(const half8*)&El[(m * 16 + lr) * 40 + quad * 8];
    #pragma unroll
    for (int n = 0; n < 3; ++n)
        bf[n] = *(const half8*)&Yt[(wave * 48 + n * 16 + lr) * 40 + quad * 8];
    float4v acc[2][3];
    #pragma unroll
    for (int m = 0; m < 2; ++m)
        #pragma unroll
        for (int n = 0; n < 3; ++n) {
            float4v z = {0.f, 0.f, 0.f, 0.f};
            acc[m][n] = __builtin_amdgcn_mfma_f32_16x16x32_f16(af[m], bf[n], z, 0, 0, 0);
        }

    // residual RMW (same pattern as old dft_inv_w)
    #pragma unroll
    for (int m = 0; m < 2; ++m)
        #pragma unroll
        for (int n = 0; n < 3; ++n) {
            int c = c0 + wave * 48 + n * 16 + lr;
            #pragma unroll
            for (int r = 0; r < 4; ++r) {
                int w = m * 16 + quad * 4 + r;
                size_t gi = (size_t)(bh * 32 + w) * 768 + c;
                th[gi] = (_Float16)(acc[m][n][r] + (float)th[gi]);
            }
        }
}

// ---------------- spectral weight prep: [i][o] fp32 -> [o][i] f16, 128 matrices ----------------
__global__ __launch_bounds__(256) void prep_specw(const float* __restrict__ w1,
        const float* __restrict__ w2, _Float16* __restrict__ out)
{
    __shared__ float tile[96][97];
    int mid = blockIdx.x;
    int n  = mid & 7;
    int ri = (mid >> 3) & 1;
    int l  = (mid >> 4) & 1;
    int d  = mid >> 5;
    const float* src = (l ? w2 : w1) + ((size_t)(d * 2 + ri) * 8 + n) * 9216;
    for (int idx = threadIdx.x; idx < 9216; idx += 256)
        tile[idx / 96][idx % 96] = src[idx];
    __syncthreads();
    _Float16* dst = out + (size_t)mid * 9216;
    for (int idx = threadIdx.x; idx < 9216; idx += 256)
        dst[idx] = (_Float16)tile[idx % 96][idx / 96];   // dst[o][i] = src[i][o]
}

// ---------------- fused spectral: H-DFT -> spec1(gelu) -> spec2(shrink) -> H-IDFT ----------------
// IN-PLACE on X ([b,kw,h,c] layout). grid (68 = b*17+kw, 8 = n).
// R17: 768 thr = 12 waves; wave = (wr = wave/6 kh-half, wo = wave%6 frag idx).
__global__ __launch_bounds__(768) void spec_fused(
        _Float16* __restrict__ Xr, _Float16* __restrict__ Xi,
        const _Float16* __restrict__ W1r, const _Float16* __restrict__ W1i,
        const _Float16* __restrict__ W2r, const _Float16* __restrict__ W2i,
        const float* __restrict__ b1r, const float* __restrict__ b1i,
        const float* __restrict__ b2r, const float* __restrict__ b2i)
{
    __shared__ alignas(16) _Float16 Ec[1024], Es[1024];       // [m][k] twiddle 32x32
    __shared__ alignas(16) _Float16 XTr[3840], XTi[3840];     // [c][h] pad40; stage C: [o][kh]
    __shared__ alignas(16) _Float16 Zr[3328], Zi[3328];       // [kh][c] pad104; stage D out [h][c]
    __shared__ alignas(16) _Float16 Sr[3328], Si[3328];       // [kh][o] pad104

    const int bk = blockIdx.x;       // b*17 + kw
    const int n  = blockIdx.y;
    const int tid = threadIdx.x;
    const int wave = tid >> 6, lane = tid & 63;
    const int wr = wave / 6;         // kh/h half (0..1)
    const int wo = wave % 6;         // fragment index (0..5)
    const int lr = lane & 15, quad = lane >> 4;
    const size_t base = (size_t)bk * 24576 + n * 96;    // + h*768 + c

    for (int i = tid; i < 1024; i += 768) {
        int kh = i >> 5, h = i & 31;
        float a = ((kh * h) & 31) * STEP32;
        Ec[i] = (_Float16)cosf(a);
        Es[i] = (_Float16)sinf(a);
    }
    // vector load -> LDS transpose [c][h]
    for (int i = tid; i < 384; i += 768) {
        int h = i / 12, cc = (i % 12) * 8;
        half8 vr = *(const half8*)(Xr + base + (size_t)h * 768 + cc);
        half8 vi = *(const half8*)(Xi + base + (size_t)h * 768 + cc);
        #pragma unroll
        for (int e = 0; e < 8; ++e) {
            XTr[(cc + e) * 40 + h] = vr[e];
            XTi[(cc + e) * 40 + h] = vi[e];
        }
    }
    __syncthreads();

    const _Float16* w1r = W1r + (size_t)n * 9216;
    const _Float16* w1i = W1i + (size_t)n * 9216;
    const _Float16* w2r = W2r + (size_t)n * 9216;
    const _Float16* w2i = W2i + (size_t)n * 9216;

    half8 eC = *(const half8*)&Ec[(wr * 16 + lr) * 32 + quad * 8];
    half8 eS = *(const half8*)&Es[(wr * 16 + lr) * 32 + quad * 8];
    half8 eSn = -eS;

    // stage A: Z[kh][c] = DFT_h(X) -- wave handles c-tile wo
    {
        int c = wo * 16 + lr;
        float4v zr = {0,0,0,0}, zi = {0,0,0,0};
        half8 xr = *(const half8*)&XTr[c * 40 + quad * 8];
        half8 xi = *(const half8*)&XTi[c * 40 + quad * 8];
        zr = __builtin_amdgcn_mfma_f32_16x16x32_f16(eC,  xr, zr, 0, 0, 0);
        zr = __builtin_amdgcn_mfma_f32_16x16x32_f16(eS,  xi, zr, 0, 0, 0);
        zi = __builtin_amdgcn_mfma_f32_16x16x32_f16(eC,  xi, zi, 0, 0, 0);
        zi = __builtin_amdgcn_mfma_f32_16x16x32_f16(eSn, xr, zi, 0, 0, 0);
        #pragma unroll
        for (int r = 0; r < 4; ++r) {
            int kh = wr * 16 + quad * 4 + r;
            Zr[kh * 104 + c] = (_Float16)zr[r];
            Zi[kh * 104 + c] = (_Float16)zi[r];
        }
    }
    __syncthreads();

    // stage B: S = gelu(Z @ W1 + b1) -- wave handles o-tile wo
    {
        int o = wo * 16 + lr;
        float4v sr = {0,0,0,0}, si = {0,0,0,0};
        #pragma unroll
        for (int kc = 0; kc < 3; ++kc) {
            half8 ar = *(const half8*)&Zr[(wr * 16 + lr) * 104 + kc * 32 + quad * 8];
            half8 ai = *(const half8*)&Zi[(wr * 16 + lr) * 104 + kc * 32 + quad * 8];
            half8 ain = -ai;
            half8 br = *(const half8*)&w1r[o * 96 + kc * 32 + quad * 8];
            half8 bi = *(const half8*)&w1i[o * 96 + kc * 32 + quad * 8];
            sr = __builtin_amdgcn_mfma_f32_16x16x32_f16(ar,  br, sr, 0, 0, 0);
            sr = __builtin_amdgcn_mfma_f32_16x16x32_f16(ain, bi, sr, 0, 0, 0);
            si = __builtin_amdgcn_mfma_f32_16x16x32_f16(ai,  br, si, 0, 0, 0);
            si = __builtin_amdgcn_mfma_f32_16x16x32_f16(ar,  bi, si, 0, 0, 0);
        }
        float br = b1r[n * 96 + o], bi = b1i[n * 96 + o];
        #pragma unroll
        for (int r = 0; r < 4; ++r) {
            int kh = wr * 16 + quad * 4 + r;
            Sr[kh * 104 + o] = (_Float16)gelu_f(sr[r] + br);
            Si[kh * 104 + o] = (_Float16)gelu_f(si[r] + bi);
        }
    }
    __syncthreads();

    // stage C: T = shrink(S @ W2 + b2) -> transposed T2T[o][kh] (alias XT)
    {
        int o = wo * 16 + lr;
        float4v tr = {0,0,0,0}, ti = {0,0,0,0};
        #pragma unroll
        for (int kc = 0; kc < 3; ++kc) {
            half8 ar = *(const half8*)&Sr[(wr * 16 + lr) * 104 + kc * 32 + quad * 8];
            half8 ai = *(const half8*)&Si[(wr * 16 + lr) * 104 + kc * 32 + quad * 8];
            half8 ain = -ai;
            half8 br = *(const half8*)&w2r[o * 96 + kc * 32 + quad * 8];
            half8 bi = *(const half8*)&w2i[o * 96 + kc * 32 + quad * 8];
            tr = __builtin_amdgcn_mfma_f32_16x16x32_f16(ar,  br, tr, 0, 0, 0);
            tr = __builtin_amdgcn_mfma_f32_16x16x32_f16(ain, bi, tr, 0, 0, 0);
            ti = __builtin_amdgcn_mfma_f32_16x16x32_f16(ai,  br, ti, 0, 0, 0);
            ti = __builtin_amdgcn_mfma_f32_16x16x32_f16(ar,  bi, ti, 0, 0, 0);
        }
        float br = b2r[n * 96 + o], bi = b2i[n * 96 + o];
        #pragma unroll
        for (int r = 0; r < 4; ++r) {
            int kh = wr * 16 + quad * 4 + r;
            XTr[o * 40 + kh] = (_Float16)shrink_f(tr[r] + br);
            XTi[o * 40 + kh] = (_Float16)shrink_f(ti[r] + bi);
        }
    }
    __syncthreads();

    // stage D: Y[h][c] = IDFT_h(T2) -> Zr/Zi as [h][c] pad104
    {
        int c = wo * 16 + lr;
        float4v yr = {0,0,0,0}, yi = {0,0,0,0};
        half8 t2r = *(const half8*)&XTr[c * 40 + quad * 8];
        half8 t2i = *(const half8*)&XTi[c * 40 + quad * 8];
        yr = __builtin_amdgcn_mfma_f32_16x16x32_f16(eC,  t2r, yr, 0, 0, 0);
        yr = __builtin_amdgcn_mfma_f32_16x16x32_f16(eSn, t2i, yr, 0, 0, 0);
        yi = __builtin_amdgcn_mfma_f32_16x16x32_f16(eC,  t2i, yi, 0, 0, 0);
        yi = __builtin_amdgcn_mfma_f32_16x16x32_f16(eS,  t2r, yi, 0, 0, 0);
        #pragma unroll
        for (int r = 0; r < 4; ++r) {
            int h = wr * 16 + quad * 4 + r;
            Zr[h * 104 + c] = (_Float16)yr[r];
            Zi[h * 104 + c] = (_Float16)yi[r];
        }
    }
    __syncthreads();

    // vector store back (in-place)
    for (int i = tid; i < 384; i += 768) {
        int h = i / 12, cc = (i % 12) * 8;
        half8 vr = *(const half8*)&Zr[h * 104 + cc];
        half8 vi = *(const half8*)&Zi[h * 104 + cc];
        *(half8*)(Xr + base + (size_t)h * 768 + cc) = vr;
        *(half8*)(Xi + base + (size_t)h * 768 + cc) = vi;
    }
}

// ---------------- f32 -> f16 elementwise (vectorized x4) ----------------
__global__ __launch_bounds__(256) void cvt_f16(const float* __restrict__ in,
        _Float16* __restrict__ out)
{
    int i = blockIdx.x * 256 + threadIdx.x;
    float4 v = ((const float4*)in)[i];
    half4v o;
    o.x = (_Float16)v.x; o.y = (_Float16)v.y; o.z = (_Float16)v.z; o.w = (_Float16)v.w;
    ((half4v*)out)[i] = o;
}

// ---------------- f32 [K][N] -> f16 [N][K] transpose ----------------
__global__ __launch_bounds__(256) void cvt_transpose(const float* __restrict__ in,
        _Float16* __restrict__ out, int K, int N)
{
    __shared__ float tile[32][33];
    int kb = blockIdx.x * 32, nb = blockIdx.y * 32;
    int tx = threadIdx.x & 31, ty = threadIdx.x >> 5;
    #pragma unroll
    for (int r = 0; r < 32; r += 8)
        tile[ty + r][tx] = in[(size_t)(kb + ty + r) * N + nb + tx];
    __syncthreads();
    #pragma unroll
    for (int r = 0; r < 32; r += 8)
        out[(size_t)(nb + ty + r) * K + kb + tx] = (_Float16)tile[tx][ty + r];
}

// ---------------- R18: batched fc-weight transpose (8 matrices, 1 launch) ----------------
// z = d*2 + l: l=0 -> fc1_w[d] (K=768,N=3072), l=1 -> fc2_w[d] (K=3072,N=768).
// dst = WtAll + z*2359296. Both shapes have 2304 32x32 tiles.
__global__ __launch_bounds__(256) void cvt_transpose8(const float* __restrict__ fc1w,
        const float* __restrict__ fc2w, _Float16* __restrict__ WtAll)
{
    __shared__ float tile[32][33];
    const int z  = blockIdx.y;
    const int l  = z & 1;
    const int d  = z >> 1;
    const int K  = l ? 3072 : 768;
    const int N  = l ? 768 : 3072;
    const float* src = (l ? fc2w : fc1w) + (size_t)d * 2359296;
    _Float16*    dst = WtAll + (size_t)z * 2359296;
    const int nt = N >> 5;
    int kb = (blockIdx.x / nt) * 32;
    int nb = (blockIdx.x % nt) * 32;
    int tx = threadIdx.x & 31, ty = threadIdx.x >> 5;
    #pragma unroll
    for (int r = 0; r < 32; r += 8)
        tile[ty + r][tx] = src[(size_t)(kb + ty + r) * N + nb + tx];
    __syncthreads();
    #pragma unroll
    for (int r = 0; r < 32; r += 8)
        dst[(size_t)(nb + ty + r) * K + kb + tx] = (_Float16)tile[tx][ty + r];
}

// ---------------- R12/R18: 128-row-tile 8-wave GEMM, counted vmcnt ----------------
// BN=192: WN=48 FN=3 BU=3 LPT=5 (fc1). BN=64: WN=16 FN=1 BU=1 LPT=3 (conv/head1).
// POS: add pos_emb[(row&1023)*N+col] in epilogue (conv).
template<int BN, int ACT, int POS>
__global__ __launch_bounds__(512, 4) void gemm128d(const _Float16* __restrict__ A,
        const _Float16* __restrict__ Bt, const float* __restrict__ bias,
        const float* __restrict__ pos, _Float16* __restrict__ C16,
        int M, int N, int K)
{
    constexpr int WN  = BN / 4;
    constexpr int FN  = WN / 16;
    constexpr int AU  = 2;                // A: 2 x 64-row units
    constexpr int BU  = BN / 64;
    constexpr int LPT = AU + BU;          // loads/thread/K-tile
    __shared__ _Float16 Al[2][128 * 64];
    __shared__ _Float16 Bl[2][BN * 64];

    const int tid  = threadIdx.x;
    const int wave = tid >> 6;            // 0..7
    const int lane = tid & 63;
    const int wr   = wave >> 2;           // 0..1 (M)
    const int wc   = wave & 3;            // 0..3 (N)
    const int lr   = lane & 15;
    const int quad = lane >> 4;

    // XCD swizzle (2D): per-XCD contiguous patch for L2 reuse
    const int gx = gridDim.x, gy = gridDim.y, nbk = gx * gy;
    int bx = blockIdx.x, by = blockIdx.y;
    if (!(gy & 3) && !(gx & 1)) {
        int id = by * gx + bx;
        int xcd = id & 7, j = id >> 3;
        int cols = gx >> 1;
        int rows = gy >> 2;
        int jr = j / cols, jc = j % cols;
        by = (xcd >> 1) * rows + jr;
        bx = (xcd & 1) * cols + jc;
    } else if (!(nbk & 7)) {
        int id  = by * gx + bx;
        int id2 = (id & 7) * (nbk >> 3) + (id >> 3);
        by = id2 / gx; bx = id2 % gx;
    }
    const int row0 = by * 128;
    const int col0 = bx * BN;

    // staging: per 64-row unit (64x64 halfs = 8KB) each wave covers 8 rows.
    const int srow = lane >> 3;
    const int schk = (lane & 7) ^ (srow & 7);
    const _Float16* Ab = A  + (size_t)(row0 + wave * 8 + srow) * K + schk * 8;
    const _Float16* Bb = Bt + (size_t)(col0 + wave * 8 + srow) * K + schk * 8;

    auto stage = [&](int b, int kt) {
        const int k0 = kt * 64;
        #pragma unroll
        for (int u = 0; u < AU; ++u)
            async16(Ab + (size_t)u * 64 * K + k0, &Al[b][(u * 64 + wave * 8) * 64]);
        #pragma unroll
        for (int u = 0; u < BU; ++u)
            async16(Bb + (size_t)u * 64 * K + k0, &Bl[b][(u * 64 + wave * 8) * 64]);
    };

    float4v acc[4][FN];
    #pragma unroll
    for (int m = 0; m < 4; ++m)
        #pragma unroll
        for (int n = 0; n < FN; ++n) {
            float4v z = {0.f, 0.f, 0.f, 0.f};
            acc[m][n] = z;
        }

    auto compute = [&](int cb) {
        #pragma unroll
        for (int ks = 0; ks < 2; ++ks) {
            const int cA = ((ks * 4 + quad) ^ (lr & 7)) * 8;   // swizzled chunk (halfs)
            half8 bf[FN];
            #pragma unroll
            for (int n = 0; n < FN; ++n)
                bf[n] = *(const half8*)&Bl[cb][(wc * WN + n * 16 + lr) * 64 + cA];
            half8 af[4];
            #pragma unroll
            for (int m = 0; m < 4; ++m)
                af[m] = *(const half8*)&Al[cb][(wr * 64 + m * 16 + lr) * 64 + cA];
            __builtin_amdgcn_s_setprio(1);
            #pragma unroll
            for (int m = 0; m < 4; ++m)
                #pragma unroll
                for (int n = 0; n < FN; ++n)
                    acc[m][n] = __builtin_amdgcn_mfma_f32_16x16x32_f16(af[m], bf[n], acc[m][n], 0, 0, 0);
            __builtin_amdgcn_s_setprio(0);
        }
    };

    const int NT = K >> 6;                // K=768 -> 12 tiles
    stage(0, 0);
    stage(1, 1);
    for (int t = 0; t < NT; ++t) {
        if (t + 1 < NT) {
            if constexpr (LPT == 5) asm volatile("s_waitcnt vmcnt(5)" ::: "memory");
            else                    asm volatile("s_waitcnt vmcnt(3)" ::: "memory");
        } else {
            asm volatile("s_waitcnt vmcnt(0)" ::: "memory");
        }
        __builtin_amdgcn_s_barrier();     // all waves' tile-t loads visible
        compute(t & 1);
        __builtin_amdgcn_s_barrier();     // all waves done reading buf[t&1]
        if (t + 2 < NT) stage(t & 1, t + 2);   // prefetch into just-freed buffer
    }

    // epilogue: bias (+pos) (+GELU) -> f16 store
    #pragma unroll
    for (int n = 0; n < FN; ++n) {
        int col = col0 + wc * WN + n * 16 + lr;
        float bj = bias[col];
        #pragma unroll
        for (int m = 0; m < 4; ++m) {
            int row = row0 + wr * 64 + m * 16 + quad * 4;
            #pragma unroll
            for (int r = 0; r < 4; ++r) {
                float v = acc[m][n][r] + bj;
                if (POS) v += pos[(size_t)((row + r) & 1023) * N + col];
                if (ACT) v = gelu_f(v);
                C16[(size_t)(row + r) * N + col] = (_Float16)v;
            }
        }
    }
}

// ---------------- R17: fc2 + fused forward W-DFT, 64x64 tile, 4 waves, 3 blk/CU ----------------
__global__ __launch_bounds__(256, 3) void fc2_fused(const _Float16* __restrict__ A,
        const _Float16* __restrict__ Bt, const float* __restrict__ bias,
        _Float16* __restrict__ C16, _Float16* __restrict__ XR,
        _Float16* __restrict__ XI)
{
    constexpr int K = 3072;
    constexpr int NT = 48;
    __shared__ _Float16 Al[2][64 * 64];        // 16 KB
    __shared__ _Float16 Bl[2][64 * 64];        // 16 KB
    __shared__ alignas(16) _Float16 Tl[2 * 64 * 40];           // 10 KB  [h][c][w pad40]
    __shared__ alignas(16) _Float16 ECl[1024], ESl[1024];      // 4 KB

    const int tid  = threadIdx.x;
    const int wave = tid >> 6;            // 0..3
    const int lane = tid & 63;
    const int wr   = wave >> 1;           // 0..1 (M: 32-row half)
    const int wc   = wave & 1;            // 0..1 (N: 32-col half)
    const int lr   = lane & 15;
    const int quad = lane >> 4;

    // twiddle fill early (hides under prologue load latency)
    for (int i = tid; i < 1024; i += 256) {
        int kw = i >> 5, w = i & 31;
        float a = ((kw * w) & 31) * STEP32;
        ECl[i] = (_Float16)(cosf(a) * 0.03125f);
        ESl[i] = (_Float16)(-sinf(a) * 0.03125f);
    }

    // XCD swizzle (2D): gx=12, gy=64 -> cols=6, rows=16 per XCD patch
    const int gx = gridDim.x, gy = gridDim.y;
    int bx = blockIdx.x, by = blockIdx.y;
    {
        int id = by * gx + bx;
        int xcd = id & 7, j = id >> 3;
        int cols = gx >> 1;
        int rows = gy >> 2;
        int jr = j / cols, jc = j % cols;
        by = (xcd >> 1) * rows + jr;
        bx = (xcd & 1) * cols + jc;
    }
    const int row0 = by * 64;
    const int col0 = bx * 64;

    // staging: A/B each 2 units of 32 rows; wave covers 8 rows/unit.
    const int srow = lane >> 3;
    const int schk = (lane & 7) ^ srow;
    const _Float16* Ab = A  + (size_t)(row0 + wave * 8 + srow) * K + schk * 8;
    const _Float16* Bb = Bt + (size_t)(col0 + wave * 8 + srow) * K + schk * 8;

    auto stage = [&](int b, int kt) {
        const int k0 = kt * 64;
        #pragma unroll
        for (int u = 0; u < 2; ++u)
            async16(Ab + (size_t)u * 32 * K + k0, &Al[b][(u * 32 + wave * 8) * 64]);
        #pragma unroll
        for (int u = 0; u < 2; ++u)
            async16(Bb + (size_t)u * 32 * K + k0, &Bl[b][(u * 32 + wave * 8) * 64]);
    };

    float4v acc[2][2];
    #pragma unroll
    for (int m = 0; m < 2; ++m)
        #pragma unroll
        for (int n = 0; n < 2; ++n) {
            float4v z = {0.f, 0.f, 0.f, 0.f};
            acc[m][n] = z;
        }

    auto compute = [&](int cb) {
        #pragma unroll
        for (int ks = 0; ks < 2; ++ks) {
            const int cA = ((ks * 4 + quad) ^ (lr & 7)) * 8;   // swizzled chunk (halfs)
            half8 bf[2], af[2];
            #pragma unroll
            for (int n = 0; n < 2; ++n)
                bf[n] = *(const half8*)&Bl[cb][(wc * 32 + n * 16 + lr) * 64 + cA];
            #pragma unroll
            for (int m = 0; m < 2; ++m)
                af[m] = *(const half8*)&Al[cb][(wr * 32 + m * 16 + lr) * 64 + cA];
            __builtin_amdgcn_s_setprio(1);
            #pragma unroll
            for (int m = 0; m < 2; ++m)
                #pragma unroll
                for (int n = 0; n < 2; ++n)
                    acc[m][n] = __builtin_amdgcn_mfma_f32_16x16x32_f16(af[m], bf[n], acc[m][n], 0, 0, 0);
            __builtin_amdgcn_s_setprio(0);
        }
    };

    stage(0, 0);
    stage(1, 1);
    for (int t = 0; t < NT; ++t) {
        if (t + 1 < NT) asm volatile("s_waitcnt vmcnt(4)" ::: "memory");
        else            asm volatile("s_waitcnt vmcnt(0)" ::: "memory");
        __builtin_amdgcn_s_barrier();
        compute(t & 1);
        __builtin_amdgcn_s_barrier();
        if (t + 2 < NT) stage(t & 1, t + 2);
    }

    // epilogue: bias -> t_h write + Tl staging ([h][c][w] pad40)
    #pragma unroll
    for (int n = 0; n < 2; ++n) {
        int cc  = wc * 32 + n * 16 + lr;
        int col = col0 + cc;
        float bj = bias[col];
        #pragma unroll
        for (int m = 0; m < 2; ++m) {
            int row = row0 + wr * 32 + m * 16 + quad * 4;
            #pragma unroll
            for (int r = 0; r < 4; ++r) {
                float v = acc[m][n][r] + bj;
                C16[(size_t)(row + r) * 768 + col] = (_Float16)v;
                int lrow = row + r - row0;
                Tl[((lrow >> 5) * 64 + cc) * 40 + (lrow & 31)] = (_Float16)v;
            }
        }
    }
    __syncthreads();

    // per-wave h-row DFT: wave handles h = wave>>1, cols (wave&1)*32..+31
    const int h     = wave >> 1;
    const int cbase = (wave & 1) * 32;
    const int b     = row0 >> 10;
    const int hp    = ((row0 >> 5) & 31) + h;
    half8 eC0 = *(const half8*)&ECl[lr * 32 + quad * 8];
    half8 eC1 = *(const half8*)&ECl[(16 + lr) * 32 + quad * 8];
    half8 eS0 = *(const half8*)&ESl[lr * 32 + quad * 8];
    half8 eS1 = *(const half8*)&ESl[(16 + lr) * 32 + quad * 8];
    float4v xr[2][2], xi[2][2];
    #pragma unroll
    for (int m = 0; m < 2; ++m)
        #pragma unroll
        for (int nj = 0; nj < 2; ++nj) {
            float4v z = {0.f, 0.f, 0.f, 0.f};
            xr[m][nj] = z; xi[m][nj] = z;
        }
    #pragma unroll
    for (int nj = 0; nj < 2; ++nj) {
        half8 tb = *(const half8*)&Tl[(h * 64 + cbase + nj * 16 + lr) * 40 + quad * 8];
        xr[0][nj] = __builtin_amdgcn_mfma_f32_16x16x32_f16(eC0, tb, xr[0][nj], 0, 0, 0);
        xr[1][nj] = __builtin_amdgcn_mfma_f32_16x16x32_f16(eC1, tb, xr[1][nj], 0, 0, 0);
        xi[0][nj] = __builtin_amdgcn_mfma_f32_16x16x32_f16(eS0, tb, xi[0][nj], 0, 0, 0);
        xi[1][nj] = __builtin_amdgcn_mfma_f32_16x16x32_f16(eS1, tb, xi[1][nj], 0, 0, 0);
    }
    #pragma unroll
    for (int m = 0; m < 2; ++m)
        #pragma unroll
        for (int r = 0; r < 4; ++r) {
            int kw = m * 16 + quad * 4 + r;
            if (kw < 17) {
                #pragma unroll
                for (int nj = 0; nj < 2; ++nj) {
                    int c = col0 + cbase + nj * 16 + lr;
                    size_t g = ((size_t)(b * 17 + kw) * 32 + hp) * 768 + c;
                    XR[g] = (_Float16)xr[m][nj][r];
                    XI[g] = (_Float16)xi[m][nj][r];
                }
            }
        }
}

// ---------------- R14: head2 64x64 tile, 4 waves, counted-vmcnt, scatter out ----------------
__global__ __launch_bounds__(256, 4) void head2_k(const _Float16* __restrict__ A,
        const _Float16* __restrict__ Bt, const float* __restrict__ bias,
        float* __restrict__ C32, int f_idx)
{
    constexpr int K = 1536;
    constexpr int NT = 24;
    __shared__ _Float16 Al[2][64 * 64];   // 16 KB
    __shared__ _Float16 Bl[2][64 * 64];   // 16 KB

    const int tid  = threadIdx.x;
    const int wave = tid >> 6;            // 0..3
    const int lane = tid & 63;
    const int wr   = wave >> 1;
    const int wc   = wave & 1;
    const int lr   = lane & 15;
    const int quad = lane >> 4;

    const int row0 = blockIdx.x * 64;

    const int srow = lane >> 3;
    const int schk = (lane & 7) ^ srow;
    const _Float16* Ab = A  + (size_t)(row0 + wave * 8 + srow) * K + schk * 8;
    const _Float16* Bb = Bt + (size_t)(wave * 8 + srow) * K + schk * 8;

    auto stage = [&](int b, int kt) {
        const int k0 = kt * 64;
        #pragma unroll
        for (int u = 0; u < 2; ++u)
            async16(Ab + (size_t)u * 32 * K + k0, &Al[b][(u * 32 + wave * 8) * 64]);
        #pragma unroll
        for (int u = 0; u < 2; ++u)
            async16(Bb + (size_t)u * 32 * K + k0, &Bl[b][(u * 32 + wave * 8) * 64]);
    };

    float4v acc[2][2];
    #pragma unroll
    for (int m = 0; m < 2; ++m)
        #pragma unroll
        for (int n = 0; n < 2; ++n) {
            float4v z = {0.f, 0.f, 0.f, 0.f};
            acc[m][n] = z;
        }

    auto compute = [&](int cb) {
        #pragma unroll
        for (int ks = 0; ks < 2; ++ks) {
            const int cA = ((ks * 4 + quad) ^ (lr & 7)) * 8;
            half8 bf[2], af[2];
            #pragma unroll
            for (int n = 0; n < 2; ++n)
                bf[n] = *(const half8*)&Bl[cb][(wc * 32 + n * 16 + lr) * 64 + cA];
            #pragma unroll
            for (int m = 0; m < 2; ++m)
                af[m] = *(const half8*)&Al[cb][(wr * 32 + m * 16 + lr) * 64 + cA];
            #pragma unroll
            for (int m = 0; m < 2; ++m)
                #pragma unroll
                for (int n = 0; n < 2; ++n)
                    acc[m][n] = __builtin_amdgcn_mfma_f32_16x16x32_f16(af[m], bf[n], acc[m][n], 0, 0, 0);
        }
    };

    stage(0, 0);
    stage(1, 1);
    for (int t = 0; t < NT; ++t) {
        if (t + 1 < NT) asm volatile("s_waitcnt vmcnt(4)" ::: "memory");
        else            asm volatile("s_waitcnt vmcnt(0)" ::: "memory");
        __builtin_amdgcn_s_barrier();
        compute(t & 1);
        __builtin_amdgcn_s_barrier();
        if (t + 2 < NT) stage(t & 1, t + 2);
    }

    // scatter epilogue: out[b][h][w][f] pixel-shuffle
    #pragma unroll
    for (int n = 0; n < 2; ++n) {
        int col = wc * 32 + n * 16 + lr;
        float bj = bias[col];
        int p = col >> 3, q = col & 7;
        #pragma unroll
        for (int m = 0; m < 2; ++m) {
            int row = row0 + wr * 32 + m * 16 + quad * 4;
            #pragma unroll
            for (int r = 0; r < 4; ++r) {
                float v = acc[m][n][r] + bj;
                int rowv = row + r;
                int bq = rowv >> 10, hp = (rowv >> 5) & 31, wp = rowv & 31;
                C32[(((size_t)(bq * 256 + hp * 8 + p)) * 256 + wp * 8 + q) * 4 + f_idx] = v;
            }
        }
    }
}

// ---------------- fp16 MFMA GEMM, depth-3 counted-vmcnt pipeline (fallback fc2 only) ----------------
template<int BN, int OUT_MODE, int ACT>
__global__ __launch_bounds__(256) void gemm_h(const _Float16* __restrict__ A,
        const _Float16* __restrict__ Bt, const float* __restrict__ bias,
        const float* __restrict__ pos, float* __restrict__ C32,
        _Float16* __restrict__ C16, _Float16* __restrict__ XR,
        _Float16* __restrict__ XI, int M, int N, int K, int f_idx)
{
    constexpr int WN  = BN / 2;
    constexpr int FN  = WN / 16;
    constexpr int NBJ = BN / 64;
    constexpr int LPT = 2 + NBJ;          // vmem loads per thread per K-tile
    __shared__ _Float16 Al[4][128 * 32];
    __shared__ _Float16 Bl[4][BN * 32];

    const int tid  = threadIdx.x;
    const int wave = tid >> 6;
    const int lane = tid & 63;
    const int wr   = wave >> 1;
    const int wc   = wave & 1;
    const int lr   = lane & 15;
    const int quad = lane >> 4;

    const int gx = gridDim.x, gy = gridDim.y, nbk = gx * gy;
    int bx = blockIdx.x, by = blockIdx.y;
    if (!(gy & 3) && !(gx & 1)) {
        int id = by * gx + bx;
        int xcd = id & 7, j = id >> 3;
        int cols = gx >> 1;
        int rows = gy >> 2;
        int jr = j / cols, jc = j % cols;
        by = (xcd >> 1) * rows + jr;
        bx = (xcd & 1) * cols + jc;
    } else if (!(nbk & 7)) {
        int id  = by * gx + bx;
        int id2 = (id & 7) * (nbk >> 3) + (id >> 3);
        by = id2 / gx; bx = id2 % gx;
    }
    const int row0 = by * 128;
    const int col0 = bx * BN;

    const int srow = lane >> 2;
    const int skof = ((lane & 3) ^ (srow & 3)) * 8;

    auto stage = [&](int b, int kt) {
        const int k0 = kt << 5;
        #pragma unroll
        for (int j = 0; j < 2; ++j)
            async16(A + (size_t)(row0 + j * 64 + wave * 16 + srow) * K + k0 + skof,
                    &Al[b][(j * 64 + wave * 16) * 32]);
        #pragma unroll
        for (int j = 0; j < NBJ; ++j)
            async16(Bt + (size_t)(col0 + j * 64 + wave * 16 + srow) * K + k0 + skof,
                    &Bl[b][(j * 64 + wave * 16) * 32]);
    };

    float4v acc[4][FN];
    #pragma unroll
    for (int i = 0; i < 4; ++i)
        #pragma unroll
        for (int j = 0; j < FN; ++j) {
            float4v z = {0.f, 0.f, 0.f, 0.f};
            acc[i][j] = z;
        }

    auto compute = [&](int cb) {
        const int cA = (quad ^ (lr & 3)) * 8;   // swizzled chunk (halfs)
        half8 af[4], bf[FN];
        #pragma unroll
        for (int i = 0; i < 4; ++i)
            af[i] = *(const half8*)&Al[cb][(wr * 64 + i * 16 + lr) * 32 + cA];
        #pragma unroll
        for (int j = 0; j < FN; ++j)
            bf[j] = *(const half8*)&Bl[cb][(wc * WN + j * 16 + lr) * 32 + cA];
        #pragma unroll
        for (int i = 0; i < 4; ++i)
            #pragma unroll
            for (int j = 0; j < FN; ++j)
                acc[i][j] = __builtin_amdgcn_mfma_f32_16x16x32_f16(af[i], bf[j], acc[i][j], 0, 0, 0);
    };

    const int KT = K >> 5;
    stage(0, 0); stage(1, 1); stage(2, 2);
    int kt = 0;
    for (; kt < KT - 3; ++kt) {
        stage((kt + 3) & 3, kt + 3);
        if constexpr (LPT == 4) asm volatile("s_waitcnt vmcnt(12)" ::: "memory");
        else                    asm volatile("s_waitcnt vmcnt(9)"  ::: "memory");
        __builtin_amdgcn_s_barrier();
        compute(kt & 3);
        asm volatile("" ::: "memory");
        __builtin_amdgcn_s_barrier();
    }
    if constexpr (LPT == 4) asm volatile("s_waitcnt vmcnt(8)" ::: "memory");
    else                    asm volatile("s_waitcnt vmcnt(6)" ::: "memory");
    __builtin_amdgcn_s_barrier();
    compute(kt & 3); ++kt;
    asm volatile("" ::: "memory");
    __builtin_amdgcn_s_barrier();
    if constexpr (LPT == 4) asm volatile("s_waitcnt vmcnt(4)" ::: "memory");
    else                    asm volatile("s_waitcnt vmcnt(3)" ::: "memory");
    __builtin_amdgcn_s_barrier();
    compute(kt & 3); ++kt;
    asm volatile("" ::: "memory");
    __builtin_amdgcn_s_barrier();
    asm volatile("s_waitcnt vmcnt(0)" ::: "memory");
    __builtin_amdgcn_s_barrier();
    compute(kt & 3);

    #pragma unroll
    for (int j = 0; j < FN; ++j) {
        int col = col0 + wc * WN + j * 16 + lr;
        float bj = bias[col];
        #pragma unroll
        for (int i = 0; i < 4; ++i) {
            int row = row0 + wr * 64 + i * 16 + quad * 4;
            #pragma unroll
            for (int r = 0; r < 4; ++r) {
                float v = acc[i][j][r] + bj;
                if (pos) v += pos[(size_t)((row + r) & 1023) * N + col];
                if (ACT) v = gelu_f(v);
                if (OUT_MODE == 3) {
                    int rowv = row + r;
                    int bq = rowv >> 10, hp = (rowv >> 5) & 31, wp = rowv & 31;
                    int p = col >> 3, q = col & 7;
                    C32[(((size_t)(bq * 256 + hp * 8 + p)) * 256 + wp * 8 + q) * 4 + f_idx] = v;
                } else {
                    C16[(size_t)(row + r) * N + col] = (_Float16)v;
                }
            }
        }
    }
}

// ---------------- launch ----------------
extern "C" void kernel_launch(void* const* d_in, const int* in_sizes, int n_in,
                              void* d_out, int out_size, void* d_ws, size_t ws_size,
                              hipStream_t stream) {
    const float* x        = (const float*)d_in[0];
    const float* grd      = (const float*)d_in[1];
    const float* conv_w   = (const float*)d_in[2];
    const float* conv_b   = (const float*)d_in[3];
    const float* pos_emb  = (const float*)d_in[4];
    const float* w1       = (const float*)d_in[5];
    const float* b1       = (const float*)d_in[6];
    const float* w2       = (const float*)d_in[7];
    const float* b2       = (const float*)d_in[8];
    const float* fc1_w    = (const float*)d_in[9];
    const float* fc1_b    = (const float*)d_in[10];
    const float* fc2_w    = (const float*)d_in[11];
    const float* fc2_b    = (const float*)d_in[12];
    const float* head_w1  = (const float*)d_in[13];
    const float* head_b1  = (const float*)d_in[14];
    const float* head_w2  = (const float*)d_in[15];
    const float* head_b2  = (const float*)d_in[16];
    float* out = (float*)d_out;
    float* ws  = (float*)d_ws;

    // ---- workspace layout, sizes in float units ----
    float* pf = ws;
    _Float16* t_h     = (_Float16*)pf; pf += 1572864;   // 4096x768 f16 (residual state)
    _Float16* Wsp     = (_Float16*)pf; pf += 589824;    // 128x9216 f16 spectral weights
    _Float16* h1t     = (_Float16*)pf; pf += 589824;    // [1536][768] f16
    _Float16* h2t     = (_Float16*)pf; pf += 49152;     // [64][1536] f16
    _Float16* convw_h = (_Float16*)pf; pf += 294912;    // 768x768 f16 (prepass only)
    float* alias    = pf;              pf += 6291456;   // hid_h 4096x3072 f16
    _Float16* hid_h = (_Float16*)alias;
    _Float16* WtAll = (_Float16*)pf;   pf += 9437184;   // 8 x [N][K] fc weights f16
    // fallback xa inside alias (hid dead when xa live); full mode: dedicated xa after WtAll
    _Float16* xa_r_fb = (_Float16*)alias;
    _Float16* xa_i_fb = (_Float16*)(alias + 835584);
    _Float16* xa_r_fu = (_Float16*)pf;                  // +835,584 f
    _Float16* xa_i_fu = (_Float16*)(pf + 835584);       // +835,584 f
    size_t full_total = (size_t)(pf - ws) + 1671168;    // 20,496,384 f = 82.0 MB
    bool full = ws_size >= full_total * 4ull;
    _Float16* xa_r = full ? xa_r_fu : xa_r_fb;
    _Float16* xa_i = full ? xa_i_fu : xa_i_fb;
    _Float16* A_h  = (_Float16*)alias;                  // prepass-only (gather input, dead after)

    // ---- prepass ----
    prep_specw<<<dim3(128), 256, 0, stream>>>(w1, w2, Wsp);
    cvt_f16<<<dim3(576), 256, 0, stream>>>(conv_w, convw_h);
    cvt_transpose<<<dim3(24, 48), 256, 0, stream>>>(head_w1, h1t, 768, 1536);
    cvt_transpose<<<dim3(48, 2), 256, 0, stream>>>(head_w2, h2t, 1536, 64);
    cvt_transpose8<<<dim3(2304, 8), 256, 0, stream>>>(fc1_w, fc2_w, WtAll);
    gather_patch<<<dim3(12288), 256, 0, stream>>>(x, grd, A_h);
    gemm128d<64, 0, 1><<<dim3(12, 32), 512, 0, stream>>>(
        A_h, convw_h, conv_b, pos_emb, t_h, 4096, 768, 768);
    dft_fwd_w<<<dim3(128, 3), 256, 0, stream>>>(t_h, xa_r, xa_i);

    for (int f = 0; f < 4; ++f) {
        for (int d = 0; d < 4; ++d) {
            // fused H-DFT + complex MLP + H-IDFT (in-place on xa), 12 waves
            spec_fused<<<dim3(68, 8), 768, 0, stream>>>(
                xa_r, xa_i,
                Wsp + (size_t)(d * 4 + 0) * 73728, Wsp + (size_t)(d * 4 + 1) * 73728,
                Wsp + (size_t)(d * 4 + 2) * 73728, Wsp + (size_t)(d * 4 + 3) * 73728,
                b1 + d * 1536, b1 + d * 1536 + 768,
                b2 + d * 1536, b2 + d * 1536 + 768);
            // irfft2 W-pass + f16 residual (in place on t_h) -- MFMA version (R15)
            idft_w_mfma<<<dim3(128, 4), 256, 0, stream>>>(xa_r, xa_i, t_h);
            // channel MLP fc1: 128x192 tile, 512 blocks = 2/CU
            gemm128d<192, 1, 0><<<dim3(16, 32), 512, 0, stream>>>(
                t_h, WtAll + (size_t)(2 * d) * 2359296, fc1_b + d * 3072,
                nullptr, hid_h, 4096, 3072, 768);
            if (full) {
                // fc2 + fused forward W-DFT (seeds xa for the next spectral block)
                fc2_fused<<<dim3(12, 64), 256, 0, stream>>>(
                    hid_h, WtAll + (size_t)(2 * d + 1) * 2359296, fc2_b + d * 768,
                    t_h, xa_r, xa_i);
            } else {
                gemm_h<64, 1, 0><<<dim3(12, 32), 256, 0, stream>>>(
                    hid_h, WtAll + (size_t)(2 * d + 1) * 2359296, fc2_b + d * 768,
                    nullptr, nullptr, t_h, nullptr, nullptr, 4096, 768, 3072, 0);
                dft_fwd_w<<<dim3(128, 3), 256, 0, stream>>>(t_h, xa_r, xa_i);
            }
        }
        // head on current state (t_h from fc2): 64-col tile, 768 blocks = 3/CU
        gemm128d<64, 1, 0><<<dim3(24, 32), 512, 0, stream>>>(
            t_h, h1t, head_b1, nullptr, hid_h, 4096, 1536, 768);
        head2_k<<<dim3(64), 256, 0, stream>>>(
            hid_h, h2t, head_b2, out, f);
    }
}